// Round 10
// baseline (610.879 us; speedup 1.0000x reference)
//
#include <hip/hip_runtime.h>
#include <hip/hip_fp16.h>
#include <math.h>
#include <stdint.h>

#define N_C 60000
#define N_V 256
#define CH 128
#define NH 4
#define HD 32
#define NL 3
#define NE1 600000
#define NE2 240000

#define CDIV(a,b) (((a)+(b)-1)/(b))
#define EPB 1024   // elems per block in counting-sort kernels

// Node KV record (512 B, stride <<9), fp8-e4m3 storage (math stays f32):
//   bytes [0,256)   : cc view, 16 chunks of 16B: chunk j = { k[8j..8j+8) , v_cc[8j..8j+8) }
//   bytes [256,512) : cv view, chunk j = { k[8j..8j+8) , v_cv[8j..8j+8) }
// gemm weights stored in MFMA FRAGMENT ORDER (see cvt_w16); LDS stage is a
// linear copy; ds_read_b128 at lane*16 is conflict-free. Weight staging is
// REGISTER-PREFETCHED one phase ahead (overlaps MFMA with the next L2 fill).

typedef _Float16 f16x8 __attribute__((ext_vector_type(8)));
typedef _Float16 f16x4 __attribute__((ext_vector_type(4)));
typedef float f32x4 __attribute__((ext_vector_type(4)));
typedef float f32x2 __attribute__((ext_vector_type(2)));

__device__ __forceinline__ float gelu_tanh(float x) {
    float x3 = x * x * x;
    float t = tanhf(0.7978845608028654f * (x + 0.044715f * x3));
    return 0.5f * x * (1.0f + t);
}

__device__ __forceinline__ void fp8x8_to_f32(uint2 w, float* f) {
    f32x2 a = __builtin_amdgcn_cvt_pk_f32_fp8(w.x, false);
    f32x2 b = __builtin_amdgcn_cvt_pk_f32_fp8(w.x, true);
    f32x2 c = __builtin_amdgcn_cvt_pk_f32_fp8(w.y, false);
    f32x2 d = __builtin_amdgcn_cvt_pk_f32_fp8(w.y, true);
    f[0] = a.x; f[1] = a.y; f[2] = b.x; f[3] = b.y;
    f[4] = c.x; f[5] = c.y; f[6] = d.x; f[7] = d.y;
}

__device__ __forceinline__ float dot8f(const float* q, const float* k) {
    float d = q[0] * k[0];
    d = fmaf(q[1], k[1], d);
    d = fmaf(q[2], k[2], d);
    d = fmaf(q[3], k[3], d);
    d = fmaf(q[4], k[4], d);
    d = fmaf(q[5], k[5], d);
    d = fmaf(q[6], k[6], d);
    d = fmaf(q[7], k[7], d);
    return d;
}

// ---------------- weight composition (Q-side + V-side in one launch) -----------
__global__ __launch_bounds__(256) void compose_both(
    const float* __restrict__ Wq, const float* __restrict__ bq,
    const float* __restrict__ arel, const float* __restrict__ prel,
    float* __restrict__ WQT, float* __restrict__ BQT,
    const float* __restrict__ Wv, const float* __restrict__ bv,
    const float* __restrict__ mrel,
    float* __restrict__ WVT, float* __restrict__ BVT)
{
    const int total = NL * 2 * (CH + 1) * CH;
    int gid = blockIdx.x * blockDim.x + threadIdx.x;
    bool qside = gid < total;
    int g2 = qside ? gid : gid - total;
    if (g2 >= total) return;
    int li2 = g2 / ((CH + 1) * CH);
    int rem = g2 % ((CH + 1) * CH);
    int c   = rem / CH;          // 0..CH ; CH => bias row
    int col = rem % CH;
    int h = col >> 5, low = col & 31;
    const float* rel = qside ? arel : mrel;
    const float* rp;
    int step;
    if (qside) { rp = rel + (li2 * NH + h) * (HD * HD) + low * HD; step = 1; }
    else       { rp = rel + (li2 * NH + h) * (HD * HD) + low;      step = HD; }
    float scale = qside ? prel[li2 * NH + h] * 0.17677669529663687f : 1.f;
    int wsel = qside ? li2 : (li2 & ~1);   // v-side always uses Wv[li][0]
    const float* W    = qside ? Wq : Wv;
    const float* bvec = qside ? bq : bv;
    const float* src = (c < CH) ? (W + ((size_t)wsel * CH + c) * CH + h * HD)
                                : (bvec + wsel * CH + h * HD);
    float acc = 0.f;
    #pragma unroll
    for (int e = 0; e < HD; e++) acc = fmaf(src[e], rp[e * step], acc);
    acc *= scale;
    float* WT = qside ? WQT : WVT;
    float* BT = qside ? BQT : BVT;
    if (c < CH) WT[((size_t)li2 * CH + c) * CH + col] = acc;
    else        BT[li2 * CH + col] = acc;
}

// ---------------- weight fp16 fragment-order emit (one thread per element) -----
// w: 0=WQT(c) 1=Wk(c) 2=WVT_cc 3=WVT_cv 4=Wa(c)
__global__ __launch_bounds__(256) void cvt_w16(
    const float* __restrict__ WQT, const float* __restrict__ Wk,
    const float* __restrict__ WVT, const float* __restrict__ Wa,
    _Float16* __restrict__ WT16)
{
    int gid = blockIdx.x * 256 + threadIdx.x;
    const int PER = CH * CH;
    if (gid >= NL * 5 * PER) return;
    int b = gid / PER, o = gid % PER;
    int li = b / 5, w = b % 5;
    const float* src;
    if      (w == 0) src = WQT + (size_t)(li * 2) * PER;
    else if (w == 1) src = Wk  + (size_t)(li * 2) * PER;
    else if (w == 2) src = WVT + (size_t)(li * 2) * PER;
    else if (w == 3) src = WVT + (size_t)(li * 2 + 1) * PER;
    else             src = Wa  + (size_t)(li * 2) * PER;
    int i = o & 7, lane = (o >> 3) & 63, f = (o >> 9) & 7, kk = o >> 12;
    int mr = lane & 15, g = lane >> 4;
    int k = kk * 32 + g * 8 + i;
    int c = (w < 4) ? (mr * 8 + f) : (f * 16 + mr);
    WT16[gid] = (_Float16)src[k * CH + c];
}

// ================= CSR build (merged cc+cv launches) ==========================
__global__ __launch_bounds__(256) void bucket_hist2(
    const int* __restrict__ dcc, const int* __restrict__ dcv, int nb_cc,
    int* __restrict__ hcc, int* __restrict__ hcv)
{
    __shared__ int h[256];
    bool cv = (int)blockIdx.x >= nb_cc;
    const int* dst = cv ? dcv : dcc;
    int E = cv ? NE2 : NE1;
    int shift = cv ? 0 : 8;
    int* bh = cv ? hcv : hcc;
    int b = cv ? blockIdx.x - nb_cc : blockIdx.x;
    int t = threadIdx.x;
    h[t] = 0;
    __syncthreads();
    int i0 = b * EPB, i1 = min(i0 + EPB, E);
    for (int i = i0 + t; i < i1; i += 256)
        atomicAdd(&h[(dst[i] >> shift) & 255], 1);
    __syncthreads();
    if (h[t] > 0) atomicAdd(&bh[t], h[t]);
}

__global__ __launch_bounds__(256) void scan256x2(
    const int* __restrict__ hcc, int* __restrict__ base_cc, int* __restrict__ cur_cc,
    const int* __restrict__ hcv, int* __restrict__ base_cv, int* __restrict__ cur_cv)
{
    __shared__ int p[256];
    bool cv = blockIdx.x > 0;
    const int* h  = cv ? hcv : hcc;
    int* base     = cv ? base_cv : base_cc;
    int* cur      = cv ? cur_cv : cur_cc;
    int t = threadIdx.x;
    int v = h[t];
    p[t] = v;
    __syncthreads();
    for (int off = 1; off < 256; off <<= 1) {
        int u = (t >= off) ? p[t - off] : 0;
        __syncthreads();
        p[t] += u;
        __syncthreads();
    }
    base[t] = p[t] - v;
    cur[t]  = p[t] - v;
    if (t == 255) base[256] = p[255];
}

__global__ __launch_bounds__(256) void partition2(
    const int* __restrict__ scc, const int* __restrict__ dcc,
    const int* __restrict__ scv, const int* __restrict__ dcv, int nb_cc,
    int* __restrict__ cur_cc, int* __restrict__ cur_cv,
    int2* __restrict__ tmp_pair, int* __restrict__ out_src)
{
    __shared__ int cnt[256], base[256], cnt2[256];
    bool cv = (int)blockIdx.x >= nb_cc;
    const int* src = cv ? scv : scc;
    const int* dst = cv ? dcv : dcc;
    int E = cv ? NE2 : NE1;
    int shift = cv ? 0 : 8;
    int* cur = cv ? cur_cv : cur_cc;
    int b = cv ? blockIdx.x - nb_cc : blockIdx.x;
    int t = threadIdx.x;
    cnt[t] = 0; cnt2[t] = 0;
    __syncthreads();
    int i0 = b * EPB, i1 = min(i0 + EPB, E);
    for (int i = i0 + t; i < i1; i += 256)
        atomicAdd(&cnt[(dst[i] >> shift) & 255], 1);
    __syncthreads();
    if (cnt[t] > 0) base[t] = atomicAdd(&cur[t], cnt[t]);
    __syncthreads();
    for (int i = i0 + t; i < i1; i += 256) {
        int d = dst[i];
        int dig = (d >> shift) & 255;
        int r = atomicAdd(&cnt2[dig], 1);
        int pos = base[dig] + r;
        if (cv) out_src[pos] = src[i];
        else    tmp_pair[pos] = make_int2(src[i], d);
    }
}

__global__ __launch_bounds__(256) void bucket_finalize(
    const int2* __restrict__ tmp, const int* __restrict__ bbase, int n, int NE,
    int* __restrict__ rs, int* __restrict__ csr)
{
    __shared__ int cnt[256], pre[256], cnt2[256];
    int b = blockIdx.x, t = threadIdx.x;
    int s0 = bbase[b], s1 = bbase[b + 1];
    cnt[t] = 0; cnt2[t] = 0;
    __syncthreads();
    for (int i = s0 + t; i < s1; i += 256)
        atomicAdd(&cnt[tmp[i].y & 255], 1);
    __syncthreads();
    int v = cnt[t];
    pre[t] = v;
    __syncthreads();
    for (int off = 1; off < 256; off <<= 1) {
        int u = (t >= off) ? pre[t - off] : 0;
        __syncthreads();
        pre[t] += u;
        __syncthreads();
    }
    pre[t] -= v;   // exclusive
    __syncthreads();
    int dstid = b * 256 + t;
    if (dstid < n) rs[dstid] = s0 + pre[t];
    if (b == 0 && t == 0) rs[n] = NE;
    for (int i = s0 + t; i < s1; i += 256) {
        int2 e = tmp[i];
        int low = e.y & 255;
        int r = atomicAdd(&cnt2[low], 1);
        csr[s0 + pre[low] + r] = e.x;
    }
}

// ---------------- layer-0 MFMA q~/k/v_cc/v_cv GEMM (prefetched staging) --------
__global__ __launch_bounds__(256) void gemm_qkv(
    const float* __restrict__ A, int lda, int M,
    const _Float16* __restrict__ WT4,   // 4 matrices, fragment order
    const float* __restrict__ b0, const float* __restrict__ b1,
    const float* __restrict__ b2, const float* __restrict__ b3,
    float* __restrict__ out, unsigned char* __restrict__ kv8)
{
    extern __shared__ char dynsm[];   // 32768 B
    int tid = threadIdx.x;

    // prefetch W0 while A stages
    uint4 wreg[8];
    {
        const uint4* W0 = (const uint4*)WT4;
        #pragma unroll
        for (int i = 0; i < 8; i++) wreg[i] = W0[tid + i * 256];
    }

    _Float16 (*Af)[136] = (_Float16(*)[136])dynsm;   // A-stage view (dead after frags)
    int row0 = blockIdx.x * 64;
    #pragma unroll
    for (int i = 0; i < 8; i++) {
        int slot = tid + i * 256;            // 2048 float4 slots
        int r = slot >> 5, q = slot & 31;
        int rr = row0 + r;
        float4 v = make_float4(0.f, 0.f, 0.f, 0.f);
        if (rr < M) v = *(const float4*)(A + (size_t)rr * lda + q * 4);
        f16x4 h = { (_Float16)v.x, (_Float16)v.y, (_Float16)v.z, (_Float16)v.w };
        *(f16x4*)&Af[r][q * 4] = h;
    }
    __syncthreads();

    int lane = tid & 63, w = tid >> 6;
    int mr = lane & 15, g = lane >> 4;
    f16x8 afr[4];
    #pragma unroll
    for (int kk = 0; kk < 4; kk++)
        afr[kk] = *(const f16x8*)&Af[w * 16 + mr][kk * 32 + g * 8];
    __syncthreads();   // A region now reusable as B buffer

    _Float16* Bl = (_Float16*)dynsm;
    uint4* Blv = (uint4*)dynsm;
    const float* bs[4] = {b0, b1, b2, b3};
    uint2 kp[4];   // packed fp8 k piece per row (carried jw=1 -> jw=2,3)
    for (int jw = 0; jw < 4; jw++) {
        #pragma unroll
        for (int i = 0; i < 8; i++) Blv[tid + i * 256] = wreg[i];
        __syncthreads();
        if (jw < 3) {
            const uint4* Wn = (const uint4*)(WT4 + (size_t)(jw + 1) * CH * CH);
            #pragma unroll
            for (int i = 0; i < 8; i++) wreg[i] = Wn[tid + i * 256];
        }

        f32x4 acc[8] = {};
        #pragma unroll
        for (int kk = 0; kk < 4; kk++) {
            f16x8 bf[8];
            #pragma unroll
            for (int f = 0; f < 8; f++)
                bf[f] = *(const f16x8*)(Bl + (size_t)((kk * 8 + f) * 64 + lane) * 8);
            #pragma unroll
            for (int f = 0; f < 8; f++)
                acc[f] = __builtin_amdgcn_mfma_f32_16x16x32_f16(afr[kk], bf[f], acc[f], 0, 0, 0);
        }
        const float* bb = bs[jw];
        float4 blo = *(const float4*)&bb[mr * 8];
        float4 bhi = *(const float4*)&bb[mr * 8 + 4];
        float bias[8] = {blo.x, blo.y, blo.z, blo.w, bhi.x, bhi.y, bhi.z, bhi.w};
        if (jw == 0) {
            #pragma unroll
            for (int r = 0; r < 4; r++) {
                int row = row0 + w * 16 + g * 4 + r;
                if (row < M) {
                    float4 o0 = make_float4(acc[0][r] + bias[0], acc[1][r] + bias[1],
                                            acc[2][r] + bias[2], acc[3][r] + bias[3]);
                    float4 o1 = make_float4(acc[4][r] + bias[4], acc[5][r] + bias[5],
                                            acc[6][r] + bias[6], acc[7][r] + bias[7]);
                    float* op = out + (size_t)row * 128 + mr * 8;
                    *(float4*)op = o0;
                    *(float4*)(op + 4) = o1;
                }
            }
        } else {
            #pragma unroll
            for (int r = 0; r < 4; r++) {
                float v0 = acc[0][r] + bias[0], v1 = acc[1][r] + bias[1];
                float v2 = acc[2][r] + bias[2], v3 = acc[3][r] + bias[3];
                float v4 = acc[4][r] + bias[4], v5 = acc[5][r] + bias[5];
                float v6 = acc[6][r] + bias[6], v7 = acc[7][r] + bias[7];
                unsigned int lo = (unsigned)__builtin_amdgcn_cvt_pk_fp8_f32(v0, v1, 0, false);
                lo = (unsigned)__builtin_amdgcn_cvt_pk_fp8_f32(v2, v3, (int)lo, true);
                unsigned int hi = (unsigned)__builtin_amdgcn_cvt_pk_fp8_f32(v4, v5, 0, false);
                hi = (unsigned)__builtin_amdgcn_cvt_pk_fp8_f32(v6, v7, (int)hi, true);
                if (jw == 1) {
                    kp[r] = make_uint2(lo, hi);
                } else {
                    int row = row0 + w * 16 + g * 4 + r;
                    if (row < M) {
                        unsigned char* base = kv8 + ((size_t)row << 9) + mr * 16
                                            + ((jw == 3) ? 256 : 0);
                        *(uint4*)base = make_uint4(kp[r].x, kp[r].y, lo, hi);
                    }
                }
            }
        }
        __syncthreads();   // B buffer reused next jw
    }
}

// ---------------- FUSED: gemm128(li) c-side + gemm_qkv(li+1); v-side tail ------
__global__ __launch_bounds__(256) void gemm_fused(
    int nblk1, int do_qkv,
    // c-side gemm128 (layer li)
    const float* __restrict__ A1, const _Float16* __restrict__ Wa_h,
    const float* __restrict__ bias1, float* __restrict__ xc_out, int M,
    const float* __restrict__ gate1, const float* __restrict__ xold1,
    const float* __restrict__ wk1, const float* __restrict__ bk1, float* __restrict__ ko1,
    const float* __restrict__ wv1, const float* __restrict__ bv1, float* __restrict__ vo1,
    // qkv of layer li+1 (ignored when do_qkv == 0)
    const _Float16* __restrict__ WT4,
    const float* __restrict__ qb0, const float* __restrict__ qb1,
    const float* __restrict__ qb2, const float* __restrict__ qb3,
    float* __restrict__ xq_out, unsigned char* __restrict__ kv8,
    // v-side gemm128 (layer li)
    const float* __restrict__ A2, int lda2, const float* __restrict__ W2,
    const float* __restrict__ bias2, float* __restrict__ out2, int M2,
    const float* __restrict__ gate2, const float* __restrict__ xold2,
    const float* __restrict__ wk2, const float* __restrict__ bk2, float* __restrict__ ko2)
{
    extern __shared__ char dynsm[];
    int tid = threadIdx.x;

    if ((int)blockIdx.x >= nblk1) {
        // ======================= v-side: fp32 vector =======================
        float (*As)[36]  = (float(*)[36])dynsm;                 // 9216 B
        float (*Bs)[128] = (float(*)[128])(dynsm + 64 * 36 * 4); // 16384 B
        int row0 = (blockIdx.x - nblk1) * 64;
        int tx = tid & 15;
        int ty = tid >> 4;
        float acc[4][8] = {};
        for (int k0 = 0; k0 < 128; k0 += 32) {
            __syncthreads();
            #pragma unroll
            for (int i = 0; i < 2; i++) {
                int slot = tid + i * 256;            // [0,512) float4 slots
                int r = slot >> 3, kq = slot & 7;
                int rr = row0 + r;
                float4 v = make_float4(0.f, 0.f, 0.f, 0.f);
                if (rr < M2) v = *(const float4*)(A2 + (size_t)rr * lda2 + k0 + kq * 4);
                *(float4*)&As[r][kq * 4] = v;
            }
            #pragma unroll
            for (int i = 0; i < 4; i++) {
                int slot = tid + i * 256;            // [0,1024)
                int kr = slot >> 5, cq = slot & 31;
                *(float4*)&Bs[kr][cq * 4] = *(const float4*)(W2 + (size_t)(k0 + kr) * 128 + cq * 4);
            }
            __syncthreads();
            #pragma unroll
            for (int k4 = 0; k4 < 32; k4 += 4) {
                float4 av[4];
                #pragma unroll
                for (int i = 0; i < 4; i++)
                    av[i] = *(const float4*)&As[ty * 4 + i][k4];
                #pragma unroll
                for (int kk = 0; kk < 4; kk++) {
                    float4 bl = *(const float4*)&Bs[k4 + kk][tx * 4];
                    float4 bh = *(const float4*)&Bs[k4 + kk][64 + tx * 4];
                    float bb[8] = {bl.x, bl.y, bl.z, bl.w, bh.x, bh.y, bh.z, bh.w};
                    #pragma unroll
                    for (int i = 0; i < 4; i++) {
                        float a = ((const float*)&av[i])[kk];
                        #pragma unroll
                        for (int j = 0; j < 8; j++)
                            acc[i][j] = fmaf(a, bb[j], acc[i][j]);
                    }
                }
            }
        }
        float gt = 1.f / (1.f + expf(-gate2[0]));
        float og = 1.f - gt;
        float wkr[8];
        #pragma unroll
        for (int j = 0; j < 4; j++) {
            wkr[j]     = wk2[tx * 4 + j];
            wkr[4 + j] = wk2[64 + tx * 4 + j];
        }
        #pragma unroll
        for (int i = 0; i < 4; i++) {
            int r = row0 + ty * 4 + i;
            if (r >= M2) continue;   // uniform across each 16-lane group
            float vals[8];
            #pragma unroll
            for (int j = 0; j < 4; j++) {
                float v0 = acc[i][j]     + bias2[tx * 4 + j];
                float v1 = acc[i][4 + j] + bias2[64 + tx * 4 + j];
                v0 = gt * v0 + og * xold2[(size_t)r * 128 + tx * 4 + j];
                v1 = gt * v1 + og * xold2[(size_t)r * 128 + 64 + tx * 4 + j];
                vals[j] = v0;
                vals[4 + j] = v1;
            }
            float* op = out2 + (size_t)r * 128;
            *(float4*)(op + tx * 4)      = make_float4(vals[0], vals[1], vals[2], vals[3]);
            *(float4*)(op + 64 + tx * 4) = make_float4(vals[4], vals[5], vals[6], vals[7]);
            float pk = 0.f;
            #pragma unroll
            for (int j = 0; j < 8; j++) pk = fmaf(vals[j], wkr[j], pk);
            #pragma unroll
            for (int off = 1; off < 16; off <<= 1)
                pk += __shfl_xor(pk, off, 64);
            if (tx == 0) ko2[r] = pk + bk2[0];
        }
        return;
    }

    // ======================= c-side: gemm128 MFMA then qkv =======================
    // prefetch Wa while A stages
    uint4 wreg[8];
    {
        const uint4* W0 = (const uint4*)Wa_h;
        #pragma unroll
        for (int i = 0; i < 8; i++) wreg[i] = W0[tid + i * 256];
    }

    _Float16 (*Af)[136] = (_Float16(*)[136])dynsm;
    int row0 = blockIdx.x * 64;
    #pragma unroll
    for (int i = 0; i < 8; i++) {
        int slot = tid + i * 256;
        int r = slot >> 5, q = slot & 31;
        int rr = row0 + r;
        float4 v = make_float4(0.f, 0.f, 0.f, 0.f);
        if (rr < M) v = *(const float4*)(A1 + (size_t)rr * 128 + q * 4);
        f16x4 h = { (_Float16)v.x, (_Float16)v.y, (_Float16)v.z, (_Float16)v.w };
        *(f16x4*)&Af[r][q * 4] = h;
    }
    __syncthreads();

    int lane = tid & 63, w = tid >> 6;
    int mr = lane & 15, g = lane >> 4;
    f16x8 afr[4];
    #pragma unroll
    for (int kk = 0; kk < 4; kk++)
        afr[kk] = *(const f16x8*)&Af[w * 16 + mr][kk * 32 + g * 8];
    __syncthreads();   // A region -> B buffer

    _Float16* Bl = (_Float16*)dynsm;
    uint4* Blv = (uint4*)dynsm;
    #pragma unroll
    for (int i = 0; i < 8; i++) Blv[tid + i * 256] = wreg[i];
    __syncthreads();
    if (do_qkv) {
        const uint4* Wn = (const uint4*)WT4;
        #pragma unroll
        for (int i = 0; i < 8; i++) wreg[i] = Wn[tid + i * 256];
    }

    f32x4 acc[8] = {};
    #pragma unroll
    for (int kk = 0; kk < 4; kk++) {
        f16x8 bf[8];
        #pragma unroll
        for (int f = 0; f < 8; f++)
            bf[f] = *(const f16x8*)(Bl + (size_t)((kk * 8 + f) * 64 + lane) * 8);
        #pragma unroll
        for (int f = 0; f < 8; f++)
            acc[f] = __builtin_amdgcn_mfma_f32_16x16x32_f16(afr[kk], bf[f], acc[f], 0, 0, 0);
    }
    __syncthreads();   // all B reads done; LDS free for phase 2

    float gt = 1.f / (1.f + expf(-gate1[0]));
    float og = 1.f - gt;
    float vals[8][4];
    float pk[4] = {}, pv[4] = {};
    #pragma unroll
    for (int f = 0; f < 8; f++) {
        int col = f * 16 + mr;
        float bias = bias1[col];
        float wkc = wk1[col];
        float wvc = wv1[col];
        #pragma unroll
        for (int r = 0; r < 4; r++) {
            int row = row0 + w * 16 + g * 4 + r;
            float v = 0.f;
            if (row < M) {
                v = acc[f][r] + bias;
                v = gt * v + og * xold1[(size_t)row * 128 + col];
                xc_out[(size_t)row * 128 + col] = v;
                pk[r] = fmaf(v, wkc, pk[r]);
                pv[r] = fmaf(v, wvc, pv[r]);
            }
            vals[f][r] = v;
        }
    }
    #pragma unroll
    for (int r = 0; r < 4; r++) {
        #pragma unroll
        for (int off = 1; off < 16; off <<= 1) {
            pk[r] += __shfl_xor(pk[r], off, 64);
            pv[r] += __shfl_xor(pv[r], off, 64);
        }
    }
    if (mr == 0) {
        #pragma unroll
        for (int r = 0; r < 4; r++) {
            int row = row0 + w * 16 + g * 4 + r;
            if (row < M) {
                ko1[row] = pk[r] + bk1[0];
                vo1[row] = pv[r] + bv1[0];
            }
        }
    }

    if (!do_qkv) return;

    // -------- phase 2: next-layer q~/k/v_cc/v_cv from the block-local XC tile ---
    #pragma unroll
    for (int f = 0; f < 8; f++) {
        int col = f * 16 + mr;
        #pragma unroll
        for (int r = 0; r < 4; r++)
            Af[w * 16 + g * 4 + r][col] = (_Float16)vals[f][r];
    }
    __syncthreads();
    f16x8 afr2[4];
    #pragma unroll
    for (int kk = 0; kk < 4; kk++)
        afr2[kk] = *(const f16x8*)&Af[w * 16 + mr][kk * 32 + g * 8];
    __syncthreads();

    const float* bs[4] = {qb0, qb1, qb2, qb3};
    uint2 kp[4];
    for (int jw = 0; jw < 4; jw++) {
        #pragma unroll
        for (int i = 0; i < 8; i++) Blv[tid + i * 256] = wreg[i];
        __syncthreads();
        if (jw < 3) {
            const uint4* Wn = (const uint4*)(WT4 + (size_t)(jw + 1) * CH * CH);
            #pragma unroll
            for (int i = 0; i < 8; i++) wreg[i] = Wn[tid + i * 256];
        }

        f32x4 acc2[8] = {};
        #pragma unroll
        for (int kk = 0; kk < 4; kk++) {
            f16x8 bf[8];
            #pragma unroll
            for (int f = 0; f < 8; f++)
                bf[f] = *(const f16x8*)(Bl + (size_t)((kk * 8 + f) * 64 + lane) * 8);
            #pragma unroll
            for (int f = 0; f < 8; f++)
                acc2[f] = __builtin_amdgcn_mfma_f32_16x16x32_f16(afr2[kk], bf[f], acc2[f], 0, 0, 0);
        }
        const float* bb = bs[jw];
        float4 blo = *(const float4*)&bb[mr * 8];
        float4 bhi = *(const float4*)&bb[mr * 8 + 4];
        float bias[8] = {blo.x, blo.y, blo.z, blo.w, bhi.x, bhi.y, bhi.z, bhi.w};
        if (jw == 0) {
            #pragma unroll
            for (int r = 0; r < 4; r++) {
                int row = row0 + w * 16 + g * 4 + r;
                if (row < M) {
                    float4 o0 = make_float4(acc2[0][r] + bias[0], acc2[1][r] + bias[1],
                                            acc2[2][r] + bias[2], acc2[3][r] + bias[3]);
                    float4 o1 = make_float4(acc2[4][r] + bias[4], acc2[5][r] + bias[5],
                                            acc2[6][r] + bias[6], acc2[7][r] + bias[7]);
                    float* op = xq_out + (size_t)row * 128 + mr * 8;
                    *(float4*)op = o0;
                    *(float4*)(op + 4) = o1;
                }
            }
        } else {
            #pragma unroll
            for (int r = 0; r < 4; r++) {
                float v0 = acc2[0][r] + bias[0], v1 = acc2[1][r] + bias[1];
                float v2 = acc2[2][r] + bias[2], v3 = acc2[3][r] + bias[3];
                float v4 = acc2[4][r] + bias[4], v5 = acc2[5][r] + bias[5];
                float v6 = acc2[6][r] + bias[6], v7 = acc2[7][r] + bias[7];
                unsigned int lo = (unsigned)__builtin_amdgcn_cvt_pk_fp8_f32(v0, v1, 0, false);
                lo = (unsigned)__builtin_amdgcn_cvt_pk_fp8_f32(v2, v3, (int)lo, true);
                unsigned int hi = (unsigned)__builtin_amdgcn_cvt_pk_fp8_f32(v4, v5, 0, false);
                hi = (unsigned)__builtin_amdgcn_cvt_pk_fp8_f32(v6, v7, (int)hi, true);
                if (jw == 1) {
                    kp[r] = make_uint2(lo, hi);
                } else {
                    int row = row0 + w * 16 + g * 4 + r;
                    if (row < M) {
                        unsigned char* base = kv8 + ((size_t)row << 9) + mr * 16
                                            + ((jw == 3) ? 256 : 0);
                        *(uint4*)base = make_uint4(kp[r].x, kp[r].y, lo, hi);
                    }
                }
            }
        }
        __syncthreads();
    }
}

// ---------------- cv gather: 4 groups on one node, 64-edge chunks --------------
__device__ __forceinline__ void gather_cv(
    const unsigned char* __restrict__ kv8, const int* __restrict__ csr,
    int e0, int e1, int g, int j, const float* q8,
    float& s_io, float acc[8])
{
    int lane = threadIdx.x & 63;
    float s = s_io;
    for (int cs = e0; cs < e1; cs += 64) {
        int n = e1 - cs; if (n > 64) n = 64;
        int nm1 = n - 1;
        int idx0 = 0;
        if (lane < n) idx0 = csr[cs + lane];
        int R = (n + 7) >> 3;
        uint4 a0, a1, b0, b1;

#define LD2(E0_, E1_, B0_, B1_) { \
            int i0_ = __shfl(idx0, min((E0_), nm1), 64); \
            int i1_ = __shfl(idx0, min((E1_), nm1), 64); \
            B0_ = *(const uint4*)(kv8 + ((size_t)i0_ << 9) + 256 + (j << 4)); \
            B1_ = *(const uint4*)(kv8 + ((size_t)i1_ << 9) + 256 + (j << 4)); }

#define CMP2(E0_, E1_, B0_, B1_) { \
            float k0f[8], k1f[8], v0f[8], v1f[8]; \
            fp8x8_to_f32(make_uint2(B0_.x, B0_.y), k0f); \
            fp8x8_to_f32(make_uint2(B1_.x, B1_.y), k1f); \
            float d0_ = dot8f(q8, k0f); \
            float d1_ = dot8f(q8, k1f); \
            d0_ += __shfl_xor(d0_, 1, 64); d1_ += __shfl_xor(d1_, 1, 64); \
            d0_ += __shfl_xor(d0_, 2, 64); d1_ += __shfl_xor(d1_, 2, 64); \
            float w0_ = ((E0_) < n) ? __expf(d0_) : 0.f; \
            float w1_ = ((E1_) < n) ? __expf(d1_) : 0.f; \
            s += w0_ + w1_; \
            fp8x8_to_f32(make_uint2(B0_.z, B0_.w), v0f); \
            fp8x8_to_f32(make_uint2(B1_.z, B1_.w), v1f); \
            acc[0] = fmaf(w0_, v0f[0], acc[0]); acc[0] = fmaf(w1_, v1f[0], acc[0]); \
            acc[1] = fmaf(w0_, v0f[1], acc[1]); acc[1] = fmaf(w1_, v1f[1], acc[1]); \
            acc[2] = fmaf(w0_, v0f[2], acc[2]); acc[2] = fmaf(w1_, v1f[2], acc[2]); \
            acc[3] = fmaf(w0_, v0f[3], acc[3]); acc[3] = fmaf(w1_, v1f[3], acc[3]); \
            acc[4] = fmaf(w0_, v0f[4], acc[4]); acc[4] = fmaf(w1_, v1f[4], acc[4]); \
            acc[5] = fmaf(w0_, v0f[5], acc[5]); acc[5] = fmaf(w1_, v1f[5], acc[5]); \
            acc[6] = fmaf(w0_, v0f[6], acc[6]); acc[6] = fmaf(w1_, v1f[6], acc[6]); \
            acc[7] = fmaf(w0_, v0f[7], acc[7]); acc[7] = fmaf(w1_, v1f[7], acc[7]); }

        LD2(g, g + 4, a0, a1);
        if (R > 1) LD2(g + 8, g + 12, b0, b1);
        for (int r = 0; r < R; r += 2) {
            int er = g + 8 * r;
            CMP2(er, er + 4, a0, a1);
            if (r + 2 < R) LD2(g + 8 * (r + 2), g + 8 * (r + 2) + 4, a0, a1);
            if (r + 1 < R) {
                int eo = g + 8 * (r + 1);
                CMP2(eo, eo + 4, b0, b1);
                if (r + 3 < R) LD2(g + 8 * (r + 3), g + 8 * (r + 3) + 4, b0, b1);
            }
        }
#undef LD2
#undef CMP2
    }
    s_io = s;
}

// ---------------- unified attention: cv | cc | prev-layer out-conv tail --------
__global__ __launch_bounds__(256) void attn_uni(
    float* __restrict__ xq, const unsigned char* __restrict__ kv8,
    const float* __restrict__ xv, const float* __restrict__ wqt,
    const float* __restrict__ bqt,
    const int* __restrict__ rs_cc, const int* __restrict__ csr_cc,
    const int* __restrict__ rs_cv, const int* __restrict__ csr_cv,
    float* __restrict__ aggv, int n_c, int ccb,
    // out-conv tail (prev layer); only when grid extends past N_V+ccb
    const float* __restrict__ qo, const float* __restrict__ ko,
    const float* __restrict__ vo,
    const float* __restrict__ arel_o, const float* __restrict__ prel_o,
    const float* __restrict__ mrel_o, const float* __restrict__ Wa_o,
    const float* __restrict__ ba_o, float* __restrict__ outl)
{
    __shared__ float smem[656];
    int lane = threadIdx.x & 63, wid = threadIdx.x >> 6;
    int g = lane >> 4, j = lane & 15;

    if (blockIdx.x < N_V) {
        // ---------------- cv node (4 waves, 4 groups each) ----------------
        int node = blockIdx.x;
        float* qrow = smem;          // [128]
        float* sm_s = smem + 128;    // [4][4]
        float* sm_a = smem + 144;    // [4][128]
        if (wid < 2) {
            int col = wid * 64 + lane;
            float a = bqt[col];
            const float* xr = xv + (size_t)node * 128;
            for (int k = 0; k < 128; k++)
                a = fmaf(xr[k], wqt[(size_t)k * 128 + col], a);
            qrow[col] = a;
        }
        __syncthreads();
        float q8[8];
        *(float4*)&q8[0] = *(const float4*)&qrow[8 * j];
        *(float4*)&q8[4] = *(const float4*)&qrow[8 * j + 4];
        int rs = rs_cv[node], re = rs_cv[node + 1];
        int cnt = re - rs;
        int per = (cnt + 3) >> 2;
        int e0 = rs + wid * per, e1 = min(e0 + per, re);
        float s = 0.f;
        float acc[8] = {};
        gather_cv(kv8, csr_cv, e0, e1, g, j, q8, s, acc);
        #pragma unroll
        for (int i = 0; i < 8; i++) {
            acc[i] += __shfl_xor(acc[i], 16, 64);
            acc[i] += __shfl_xor(acc[i], 32, 64);
        }
        s += __shfl_xor(s, 16, 64);
        s += __shfl_xor(s, 32, 64);
        if (g == 0) {
            *(float4*)&sm_a[wid * 128 + 8 * j]     = make_float4(acc[0], acc[1], acc[2], acc[3]);
            *(float4*)&sm_a[wid * 128 + 8 * j + 4] = make_float4(acc[4], acc[5], acc[6], acc[7]);
            if ((j & 3) == 0) sm_s[wid * 4 + (j >> 2)] = s;
        }
        __syncthreads();
        if (threadIdx.x < 64) {
            int lp = 2 * lane;
            int h = lp >> 5;
            float S = 0.f, AX = 0.f, AY = 0.f;
            #pragma unroll
            for (int i = 0; i < 4; i++) {
                S  += sm_s[i * 4 + h];
                float2 a2 = *(const float2*)&sm_a[i * 128 + lp];
                AX += a2.x;
                AY += a2.y;
            }
            float inv = (S > 0.f) ? 1.f / S : 0.f;
            aggv[(size_t)node * 128 + lp]     = gelu_tanh(AX * inv);
            aggv[(size_t)node * 128 + lp + 1] = gelu_tanh(AY * inv);
        }
    } else if ((int)blockIdx.x < N_V + ccb) {
        // ---------------- cc: one node per 16-lane group ----------------
        int node = (blockIdx.x - N_V) * 16 + wid * 4 + g;
        bool valid = (node < n_c);
        int rs = valid ? rs_cc[node] : 0;
        int re = valid ? rs_cc[node + 1] : 0;
        float q8[8];
        if (valid) {
            const float* qp = xq + (size_t)node * 128 + 8 * j;
            *(float4*)&q8[0] = *(const float4*)qp;
            *(float4*)&q8[4] = *(const float4*)(qp + 4);
        } else {
            #pragma unroll
            for (int i = 0; i < 8; i++) q8[i] = 0.f;
        }
        float s = 0.f;
        float acc[8] = {};
        int base = lane & 48;

        for (int cs = rs; cs < re; cs += 16) {
            int cnt = min(16, re - cs);
            int cm1 = cnt - 1;
            int idx = csr_cc[cs + min(j, cm1)];
            uint4 B0, B1, B2, B3;

#define LDE(E_, B_) { int i_ = __shfl(idx, base + min((E_), cm1), 64); \
            B_ = *(const uint4*)(kv8 + ((size_t)i_ << 9) + (j << 4)); }
#define CMPE(E_, B_) { float kf[8], vf[8]; \
            fp8x8_to_f32(make_uint2(B_.x, B_.y), kf); \
            float d_ = dot8f(q8, kf); \
            d_ += __shfl_xor(d_, 1, 64); d_ += __shfl_xor(d_, 2, 64); \
            float w_ = ((E_) < cnt) ? __expf(d_) : 0.f; \
            s += w_; \
            fp8x8_to_f32(make_uint2(B_.z, B_.w), vf); \
            acc[0] = fmaf(w_, vf[0], acc[0]); \
            acc[1] = fmaf(w_, vf[1], acc[1]); \
            acc[2] = fmaf(w_, vf[2], acc[2]); \
            acc[3] = fmaf(w_, vf[3], acc[3]); \
            acc[4] = fmaf(w_, vf[4], acc[4]); \
            acc[5] = fmaf(w_, vf[5], acc[5]); \
            acc[6] = fmaf(w_, vf[6], acc[6]); \
            acc[7] = fmaf(w_, vf[7], acc[7]); }

            LDE(0, B0) LDE(1, B1) LDE(2, B2) LDE(3, B3)
            CMPE(0, B0) CMPE(1, B1)
            if (cnt > 4) { LDE(4, B0) LDE(5, B1) }
            CMPE(2, B2) CMPE(3, B3)
            if (cnt > 6) { LDE(6, B2) LDE(7, B3) }
            if (cnt > 4) {
                CMPE(4, B0) CMPE(5, B1)
                if (cnt > 8) { LDE(8, B0) LDE(9, B1) }
                CMPE(6, B2) CMPE(7, B3)
                if (cnt > 10) { LDE(10, B2) LDE(11, B3) }
                if (cnt > 8) {
                    CMPE(8, B0) CMPE(9, B1)
                    if (cnt > 12) { LDE(12, B0) LDE(13, B1) }
                    CMPE(10, B2) CMPE(11, B3)
                    if (cnt > 14) { LDE(14, B2) LDE(15, B3) }
                    if (cnt > 12) {
                        CMPE(12, B0) CMPE(13, B1) CMPE(14, B2) CMPE(15, B3)
                    }
                }
            }
#undef LDE
#undef CMPE
        }
        if (valid) {
            float inv = (s > 0.f) ? 1.f / s : 0.f;
            float4 o0 = make_float4(gelu_tanh(acc[0] * inv), gelu_tanh(acc[1] * inv),
                                    gelu_tanh(acc[2] * inv), gelu_tanh(acc[3] * inv));
            float4 o1 = make_float4(gelu_tanh(acc[4] * inv), gelu_tanh(acc[5] * inv),
                                    gelu_tanh(acc[6] * inv), gelu_tanh(acc[7] * inv));
            float* op = xq + (size_t)node * 128 + 8 * j;
            *(float4*)op = o0;
            *(float4*)(op + 4) = o1;
        }
    } else {
        // ---------------- prev-layer out-conv scalar attention ----------------
        int node = blockIdx.x - N_V - ccb;
        float* sms = smem;       // [4]
        float* sma = smem + 4;   // [4]
        float qs = qo[node] * arel_o[0] * prel_o[0];
        int rs = rs_cv[node], re = rs_cv[node + 1];
        float s = 0.f, a = 0.f;
        for (int e = rs + (int)threadIdx.x; e < re; e += 256) {
            int si = csr_cv[e];
            float w = __expf(qs * ko[si]);
            s += w;
            a = fmaf(w, vo[si], a);
        }
        #pragma unroll
        for (int off = 32; off >= 1; off >>= 1) {
            s += __shfl_xor(s, off, 64);
            a += __shfl_xor(a, off, 64);
        }
        if (lane == 0) { sms[wid] = s; sma[wid] = a; }
        __syncthreads();
        if (threadIdx.x == 0) {
            float S = sms[0] + sms[1] + sms[2] + sms[3];
            float A = sma[0] + sma[1] + sma[2] + sma[3];
            float agg = (S > 0.f) ? A / S : 0.f;
            agg *= mrel_o[0];
            outl[node] = gelu_tanh(agg) * Wa_o[0] + ba_o[0];
        }
    }
}

// ---------------- out-conv scalar attention (standalone, last layer) -----------
__global__ __launch_bounds__(256) void attn_out(
    const float* __restrict__ qo, const float* __restrict__ ko, const float* __restrict__ vo,
    const int* __restrict__ rowstart, const int* __restrict__ csr,
    const float* __restrict__ arel_o, const float* __restrict__ prel_o,
    const float* __restrict__ mrel_o, const float* __restrict__ Wa_o,
    const float* __restrict__ ba_o, float* __restrict__ outl)
{
    int node = blockIdx.x;
    float qs = qo[node] * arel_o[0] * prel_o[0];
    int rs = rowstart[node], re = rowstart[node + 1];
    float s = 0.f, a = 0.f;
    for (int e = rs + (int)threadIdx.x; e < re; e += 256) {
        int si = csr[e];
        float w = __expf(qs * ko[si]);
        s += w;
        a = fmaf(w, vo[si], a);
    }
    #pragma unroll
    for (int off = 32; off >= 1; off >>= 1) {
        s += __shfl_xor(s, off, 64);
        a += __shfl_xor(a, off, 64);
    }
    __shared__ float sms[4], sma[4];
    int lane = threadIdx.x & 63, wid = threadIdx.x >> 6;
    if (lane == 0) { sms[wid] = s; sma[wid] = a; }
    __syncthreads();
    if (threadIdx.x == 0) {
        float S = sms[0] + sms[1] + sms[2] + sms[3];
        float A = sma[0] + sma[1] + sma[2] + sma[3];
        float agg = (S > 0.f) ? A / S : 0.f;
        agg *= mrel_o[0];
        outl[node] = gelu_tanh(agg) * Wa_o[0] + ba_o[0];
    }
}

// ---------------- final head: JK-max -> node_fc -> MLP ------------------------
__global__ void final_head(const float* __restrict__ outs,
    const float* __restrict__ fc_W, const float* __restrict__ fc_b,
    const float* __restrict__ W1, const float* __restrict__ b1,
    const float* __restrict__ W2, const float* __restrict__ b2,
    float* __restrict__ out)
{
    int b = threadIdx.x;
    if (b >= 64) return;
    float h = fc_b[0];
    #pragma unroll
    for (int v = 0; v < 4; v++) {
        int n = b * 4 + v;
        float jk = fmaxf(fmaxf(outs[0 * N_V + n], outs[1 * N_V + n]), outs[2 * N_V + n]);
        h = fmaf(jk, fc_W[v], h);
    }
    h = gelu_tanh(h);
    float h0 = gelu_tanh(h * W1[0] + b1[0]);
    float h1 = gelu_tanh(h * W1[1] + b1[1]);
    out[b] = h0 * W2[0] + h1 * W2[1] + b2[0];
}

// ---------------- orchestration ----------------------------------------------
extern "C" void kernel_launch(void* const* d_in, const int* in_sizes, int n_in,
                              void* d_out, int out_size, void* d_ws, size_t ws_size,
                              hipStream_t stream) {
    (void)in_sizes; (void)n_in; (void)out_size; (void)ws_size;
    const float* x_cell  = (const float*)d_in[0];
    const float* x_vcell = (const float*)d_in[1];
    const float* Wk   = (const float*)d_in[2];
    const float* bk   = (const float*)d_in[3];
    const float* Wq   = (const float*)d_in[4];
    const float* bq   = (const float*)d_in[5];
    const float* Wv   = (const float*)d_in[6];
    const float* bv   = (const float*)d_in[7];
    const float* Wa   = (const float*)d_in[8];
    const float* ba   = (const float*)d_in[9];
    const float* skip = (const float*)d_in[10];
    const float* arel = (const float*)d_in[11];
    const float* mrel = (const float*)d_in[12];
    const float* prel = (const float*)d_in[13];
    const float* Wk_o = (const float*)d_in[14];
    const float* bk_o = (const float*)d_in[15];
    const float* Wq_o = (const float*)d_in[16];
    const float* bq_o = (const float*)d_in[17];
    const float* Wv_o = (const float*)d_in[18];
    const float* bv_o = (const float*)d_in[19];
    const float* Wa_o = (const float*)d_in[20];
    const float* ba_o = (const float*)d_in[21];
    const float* arel_o = (const float*)d_in[22];
    const float* mrel_o = (const float*)d_in[23];
    const float* prel_o = (const float*)d_in[24];
    const float* fc_W  = (const float*)d_in[25];
    const float* fc_b  = (const float*)d_in[26];
    const float* mlp_W1 = (const float*)d_in[27];
    const float* mlp_b1 = (const float*)d_in[28];
    const float* mlp_W2 = (const float*)d_in[29];
    const float* mlp_b2 = (const float*)d_in[30];
    const int* src_cc = (const int*)d_in[31];
    const int* dst_cc = (const int*)d_in[32];
    const int* src_cv = (const int*)d_in[33];
    const int* dst_cv = (const int*)d_in[34];

    // workspace carve-up (256B aligned)
    char* p = (char*)d_ws;
    auto alloc = [&](size_t bytes) -> char* {
        uintptr_t q = ((uintptr_t)p + 255) & ~(uintptr_t)255;
        p = (char*)(q + bytes);
        return (char*)q;
    };
    float* WQT  = (float*)alloc(sizeof(float) * NL * 2 * CH * CH);
    float* BQT  = (float*)alloc(sizeof(float) * NL * 2 * CH);
    float* WVT  = (float*)alloc(sizeof(float) * NL * 2 * CH * CH);
    float* BVT  = (float*)alloc(sizeof(float) * NL * 2 * CH);
    _Float16* WT16 = (_Float16*)alloc(sizeof(_Float16) * NL * 5 * CH * CH);
    float* XC   = (float*)alloc(sizeof(float) * (size_t)N_C * CH);
    float* XV   = (float*)alloc(sizeof(float) * (size_t)N_V * CH);
    float* XQ   = (float*)alloc(sizeof(float) * (size_t)N_C * CH);  // q~ / agg
    unsigned char* KV8 = (unsigned char*)alloc((size_t)N_C * 512);  // k|v_cc , k|v_cv fp8
    float* AGGV = (float*)alloc(sizeof(float) * (size_t)N_V * CH);
    float* KO   = (float*)alloc(sizeof(float) * N_C);
    float* VO   = (float*)alloc(sizeof(float) * N_C);
    float* QO   = (float*)alloc(sizeof(float) * N_V);
    float* OUTS = (float*)alloc(sizeof(float) * NL * N_V);
    // CSR-build scratch (hist region zeroed in one memset)
    int* bhist    = (int*)alloc(sizeof(int) * 512);
    int* bhist_cc = bhist;
    int* bhist_cv = bhist + 256;
    int* bbase_cc = (int*)alloc(sizeof(int) * 257);
    int* cur_cc   = (int*)alloc(sizeof(int) * 256);
    int* cur_cv   = (int*)alloc(sizeof(int) * 256);
    int* rs_cc    = (int*)alloc(sizeof(int) * (N_C + 1));
    int* rs_cv    = (int*)alloc(sizeof(int) * (N_V + 1));
    int* csr_cc   = (int*)alloc(sizeof(int) * NE1);
    int* csr_cv   = (int*)alloc(sizeof(int) * NE2);
    int2* tmp_cc  = (int2*)alloc(sizeof(int2) * NE1);

    // ---- setup: composed weights + fp16 fragment weights + CSR ----
    const int tot_c = NL * 2 * (CH + 1) * CH;
    compose_both<<<CDIV(2 * tot_c, 256), 256, 0, stream>>>(
        Wq, bq, arel, prel, WQT, BQT, Wv, bv, mrel, WVT, BVT);
    cvt_w16<<<CDIV(NL * 5 * CH * CH, 256), 256, 0, stream>>>(WQT, Wk, WVT, Wa, WT16);
    hipMemsetAsync(bhist, 0, sizeof(int) * 512, stream);
    const int nb_cc = CDIV(NE1, EPB), nb_cv = CDIV(NE2, EPB);
    bucket_hist2<<<nb_cc + nb_cv, 256, 0, stream>>>(dst_cc, dst_cv, nb_cc,
                                                    bhist_cc, bhist_cv);
    scan256x2<<<2, 256, 0, stream>>>(bhist_cc, bbase_cc, cur_cc,
                                     bhist_cv, rs_cv, cur_cv);  // rs_cv IS cv row starts
    partition2<<<nb_cc + nb_cv, 256, 0, stream>>>(src_cc, dst_cc, src_cv, dst_cv, nb_cc,
                                                  cur_cc, cur_cv, tmp_cc, csr_cv);
    bucket_finalize<<<CDIV(N_C, 256), 256, 0, stream>>>(tmp_cc, bbase_cc, N_C, NE1,
                                                        rs_cc, csr_cc);

    const int gb_c = CDIV(N_C, 64);             // 938
    const int gb_v = CDIV(N_V, 64);             // 4
    const int ccb = CDIV(N_C, 16);              // 3750 cc blocks
    const int SM_BIG = 32768;

    // ---- layer 0 q~/k/v from x_cell ----
    gemm_qkv<<<gb_c, 256, SM_BIG, stream>>>(
        x_cell, 128, N_C,
        WT16, BQT, bk, BVT, BVT + CH, XQ, KV8);
    attn_uni<<<N_V + ccb, 256, 0, stream>>>(
        XQ, KV8, x_vcell, WQT + (size_t)CH * CH, BQT + CH,
        rs_cc, csr_cc, rs_cv, csr_cv, AGGV, N_C, ccb,
        nullptr, nullptr, nullptr, nullptr, nullptr, nullptr, nullptr, nullptr, nullptr);

    for (int li = 0; li < NL; li++) {
        const float* xc_src = (li == 0) ? x_cell : XC;   // xold for gemm128(li)
        const float* xv_src = (li == 0) ? x_vcell : XV;
        int b0 = (li * 2) * CH, b1 = (li * 2 + 1) * CH;
        size_t w1 = (size_t)(li * 2 + 1) * CH * CH;
        const _Float16* WT_a = WT16 + (size_t)(li * 5 + 4) * CH * CH;
        int do_qkv = (li + 1 < NL) ? 1 : 0;
        const _Float16* WT5n = WT16 + (size_t)((li + 1) % NL * 5) * CH * CH;
        int nb0 = ((li + 1) % NL * 2) * CH, nb1 = ((li + 1) % NL * 2 + 1) * CH;

        // fused: gemm128(li) c-side + v-side; then qkv(li+1) from block-local XC
        gemm_fused<<<gb_c + gb_v, 256, SM_BIG, stream>>>(
            gb_c, do_qkv,
            XQ, WT_a, ba + b0, XC, N_C,
            skip + li * 2, xc_src,
            Wk_o + li * CH, bk_o + li, KO,
            Wv_o + li * CH, bv_o + li, VO,
            WT5n, BQT + nb0, bk + nb0, BVT + nb0, BVT + nb1, XQ, KV8,
            AGGV, 128, Wa + w1, ba + b1, XV, N_V,
            skip + li * 2 + 1, xv_src,
            Wq_o + li * CH, bq_o + li, QO);

        if (do_qkv) {
            // attention for layer li+1, plus out-conv(li) tail -> OUTS[li]
            size_t w1n = (size_t)((li + 1) * 2 + 1) * CH * CH;
            attn_uni<<<N_V + ccb + N_V, 256, 0, stream>>>(
                XQ, KV8, XV, WQT + w1n, BQT + (li + 1) * 2 * CH + CH,
                rs_cc, csr_cc, rs_cv, csr_cv, AGGV, N_C, ccb,
                QO, KO, VO,
                arel_o + li, prel_o + li, mrel_o + li,
                Wa_o + li, ba_o + li, OUTS + li * N_V);
        }
    }

    // last layer's out-conv attention, then final head
    attn_out<<<N_V, 256, 0, stream>>>(QO, KO, VO, rs_cv, csr_cv,
                                      arel_o + (NL - 1), prel_o + (NL - 1), mrel_o + (NL - 1),
                                      Wa_o + (NL - 1), ba_o + (NL - 1), OUTS + (NL - 1) * N_V);
    final_head<<<1, 64, 0, stream>>>(OUTS, fc_W, fc_b, mlp_W1, mlp_b1, mlp_W2, mlp_b2,
                                     (float*)d_out);
}

// Round 11
// 489.737 us; speedup vs baseline: 1.2474x; 1.2474x over previous
//
#include <hip/hip_runtime.h>
#include <hip/hip_fp16.h>
#include <math.h>
#include <stdint.h>

#define N_C 60000
#define N_V 256
#define CH 128
#define NH 4
#define HD 32
#define NL 3
#define NE1 600000
#define NE2 240000

#define CDIV(a,b) (((a)+(b)-1)/(b))
#define EPB 1024   // elems per block in counting-sort kernels

// Node KV record (512 B, stride <<9), fp8-e4m3 storage (math stays f32):
//   bytes [0,256)   : cc view, 16 chunks of 16B: chunk j = { k[8j..8j+8) , v_cc[8j..8j+8) }
//   bytes [256,512) : cv view, chunk j = { k[8j..8j+8) , v_cv[8j..8j+8) }
// gemm weights stored in MFMA FRAGMENT ORDER (see cvt_w16); LDS stage is a
// linear copy; ds_read_b128 at lane*16 is conflict-free. Weight staging uses
// SHORT-LIVED tmp registers (R10's phase-long prefetch spilled to scratch:
// WRITE_SIZE 90->218 MB — do not reintroduce).

typedef _Float16 f16x8 __attribute__((ext_vector_type(8)));
typedef _Float16 f16x4 __attribute__((ext_vector_type(4)));
typedef float f32x4 __attribute__((ext_vector_type(4)));
typedef float f32x2 __attribute__((ext_vector_type(2)));

__device__ __forceinline__ float gelu_tanh(float x) {
    float x3 = x * x * x;
    float t = tanhf(0.7978845608028654f * (x + 0.044715f * x3));
    return 0.5f * x * (1.0f + t);
}

__device__ __forceinline__ void fp8x8_to_f32(uint2 w, float* f) {
    f32x2 a = __builtin_amdgcn_cvt_pk_f32_fp8(w.x, false);
    f32x2 b = __builtin_amdgcn_cvt_pk_f32_fp8(w.x, true);
    f32x2 c = __builtin_amdgcn_cvt_pk_f32_fp8(w.y, false);
    f32x2 d = __builtin_amdgcn_cvt_pk_f32_fp8(w.y, true);
    f[0] = a.x; f[1] = a.y; f[2] = b.x; f[3] = b.y;
    f[4] = c.x; f[5] = c.y; f[6] = d.x; f[7] = d.y;
}

__device__ __forceinline__ float dot8f(const float* q, const float* k) {
    float d = q[0] * k[0];
    d = fmaf(q[1], k[1], d);
    d = fmaf(q[2], k[2], d);
    d = fmaf(q[3], k[3], d);
    d = fmaf(q[4], k[4], d);
    d = fmaf(q[5], k[5], d);
    d = fmaf(q[6], k[6], d);
    d = fmaf(q[7], k[7], d);
    return d;
}

// ---------------- weight composition (Q-side + V-side in one launch) -----------
__global__ __launch_bounds__(256) void compose_both(
    const float* __restrict__ Wq, const float* __restrict__ bq,
    const float* __restrict__ arel, const float* __restrict__ prel,
    float* __restrict__ WQT, float* __restrict__ BQT,
    const float* __restrict__ Wv, const float* __restrict__ bv,
    const float* __restrict__ mrel,
    float* __restrict__ WVT, float* __restrict__ BVT)
{
    const int total = NL * 2 * (CH + 1) * CH;
    int gid = blockIdx.x * blockDim.x + threadIdx.x;
    bool qside = gid < total;
    int g2 = qside ? gid : gid - total;
    if (g2 >= total) return;
    int li2 = g2 / ((CH + 1) * CH);
    int rem = g2 % ((CH + 1) * CH);
    int c   = rem / CH;          // 0..CH ; CH => bias row
    int col = rem % CH;
    int h = col >> 5, low = col & 31;
    const float* rel = qside ? arel : mrel;
    const float* rp;
    int step;
    if (qside) { rp = rel + (li2 * NH + h) * (HD * HD) + low * HD; step = 1; }
    else       { rp = rel + (li2 * NH + h) * (HD * HD) + low;      step = HD; }
    float scale = qside ? prel[li2 * NH + h] * 0.17677669529663687f : 1.f;
    int wsel = qside ? li2 : (li2 & ~1);   // v-side always uses Wv[li][0]
    const float* W    = qside ? Wq : Wv;
    const float* bvec = qside ? bq : bv;
    const float* src = (c < CH) ? (W + ((size_t)wsel * CH + c) * CH + h * HD)
                                : (bvec + wsel * CH + h * HD);
    float acc = 0.f;
    #pragma unroll
    for (int e = 0; e < HD; e++) acc = fmaf(src[e], rp[e * step], acc);
    acc *= scale;
    float* WT = qside ? WQT : WVT;
    float* BT = qside ? BQT : BVT;
    if (c < CH) WT[((size_t)li2 * CH + c) * CH + col] = acc;
    else        BT[li2 * CH + col] = acc;
}

// ---------------- weight fp16 fragment-order emit (one thread per element) -----
// w: 0=WQT(c) 1=Wk(c) 2=WVT_cc 3=WVT_cv 4=Wa(c)
__global__ __launch_bounds__(256) void cvt_w16(
    const float* __restrict__ WQT, const float* __restrict__ Wk,
    const float* __restrict__ WVT, const float* __restrict__ Wa,
    _Float16* __restrict__ WT16)
{
    int gid = blockIdx.x * 256 + threadIdx.x;
    const int PER = CH * CH;
    if (gid >= NL * 5 * PER) return;
    int b = gid / PER, o = gid % PER;
    int li = b / 5, w = b % 5;
    const float* src;
    if      (w == 0) src = WQT + (size_t)(li * 2) * PER;
    else if (w == 1) src = Wk  + (size_t)(li * 2) * PER;
    else if (w == 2) src = WVT + (size_t)(li * 2) * PER;
    else if (w == 3) src = WVT + (size_t)(li * 2 + 1) * PER;
    else             src = Wa  + (size_t)(li * 2) * PER;
    int i = o & 7, lane = (o >> 3) & 63, f = (o >> 9) & 7, kk = o >> 12;
    int mr = lane & 15, g = lane >> 4;
    int k = kk * 32 + g * 8 + i;
    int c = (w < 4) ? (mr * 8 + f) : (f * 16 + mr);
    WT16[gid] = (_Float16)src[k * CH + c];
}

// ================= CSR build (merged cc+cv launches) ==========================
__global__ __launch_bounds__(256) void bucket_hist2(
    const int* __restrict__ dcc, const int* __restrict__ dcv, int nb_cc,
    int* __restrict__ hcc, int* __restrict__ hcv)
{
    __shared__ int h[256];
    bool cv = (int)blockIdx.x >= nb_cc;
    const int* dst = cv ? dcv : dcc;
    int E = cv ? NE2 : NE1;
    int shift = cv ? 0 : 8;
    int* bh = cv ? hcv : hcc;
    int b = cv ? blockIdx.x - nb_cc : blockIdx.x;
    int t = threadIdx.x;
    h[t] = 0;
    __syncthreads();
    int i0 = b * EPB, i1 = min(i0 + EPB, E);
    for (int i = i0 + t; i < i1; i += 256)
        atomicAdd(&h[(dst[i] >> shift) & 255], 1);
    __syncthreads();
    if (h[t] > 0) atomicAdd(&bh[t], h[t]);
}

__global__ __launch_bounds__(256) void scan256x2(
    const int* __restrict__ hcc, int* __restrict__ base_cc, int* __restrict__ cur_cc,
    const int* __restrict__ hcv, int* __restrict__ base_cv, int* __restrict__ cur_cv)
{
    __shared__ int p[256];
    bool cv = blockIdx.x > 0;
    const int* h  = cv ? hcv : hcc;
    int* base     = cv ? base_cv : base_cc;
    int* cur      = cv ? cur_cv : cur_cc;
    int t = threadIdx.x;
    int v = h[t];
    p[t] = v;
    __syncthreads();
    for (int off = 1; off < 256; off <<= 1) {
        int u = (t >= off) ? p[t - off] : 0;
        __syncthreads();
        p[t] += u;
        __syncthreads();
    }
    base[t] = p[t] - v;
    cur[t]  = p[t] - v;
    if (t == 255) base[256] = p[255];
}

__global__ __launch_bounds__(256) void partition2(
    const int* __restrict__ scc, const int* __restrict__ dcc,
    const int* __restrict__ scv, const int* __restrict__ dcv, int nb_cc,
    int* __restrict__ cur_cc, int* __restrict__ cur_cv,
    int2* __restrict__ tmp_pair, int* __restrict__ out_src)
{
    __shared__ int cnt[256], base[256], cnt2[256];
    bool cv = (int)blockIdx.x >= nb_cc;
    const int* src = cv ? scv : scc;
    const int* dst = cv ? dcv : dcc;
    int E = cv ? NE2 : NE1;
    int shift = cv ? 0 : 8;
    int* cur = cv ? cur_cv : cur_cc;
    int b = cv ? blockIdx.x - nb_cc : blockIdx.x;
    int t = threadIdx.x;
    cnt[t] = 0; cnt2[t] = 0;
    __syncthreads();
    int i0 = b * EPB, i1 = min(i0 + EPB, E);
    for (int i = i0 + t; i < i1; i += 256)
        atomicAdd(&cnt[(dst[i] >> shift) & 255], 1);
    __syncthreads();
    if (cnt[t] > 0) base[t] = atomicAdd(&cur[t], cnt[t]);
    __syncthreads();
    for (int i = i0 + t; i < i1; i += 256) {
        int d = dst[i];
        int dig = (d >> shift) & 255;
        int r = atomicAdd(&cnt2[dig], 1);
        int pos = base[dig] + r;
        if (cv) out_src[pos] = src[i];
        else    tmp_pair[pos] = make_int2(src[i], d);
    }
}

__global__ __launch_bounds__(256) void bucket_finalize(
    const int2* __restrict__ tmp, const int* __restrict__ bbase, int n, int NE,
    int* __restrict__ rs, int* __restrict__ csr)
{
    __shared__ int cnt[256], pre[256], cnt2[256];
    int b = blockIdx.x, t = threadIdx.x;
    int s0 = bbase[b], s1 = bbase[b + 1];
    cnt[t] = 0; cnt2[t] = 0;
    __syncthreads();
    for (int i = s0 + t; i < s1; i += 256)
        atomicAdd(&cnt[tmp[i].y & 255], 1);
    __syncthreads();
    int v = cnt[t];
    pre[t] = v;
    __syncthreads();
    for (int off = 1; off < 256; off <<= 1) {
        int u = (t >= off) ? pre[t - off] : 0;
        __syncthreads();
        pre[t] += u;
        __syncthreads();
    }
    pre[t] -= v;   // exclusive
    __syncthreads();
    int dstid = b * 256 + t;
    if (dstid < n) rs[dstid] = s0 + pre[t];
    if (b == 0 && t == 0) rs[n] = NE;
    for (int i = s0 + t; i < s1; i += 256) {
        int2 e = tmp[i];
        int low = e.y & 255;
        int r = atomicAdd(&cnt2[low], 1);
        csr[s0 + pre[low] + r] = e.x;
    }
}

// ---------------- layer-0 MFMA q~/k/v_cc/v_cv GEMM -----------------------------
__global__ __launch_bounds__(256) void gemm_qkv(
    const float* __restrict__ A, int lda, int M,
    const _Float16* __restrict__ WT4,   // 4 matrices, fragment order
    const float* __restrict__ b0, const float* __restrict__ b1,
    const float* __restrict__ b2, const float* __restrict__ b3,
    float* __restrict__ out, unsigned char* __restrict__ kv8)
{
    extern __shared__ char dynsm[];   // 32768 B
    int tid = threadIdx.x;

    _Float16 (*Af)[136] = (_Float16(*)[136])dynsm;   // A-stage view (dead after frags)
    int row0 = blockIdx.x * 64;
    #pragma unroll
    for (int i = 0; i < 8; i++) {
        int slot = tid + i * 256;            // 2048 float4 slots
        int r = slot >> 5, q = slot & 31;
        int rr = row0 + r;
        float4 v = make_float4(0.f, 0.f, 0.f, 0.f);
        if (rr < M) v = *(const float4*)(A + (size_t)rr * lda + q * 4);
        f16x4 h = { (_Float16)v.x, (_Float16)v.y, (_Float16)v.z, (_Float16)v.w };
        *(f16x4*)&Af[r][q * 4] = h;
    }
    __syncthreads();

    int lane = tid & 63, w = tid >> 6;
    int mr = lane & 15, g = lane >> 4;
    f16x8 afr[4];
    #pragma unroll
    for (int kk = 0; kk < 4; kk++)
        afr[kk] = *(const f16x8*)&Af[w * 16 + mr][kk * 32 + g * 8];
    __syncthreads();   // A region now reusable as B buffer

    _Float16* Bl = (_Float16*)dynsm;
    uint4* Blv = (uint4*)dynsm;
    const float* bs[4] = {b0, b1, b2, b3};
    uint2 kp[4];   // packed fp8 k piece per row (carried jw=1 -> jw=2,3)
    for (int jw = 0; jw < 4; jw++) {
        // stage 32 KB fragment-ordered weights: short-lived tmp regs (no spill)
        {
            const uint4* WTv = (const uint4*)(WT4 + (size_t)jw * CH * CH);
            uint4 tmp[8];
            #pragma unroll
            for (int i = 0; i < 8; i++) tmp[i] = WTv[tid + i * 256];
            #pragma unroll
            for (int i = 0; i < 8; i++) Blv[tid + i * 256] = tmp[i];
        }
        __syncthreads();

        f32x4 acc[8] = {};
        #pragma unroll
        for (int kk = 0; kk < 4; kk++) {
            f16x8 bf[8];
            #pragma unroll
            for (int f = 0; f < 8; f++)
                bf[f] = *(const f16x8*)(Bl + (size_t)((kk * 8 + f) * 64 + lane) * 8);
            #pragma unroll
            for (int f = 0; f < 8; f++)
                acc[f] = __builtin_amdgcn_mfma_f32_16x16x32_f16(afr[kk], bf[f], acc[f], 0, 0, 0);
        }
        const float* bb = bs[jw];
        float4 blo = *(const float4*)&bb[mr * 8];
        float4 bhi = *(const float4*)&bb[mr * 8 + 4];
        float bias[8] = {blo.x, blo.y, blo.z, blo.w, bhi.x, bhi.y, bhi.z, bhi.w};
        if (jw == 0) {
            #pragma unroll
            for (int r = 0; r < 4; r++) {
                int row = row0 + w * 16 + g * 4 + r;
                if (row < M) {
                    float4 o0 = make_float4(acc[0][r] + bias[0], acc[1][r] + bias[1],
                                            acc[2][r] + bias[2], acc[3][r] + bias[3]);
                    float4 o1 = make_float4(acc[4][r] + bias[4], acc[5][r] + bias[5],
                                            acc[6][r] + bias[6], acc[7][r] + bias[7]);
                    float* op = out + (size_t)row * 128 + mr * 8;
                    *(float4*)op = o0;
                    *(float4*)(op + 4) = o1;
                }
            }
        } else {
            #pragma unroll
            for (int r = 0; r < 4; r++) {
                float v0 = acc[0][r] + bias[0], v1 = acc[1][r] + bias[1];
                float v2 = acc[2][r] + bias[2], v3 = acc[3][r] + bias[3];
                float v4 = acc[4][r] + bias[4], v5 = acc[5][r] + bias[5];
                float v6 = acc[6][r] + bias[6], v7 = acc[7][r] + bias[7];
                unsigned int lo = (unsigned)__builtin_amdgcn_cvt_pk_fp8_f32(v0, v1, 0, false);
                lo = (unsigned)__builtin_amdgcn_cvt_pk_fp8_f32(v2, v3, (int)lo, true);
                unsigned int hi = (unsigned)__builtin_amdgcn_cvt_pk_fp8_f32(v4, v5, 0, false);
                hi = (unsigned)__builtin_amdgcn_cvt_pk_fp8_f32(v6, v7, (int)hi, true);
                if (jw == 1) {
                    kp[r] = make_uint2(lo, hi);
                } else {
                    int row = row0 + w * 16 + g * 4 + r;
                    if (row < M) {
                        unsigned char* base = kv8 + ((size_t)row << 9) + mr * 16
                                            + ((jw == 3) ? 256 : 0);
                        *(uint4*)base = make_uint4(kp[r].x, kp[r].y, lo, hi);
                    }
                }
            }
        }
        __syncthreads();   // B buffer reused next jw
    }
}

// ---------------- FUSED: gemm128(li) c-side + gemm_qkv(li+1); v-side tail ------
__global__ __launch_bounds__(256) void gemm_fused(
    int nblk1, int do_qkv,
    // c-side gemm128 (layer li)
    const float* __restrict__ A1, const _Float16* __restrict__ Wa_h,
    const float* __restrict__ bias1, float* __restrict__ xc_out, int M,
    const float* __restrict__ gate1, const float* __restrict__ xold1,
    const float* __restrict__ wk1, const float* __restrict__ bk1, float* __restrict__ ko1,
    const float* __restrict__ wv1, const float* __restrict__ bv1, float* __restrict__ vo1,
    // qkv of layer li+1 (ignored when do_qkv == 0)
    const _Float16* __restrict__ WT4,
    const float* __restrict__ qb0, const float* __restrict__ qb1,
    const float* __restrict__ qb2, const float* __restrict__ qb3,
    float* __restrict__ xq_out, unsigned char* __restrict__ kv8,
    // v-side gemm128 (layer li)
    const float* __restrict__ A2, int lda2, const float* __restrict__ W2,
    const float* __restrict__ bias2, float* __restrict__ out2, int M2,
    const float* __restrict__ gate2, const float* __restrict__ xold2,
    const float* __restrict__ wk2, const float* __restrict__ bk2, float* __restrict__ ko2)
{
    extern __shared__ char dynsm[];
    int tid = threadIdx.x;

    if ((int)blockIdx.x >= nblk1) {
        // ======================= v-side: fp32 vector =======================
        float (*As)[36]  = (float(*)[36])dynsm;                 // 9216 B
        float (*Bs)[128] = (float(*)[128])(dynsm + 64 * 36 * 4); // 16384 B
        int row0 = (blockIdx.x - nblk1) * 64;
        int tx = tid & 15;
        int ty = tid >> 4;
        float acc[4][8] = {};
        for (int k0 = 0; k0 < 128; k0 += 32) {
            __syncthreads();
            #pragma unroll
            for (int i = 0; i < 2; i++) {
                int slot = tid + i * 256;            // [0,512) float4 slots
                int r = slot >> 3, kq = slot & 7;
                int rr = row0 + r;
                float4 v = make_float4(0.f, 0.f, 0.f, 0.f);
                if (rr < M2) v = *(const float4*)(A2 + (size_t)rr * lda2 + k0 + kq * 4);
                *(float4*)&As[r][kq * 4] = v;
            }
            #pragma unroll
            for (int i = 0; i < 4; i++) {
                int slot = tid + i * 256;            // [0,1024)
                int kr = slot >> 5, cq = slot & 31;
                *(float4*)&Bs[kr][cq * 4] = *(const float4*)(W2 + (size_t)(k0 + kr) * 128 + cq * 4);
            }
            __syncthreads();
            #pragma unroll
            for (int k4 = 0; k4 < 32; k4 += 4) {
                float4 av[4];
                #pragma unroll
                for (int i = 0; i < 4; i++)
                    av[i] = *(const float4*)&As[ty * 4 + i][k4];
                #pragma unroll
                for (int kk = 0; kk < 4; kk++) {
                    float4 bl = *(const float4*)&Bs[k4 + kk][tx * 4];
                    float4 bh = *(const float4*)&Bs[k4 + kk][64 + tx * 4];
                    float bb[8] = {bl.x, bl.y, bl.z, bl.w, bh.x, bh.y, bh.z, bh.w};
                    #pragma unroll
                    for (int i = 0; i < 4; i++) {
                        float a = ((const float*)&av[i])[kk];
                        #pragma unroll
                        for (int j = 0; j < 8; j++)
                            acc[i][j] = fmaf(a, bb[j], acc[i][j]);
                    }
                }
            }
        }
        float gt = 1.f / (1.f + expf(-gate2[0]));
        float og = 1.f - gt;
        float wkr[8];
        #pragma unroll
        for (int j = 0; j < 4; j++) {
            wkr[j]     = wk2[tx * 4 + j];
            wkr[4 + j] = wk2[64 + tx * 4 + j];
        }
        #pragma unroll
        for (int i = 0; i < 4; i++) {
            int r = row0 + ty * 4 + i;
            if (r >= M2) continue;   // uniform across each 16-lane group
            float vals[8];
            #pragma unroll
            for (int j = 0; j < 4; j++) {
                float v0 = acc[i][j]     + bias2[tx * 4 + j];
                float v1 = acc[i][4 + j] + bias2[64 + tx * 4 + j];
                v0 = gt * v0 + og * xold2[(size_t)r * 128 + tx * 4 + j];
                v1 = gt * v1 + og * xold2[(size_t)r * 128 + 64 + tx * 4 + j];
                vals[j] = v0;
                vals[4 + j] = v1;
            }
            float* op = out2 + (size_t)r * 128;
            *(float4*)(op + tx * 4)      = make_float4(vals[0], vals[1], vals[2], vals[3]);
            *(float4*)(op + 64 + tx * 4) = make_float4(vals[4], vals[5], vals[6], vals[7]);
            float pk = 0.f;
            #pragma unroll
            for (int j = 0; j < 8; j++) pk = fmaf(vals[j], wkr[j], pk);
            #pragma unroll
            for (int off = 1; off < 16; off <<= 1)
                pk += __shfl_xor(pk, off, 64);
            if (tx == 0) ko2[r] = pk + bk2[0];
        }
        return;
    }

    // ======================= c-side: gemm128 MFMA then qkv =======================
    _Float16 (*Af)[136] = (_Float16(*)[136])dynsm;
    int row0 = blockIdx.x * 64;
    #pragma unroll
    for (int i = 0; i < 8; i++) {
        int slot = tid + i * 256;
        int r = slot >> 5, q = slot & 31;
        int rr = row0 + r;
        float4 v = make_float4(0.f, 0.f, 0.f, 0.f);
        if (rr < M) v = *(const float4*)(A1 + (size_t)rr * 128 + q * 4);
        f16x4 h = { (_Float16)v.x, (_Float16)v.y, (_Float16)v.z, (_Float16)v.w };
        *(f16x4*)&Af[r][q * 4] = h;
    }
    __syncthreads();

    int lane = tid & 63, w = tid >> 6;
    int mr = lane & 15, g = lane >> 4;
    f16x8 afr[4];
    #pragma unroll
    for (int kk = 0; kk < 4; kk++)
        afr[kk] = *(const f16x8*)&Af[w * 16 + mr][kk * 32 + g * 8];
    __syncthreads();   // A region -> B buffer

    _Float16* Bl = (_Float16*)dynsm;
    uint4* Blv = (uint4*)dynsm;
    {
        const uint4* WTv = (const uint4*)Wa_h;
        uint4 tmp[8];
        #pragma unroll
        for (int i = 0; i < 8; i++) tmp[i] = WTv[tid + i * 256];
        #pragma unroll
        for (int i = 0; i < 8; i++) Blv[tid + i * 256] = tmp[i];
    }
    __syncthreads();

    f32x4 acc[8] = {};
    #pragma unroll
    for (int kk = 0; kk < 4; kk++) {
        f16x8 bf[8];
        #pragma unroll
        for (int f = 0; f < 8; f++)
            bf[f] = *(const f16x8*)(Bl + (size_t)((kk * 8 + f) * 64 + lane) * 8);
        #pragma unroll
        for (int f = 0; f < 8; f++)
            acc[f] = __builtin_amdgcn_mfma_f32_16x16x32_f16(afr[kk], bf[f], acc[f], 0, 0, 0);
    }
    __syncthreads();   // all B reads done; LDS free for phase 2

    float gt = 1.f / (1.f + expf(-gate1[0]));
    float og = 1.f - gt;
    float vals[8][4];
    float pk[4] = {}, pv[4] = {};
    #pragma unroll
    for (int f = 0; f < 8; f++) {
        int col = f * 16 + mr;
        float bias = bias1[col];
        float wkc = wk1[col];
        float wvc = wv1[col];
        #pragma unroll
        for (int r = 0; r < 4; r++) {
            int row = row0 + w * 16 + g * 4 + r;
            float v = 0.f;
            if (row < M) {
                v = acc[f][r] + bias;
                v = gt * v + og * xold1[(size_t)row * 128 + col];
                xc_out[(size_t)row * 128 + col] = v;
                pk[r] = fmaf(v, wkc, pk[r]);
                pv[r] = fmaf(v, wvc, pv[r]);
            }
            vals[f][r] = v;
        }
    }
    #pragma unroll
    for (int r = 0; r < 4; r++) {
        #pragma unroll
        for (int off = 1; off < 16; off <<= 1) {
            pk[r] += __shfl_xor(pk[r], off, 64);
            pv[r] += __shfl_xor(pv[r], off, 64);
        }
    }
    if (mr == 0) {
        #pragma unroll
        for (int r = 0; r < 4; r++) {
            int row = row0 + w * 16 + g * 4 + r;
            if (row < M) {
                ko1[row] = pk[r] + bk1[0];
                vo1[row] = pv[r] + bv1[0];
            }
        }
    }

    if (!do_qkv) return;

    // -------- phase 2: next-layer q~/k/v_cc/v_cv from the block-local XC tile ---
    #pragma unroll
    for (int f = 0; f < 8; f++) {
        int col = f * 16 + mr;
        #pragma unroll
        for (int r = 0; r < 4; r++)
            Af[w * 16 + g * 4 + r][col] = (_Float16)vals[f][r];
    }
    __syncthreads();
    f16x8 afr2[4];
    #pragma unroll
    for (int kk = 0; kk < 4; kk++)
        afr2[kk] = *(const f16x8*)&Af[w * 16 + mr][kk * 32 + g * 8];
    __syncthreads();

    const float* bs[4] = {qb0, qb1, qb2, qb3};
    uint2 kp[4];
    for (int jw = 0; jw < 4; jw++) {
        {
            const uint4* WTv = (const uint4*)(WT4 + (size_t)jw * CH * CH);
            uint4 tmp[8];
            #pragma unroll
            for (int i = 0; i < 8; i++) tmp[i] = WTv[tid + i * 256];
            #pragma unroll
            for (int i = 0; i < 8; i++) Blv[tid + i * 256] = tmp[i];
        }
        __syncthreads();

        f32x4 acc2[8] = {};
        #pragma unroll
        for (int kk = 0; kk < 4; kk++) {
            f16x8 bf[8];
            #pragma unroll
            for (int f = 0; f < 8; f++)
                bf[f] = *(const f16x8*)(Bl + (size_t)((kk * 8 + f) * 64 + lane) * 8);
            #pragma unroll
            for (int f = 0; f < 8; f++)
                acc2[f] = __builtin_amdgcn_mfma_f32_16x16x32_f16(afr2[kk], bf[f], acc2[f], 0, 0, 0);
        }
        const float* bb = bs[jw];
        float4 blo = *(const float4*)&bb[mr * 8];
        float4 bhi = *(const float4*)&bb[mr * 8 + 4];
        float bias[8] = {blo.x, blo.y, blo.z, blo.w, bhi.x, bhi.y, bhi.z, bhi.w};
        if (jw == 0) {
            #pragma unroll
            for (int r = 0; r < 4; r++) {
                int row = row0 + w * 16 + g * 4 + r;
                if (row < M) {
                    float4 o0 = make_float4(acc2[0][r] + bias[0], acc2[1][r] + bias[1],
                                            acc2[2][r] + bias[2], acc2[3][r] + bias[3]);
                    float4 o1 = make_float4(acc2[4][r] + bias[4], acc2[5][r] + bias[5],
                                            acc2[6][r] + bias[6], acc2[7][r] + bias[7]);
                    float* op = xq_out + (size_t)row * 128 + mr * 8;
                    *(float4*)op = o0;
                    *(float4*)(op + 4) = o1;
                }
            }
        } else {
            #pragma unroll
            for (int r = 0; r < 4; r++) {
                float v0 = acc2[0][r] + bias[0], v1 = acc2[1][r] + bias[1];
                float v2 = acc2[2][r] + bias[2], v3 = acc2[3][r] + bias[3];
                float v4 = acc2[4][r] + bias[4], v5 = acc2[5][r] + bias[5];
                float v6 = acc2[6][r] + bias[6], v7 = acc2[7][r] + bias[7];
                unsigned int lo = (unsigned)__builtin_amdgcn_cvt_pk_fp8_f32(v0, v1, 0, false);
                lo = (unsigned)__builtin_amdgcn_cvt_pk_fp8_f32(v2, v3, (int)lo, true);
                unsigned int hi = (unsigned)__builtin_amdgcn_cvt_pk_fp8_f32(v4, v5, 0, false);
                hi = (unsigned)__builtin_amdgcn_cvt_pk_fp8_f32(v6, v7, (int)hi, true);
                if (jw == 1) {
                    kp[r] = make_uint2(lo, hi);
                } else {
                    int row = row0 + w * 16 + g * 4 + r;
                    if (row < M) {
                        unsigned char* base = kv8 + ((size_t)row << 9) + mr * 16
                                            + ((jw == 3) ? 256 : 0);
                        *(uint4*)base = make_uint4(kp[r].x, kp[r].y, lo, hi);
                    }
                }
            }
        }
        __syncthreads();
    }
}

// ---------------- cv gather: 4 groups on one node, 64-edge chunks --------------
__device__ __forceinline__ void gather_cv(
    const unsigned char* __restrict__ kv8, const int* __restrict__ csr,
    int e0, int e1, int g, int j, const float* q8,
    float& s_io, float acc[8])
{
    int lane = threadIdx.x & 63;
    float s = s_io;
    for (int cs = e0; cs < e1; cs += 64) {
        int n = e1 - cs; if (n > 64) n = 64;
        int nm1 = n - 1;
        int idx0 = 0;
        if (lane < n) idx0 = csr[cs + lane];
        int R = (n + 7) >> 3;
        uint4 a0, a1, b0, b1;

#define LD2(E0_, E1_, B0_, B1_) { \
            int i0_ = __shfl(idx0, min((E0_), nm1), 64); \
            int i1_ = __shfl(idx0, min((E1_), nm1), 64); \
            B0_ = *(const uint4*)(kv8 + ((size_t)i0_ << 9) + 256 + (j << 4)); \
            B1_ = *(const uint4*)(kv8 + ((size_t)i1_ << 9) + 256 + (j << 4)); }

#define CMP2(E0_, E1_, B0_, B1_) { \
            float k0f[8], k1f[8], v0f[8], v1f[8]; \
            fp8x8_to_f32(make_uint2(B0_.x, B0_.y), k0f); \
            fp8x8_to_f32(make_uint2(B1_.x, B1_.y), k1f); \
            float d0_ = dot8f(q8, k0f); \
            float d1_ = dot8f(q8, k1f); \
            d0_ += __shfl_xor(d0_, 1, 64); d1_ += __shfl_xor(d1_, 1, 64); \
            d0_ += __shfl_xor(d0_, 2, 64); d1_ += __shfl_xor(d1_, 2, 64); \
            float w0_ = ((E0_) < n) ? __expf(d0_) : 0.f; \
            float w1_ = ((E1_) < n) ? __expf(d1_) : 0.f; \
            s += w0_ + w1_; \
            fp8x8_to_f32(make_uint2(B0_.z, B0_.w), v0f); \
            fp8x8_to_f32(make_uint2(B1_.z, B1_.w), v1f); \
            acc[0] = fmaf(w0_, v0f[0], acc[0]); acc[0] = fmaf(w1_, v1f[0], acc[0]); \
            acc[1] = fmaf(w0_, v0f[1], acc[1]); acc[1] = fmaf(w1_, v1f[1], acc[1]); \
            acc[2] = fmaf(w0_, v0f[2], acc[2]); acc[2] = fmaf(w1_, v1f[2], acc[2]); \
            acc[3] = fmaf(w0_, v0f[3], acc[3]); acc[3] = fmaf(w1_, v1f[3], acc[3]); \
            acc[4] = fmaf(w0_, v0f[4], acc[4]); acc[4] = fmaf(w1_, v1f[4], acc[4]); \
            acc[5] = fmaf(w0_, v0f[5], acc[5]); acc[5] = fmaf(w1_, v1f[5], acc[5]); \
            acc[6] = fmaf(w0_, v0f[6], acc[6]); acc[6] = fmaf(w1_, v1f[6], acc[6]); \
            acc[7] = fmaf(w0_, v0f[7], acc[7]); acc[7] = fmaf(w1_, v1f[7], acc[7]); }

        LD2(g, g + 4, a0, a1);
        if (R > 1) LD2(g + 8, g + 12, b0, b1);
        for (int r = 0; r < R; r += 2) {
            int er = g + 8 * r;
            CMP2(er, er + 4, a0, a1);
            if (r + 2 < R) LD2(g + 8 * (r + 2), g + 8 * (r + 2) + 4, a0, a1);
            if (r + 1 < R) {
                int eo = g + 8 * (r + 1);
                CMP2(eo, eo + 4, b0, b1);
                if (r + 3 < R) LD2(g + 8 * (r + 3), g + 8 * (r + 3) + 4, b0, b1);
            }
        }
#undef LD2
#undef CMP2
    }
    s_io = s;
}

// ---------------- unified attention: cv | cc | prev-layer out-conv tail --------
__global__ __launch_bounds__(256) void attn_uni(
    float* __restrict__ xq, const unsigned char* __restrict__ kv8,
    const float* __restrict__ xv, const float* __restrict__ wqt,
    const float* __restrict__ bqt,
    const int* __restrict__ rs_cc, const int* __restrict__ csr_cc,
    const int* __restrict__ rs_cv, const int* __restrict__ csr_cv,
    float* __restrict__ aggv, int n_c, int ccb,
    // out-conv tail (prev layer); only when grid extends past N_V+ccb
    const float* __restrict__ qo, const float* __restrict__ ko,
    const float* __restrict__ vo,
    const float* __restrict__ arel_o, const float* __restrict__ prel_o,
    const float* __restrict__ mrel_o, const float* __restrict__ Wa_o,
    const float* __restrict__ ba_o, float* __restrict__ outl)
{
    __shared__ float smem[656];
    int lane = threadIdx.x & 63, wid = threadIdx.x >> 6;
    int g = lane >> 4, j = lane & 15;

    if (blockIdx.x < N_V) {
        // ---------------- cv node (4 waves, 4 groups each) ----------------
        int node = blockIdx.x;
        float* qrow = smem;          // [128]
        float* sm_s = smem + 128;    // [4][4]
        float* sm_a = smem + 144;    // [4][128]
        if (wid < 2) {
            int col = wid * 64 + lane;
            float a = bqt[col];
            const float* xr = xv + (size_t)node * 128;
            for (int k = 0; k < 128; k++)
                a = fmaf(xr[k], wqt[(size_t)k * 128 + col], a);
            qrow[col] = a;
        }
        __syncthreads();
        float q8[8];
        *(float4*)&q8[0] = *(const float4*)&qrow[8 * j];
        *(float4*)&q8[4] = *(const float4*)&qrow[8 * j + 4];
        int rs = rs_cv[node], re = rs_cv[node + 1];
        int cnt = re - rs;
        int per = (cnt + 3) >> 2;
        int e0 = rs + wid * per, e1 = min(e0 + per, re);
        float s = 0.f;
        float acc[8] = {};
        gather_cv(kv8, csr_cv, e0, e1, g, j, q8, s, acc);
        #pragma unroll
        for (int i = 0; i < 8; i++) {
            acc[i] += __shfl_xor(acc[i], 16, 64);
            acc[i] += __shfl_xor(acc[i], 32, 64);
        }
        s += __shfl_xor(s, 16, 64);
        s += __shfl_xor(s, 32, 64);
        if (g == 0) {
            *(float4*)&sm_a[wid * 128 + 8 * j]     = make_float4(acc[0], acc[1], acc[2], acc[3]);
            *(float4*)&sm_a[wid * 128 + 8 * j + 4] = make_float4(acc[4], acc[5], acc[6], acc[7]);
            if ((j & 3) == 0) sm_s[wid * 4 + (j >> 2)] = s;
        }
        __syncthreads();
        if (threadIdx.x < 64) {
            int lp = 2 * lane;
            int h = lp >> 5;
            float S = 0.f, AX = 0.f, AY = 0.f;
            #pragma unroll
            for (int i = 0; i < 4; i++) {
                S  += sm_s[i * 4 + h];
                float2 a2 = *(const float2*)&sm_a[i * 128 + lp];
                AX += a2.x;
                AY += a2.y;
            }
            float inv = (S > 0.f) ? 1.f / S : 0.f;
            aggv[(size_t)node * 128 + lp]     = gelu_tanh(AX * inv);
            aggv[(size_t)node * 128 + lp + 1] = gelu_tanh(AY * inv);
        }
    } else if ((int)blockIdx.x < N_V + ccb) {
        // ---------------- cc: one node per 16-lane group ----------------
        int node = (blockIdx.x - N_V) * 16 + wid * 4 + g;
        bool valid = (node < n_c);
        int rs = valid ? rs_cc[node] : 0;
        int re = valid ? rs_cc[node + 1] : 0;
        float q8[8];
        if (valid) {
            const float* qp = xq + (size_t)node * 128 + 8 * j;
            *(float4*)&q8[0] = *(const float4*)qp;
            *(float4*)&q8[4] = *(const float4*)(qp + 4);
        } else {
            #pragma unroll
            for (int i = 0; i < 8; i++) q8[i] = 0.f;
        }
        float s = 0.f;
        float acc[8] = {};
        int base = lane & 48;

        for (int cs = rs; cs < re; cs += 16) {
            int cnt = min(16, re - cs);
            int cm1 = cnt - 1;
            int idx = csr_cc[cs + min(j, cm1)];
            uint4 B0, B1, B2, B3;

#define LDE(E_, B_) { int i_ = __shfl(idx, base + min((E_), cm1), 64); \
            B_ = *(const uint4*)(kv8 + ((size_t)i_ << 9) + (j << 4)); }
#define CMPE(E_, B_) { float kf[8], vf[8]; \
            fp8x8_to_f32(make_uint2(B_.x, B_.y), kf); \
            float d_ = dot8f(q8, kf); \
            d_ += __shfl_xor(d_, 1, 64); d_ += __shfl_xor(d_, 2, 64); \
            float w_ = ((E_) < cnt) ? __expf(d_) : 0.f; \
            s += w_; \
            fp8x8_to_f32(make_uint2(B_.z, B_.w), vf); \
            acc[0] = fmaf(w_, vf[0], acc[0]); \
            acc[1] = fmaf(w_, vf[1], acc[1]); \
            acc[2] = fmaf(w_, vf[2], acc[2]); \
            acc[3] = fmaf(w_, vf[3], acc[3]); \
            acc[4] = fmaf(w_, vf[4], acc[4]); \
            acc[5] = fmaf(w_, vf[5], acc[5]); \
            acc[6] = fmaf(w_, vf[6], acc[6]); \
            acc[7] = fmaf(w_, vf[7], acc[7]); }

            LDE(0, B0) LDE(1, B1) LDE(2, B2) LDE(3, B3)
            CMPE(0, B0) CMPE(1, B1)
            if (cnt > 4) { LDE(4, B0) LDE(5, B1) }
            CMPE(2, B2) CMPE(3, B3)
            if (cnt > 6) { LDE(6, B2) LDE(7, B3) }
            if (cnt > 4) {
                CMPE(4, B0) CMPE(5, B1)
                if (cnt > 8) { LDE(8, B0) LDE(9, B1) }
                CMPE(6, B2) CMPE(7, B3)
                if (cnt > 10) { LDE(10, B2) LDE(11, B3) }
                if (cnt > 8) {
                    CMPE(8, B0) CMPE(9, B1)
                    if (cnt > 12) { LDE(12, B0) LDE(13, B1) }
                    CMPE(10, B2) CMPE(11, B3)
                    if (cnt > 14) { LDE(14, B2) LDE(15, B3) }
                    if (cnt > 12) {
                        CMPE(12, B0) CMPE(13, B1) CMPE(14, B2) CMPE(15, B3)
                    }
                }
            }
#undef LDE
#undef CMPE
        }
        if (valid) {
            float inv = (s > 0.f) ? 1.f / s : 0.f;
            float4 o0 = make_float4(gelu_tanh(acc[0] * inv), gelu_tanh(acc[1] * inv),
                                    gelu_tanh(acc[2] * inv), gelu_tanh(acc[3] * inv));
            float4 o1 = make_float4(gelu_tanh(acc[4] * inv), gelu_tanh(acc[5] * inv),
                                    gelu_tanh(acc[6] * inv), gelu_tanh(acc[7] * inv));
            float* op = xq + (size_t)node * 128 + 8 * j;
            *(float4*)op = o0;
            *(float4*)(op + 4) = o1;
        }
    } else {
        // ---------------- prev-layer out-conv scalar attention ----------------
        int node = blockIdx.x - N_V - ccb;
        float* sms = smem;       // [4]
        float* sma = smem + 4;   // [4]
        float qs = qo[node] * arel_o[0] * prel_o[0];
        int rs = rs_cv[node], re = rs_cv[node + 1];
        float s = 0.f, a = 0.f;
        for (int e = rs + (int)threadIdx.x; e < re; e += 256) {
            int si = csr_cv[e];
            float w = __expf(qs * ko[si]);
            s += w;
            a = fmaf(w, vo[si], a);
        }
        #pragma unroll
        for (int off = 32; off >= 1; off >>= 1) {
            s += __shfl_xor(s, off, 64);
            a += __shfl_xor(a, off, 64);
        }
        if (lane == 0) { sms[wid] = s; sma[wid] = a; }
        __syncthreads();
        if (threadIdx.x == 0) {
            float S = sms[0] + sms[1] + sms[2] + sms[3];
            float A = sma[0] + sma[1] + sma[2] + sma[3];
            float agg = (S > 0.f) ? A / S : 0.f;
            agg *= mrel_o[0];
            outl[node] = gelu_tanh(agg) * Wa_o[0] + ba_o[0];
        }
    }
}

// ---------------- out-conv scalar attention (standalone, last layer) -----------
__global__ __launch_bounds__(256) void attn_out(
    const float* __restrict__ qo, const float* __restrict__ ko, const float* __restrict__ vo,
    const int* __restrict__ rowstart, const int* __restrict__ csr,
    const float* __restrict__ arel_o, const float* __restrict__ prel_o,
    const float* __restrict__ mrel_o, const float* __restrict__ Wa_o,
    const float* __restrict__ ba_o, float* __restrict__ outl)
{
    int node = blockIdx.x;
    float qs = qo[node] * arel_o[0] * prel_o[0];
    int rs = rowstart[node], re = rowstart[node + 1];
    float s = 0.f, a = 0.f;
    for (int e = rs + (int)threadIdx.x; e < re; e += 256) {
        int si = csr[e];
        float w = __expf(qs * ko[si]);
        s += w;
        a = fmaf(w, vo[si], a);
    }
    #pragma unroll
    for (int off = 32; off >= 1; off >>= 1) {
        s += __shfl_xor(s, off, 64);
        a += __shfl_xor(a, off, 64);
    }
    __shared__ float sms[4], sma[4];
    int lane = threadIdx.x & 63, wid = threadIdx.x >> 6;
    if (lane == 0) { sms[wid] = s; sma[wid] = a; }
    __syncthreads();
    if (threadIdx.x == 0) {
        float S = sms[0] + sms[1] + sms[2] + sms[3];
        float A = sma[0] + sma[1] + sma[2] + sma[3];
        float agg = (S > 0.f) ? A / S : 0.f;
        agg *= mrel_o[0];
        outl[node] = gelu_tanh(agg) * Wa_o[0] + ba_o[0];
    }
}

// ---------------- final head: JK-max -> node_fc -> MLP ------------------------
__global__ void final_head(const float* __restrict__ outs,
    const float* __restrict__ fc_W, const float* __restrict__ fc_b,
    const float* __restrict__ W1, const float* __restrict__ b1,
    const float* __restrict__ W2, const float* __restrict__ b2,
    float* __restrict__ out)
{
    int b = threadIdx.x;
    if (b >= 64) return;
    float h = fc_b[0];
    #pragma unroll
    for (int v = 0; v < 4; v++) {
        int n = b * 4 + v;
        float jk = fmaxf(fmaxf(outs[0 * N_V + n], outs[1 * N_V + n]), outs[2 * N_V + n]);
        h = fmaf(jk, fc_W[v], h);
    }
    h = gelu_tanh(h);
    float h0 = gelu_tanh(h * W1[0] + b1[0]);
    float h1 = gelu_tanh(h * W1[1] + b1[1]);
    out[b] = h0 * W2[0] + h1 * W2[1] + b2[0];
}

// ---------------- orchestration ----------------------------------------------
extern "C" void kernel_launch(void* const* d_in, const int* in_sizes, int n_in,
                              void* d_out, int out_size, void* d_ws, size_t ws_size,
                              hipStream_t stream) {
    (void)in_sizes; (void)n_in; (void)out_size; (void)ws_size;
    const float* x_cell  = (const float*)d_in[0];
    const float* x_vcell = (const float*)d_in[1];
    const float* Wk   = (const float*)d_in[2];
    const float* bk   = (const float*)d_in[3];
    const float* Wq   = (const float*)d_in[4];
    const float* bq   = (const float*)d_in[5];
    const float* Wv   = (const float*)d_in[6];
    const float* bv   = (const float*)d_in[7];
    const float* Wa   = (const float*)d_in[8];
    const float* ba   = (const float*)d_in[9];
    const float* skip = (const float*)d_in[10];
    const float* arel = (const float*)d_in[11];
    const float* mrel = (const float*)d_in[12];
    const float* prel = (const float*)d_in[13];
    const float* Wk_o = (const float*)d_in[14];
    const float* bk_o = (const float*)d_in[15];
    const float* Wq_o = (const float*)d_in[16];
    const float* bq_o = (const float*)d_in[17];
    const float* Wv_o = (const float*)d_in[18];
    const float* bv_o = (const float*)d_in[19];
    const float* Wa_o = (const float*)d_in[20];
    const float* ba_o = (const float*)d_in[21];
    const float* arel_o = (const float*)d_in[22];
    const float* mrel_o = (const float*)d_in[23];
    const float* prel_o = (const float*)d_in[24];
    const float* fc_W  = (const float*)d_in[25];
    const float* fc_b  = (const float*)d_in[26];
    const float* mlp_W1 = (const float*)d_in[27];
    const float* mlp_b1 = (const float*)d_in[28];
    const float* mlp_W2 = (const float*)d_in[29];
    const float* mlp_b2 = (const float*)d_in[30];
    const int* src_cc = (const int*)d_in[31];
    const int* dst_cc = (const int*)d_in[32];
    const int* src_cv = (const int*)d_in[33];
    const int* dst_cv = (const int*)d_in[34];

    // workspace carve-up (256B aligned)
    char* p = (char*)d_ws;
    auto alloc = [&](size_t bytes) -> char* {
        uintptr_t q = ((uintptr_t)p + 255) & ~(uintptr_t)255;
        p = (char*)(q + bytes);
        return (char*)q;
    };
    float* WQT  = (float*)alloc(sizeof(float) * NL * 2 * CH * CH);
    float* BQT  = (float*)alloc(sizeof(float) * NL * 2 * CH);
    float* WVT  = (float*)alloc(sizeof(float) * NL * 2 * CH * CH);
    float* BVT  = (float*)alloc(sizeof(float) * NL * 2 * CH);
    _Float16* WT16 = (_Float16*)alloc(sizeof(_Float16) * NL * 5 * CH * CH);
    float* XC   = (float*)alloc(sizeof(float) * (size_t)N_C * CH);
    float* XV   = (float*)alloc(sizeof(float) * (size_t)N_V * CH);
    float* XQ   = (float*)alloc(sizeof(float) * (size_t)N_C * CH);  // q~ / agg
    unsigned char* KV8 = (unsigned char*)alloc((size_t)N_C * 512);  // k|v_cc , k|v_cv fp8
    float* AGGV = (float*)alloc(sizeof(float) * (size_t)N_V * CH);
    float* KO   = (float*)alloc(sizeof(float) * N_C);
    float* VO   = (float*)alloc(sizeof(float) * N_C);
    float* QO   = (float*)alloc(sizeof(float) * N_V);
    float* OUTS = (float*)alloc(sizeof(float) * NL * N_V);
    // CSR-build scratch (hist region zeroed in one memset)
    int* bhist    = (int*)alloc(sizeof(int) * 512);
    int* bhist_cc = bhist;
    int* bhist_cv = bhist + 256;
    int* bbase_cc = (int*)alloc(sizeof(int) * 257);
    int* cur_cc   = (int*)alloc(sizeof(int) * 256);
    int* cur_cv   = (int*)alloc(sizeof(int) * 256);
    int* rs_cc    = (int*)alloc(sizeof(int) * (N_C + 1));
    int* rs_cv    = (int*)alloc(sizeof(int) * (N_V + 1));
    int* csr_cc   = (int*)alloc(sizeof(int) * NE1);
    int* csr_cv   = (int*)alloc(sizeof(int) * NE2);
    int2* tmp_cc  = (int2*)alloc(sizeof(int2) * NE1);

    // ---- setup: composed weights + fp16 fragment weights + CSR ----
    const int tot_c = NL * 2 * (CH + 1) * CH;
    compose_both<<<CDIV(2 * tot_c, 256), 256, 0, stream>>>(
        Wq, bq, arel, prel, WQT, BQT, Wv, bv, mrel, WVT, BVT);
    cvt_w16<<<CDIV(NL * 5 * CH * CH, 256), 256, 0, stream>>>(WQT, Wk, WVT, Wa, WT16);
    hipMemsetAsync(bhist, 0, sizeof(int) * 512, stream);
    const int nb_cc = CDIV(NE1, EPB), nb_cv = CDIV(NE2, EPB);
    bucket_hist2<<<nb_cc + nb_cv, 256, 0, stream>>>(dst_cc, dst_cv, nb_cc,
                                                    bhist_cc, bhist_cv);
    scan256x2<<<2, 256, 0, stream>>>(bhist_cc, bbase_cc, cur_cc,
                                     bhist_cv, rs_cv, cur_cv);  // rs_cv IS cv row starts
    partition2<<<nb_cc + nb_cv, 256, 0, stream>>>(src_cc, dst_cc, src_cv, dst_cv, nb_cc,
                                                  cur_cc, cur_cv, tmp_cc, csr_cv);
    bucket_finalize<<<CDIV(N_C, 256), 256, 0, stream>>>(tmp_cc, bbase_cc, N_C, NE1,
                                                        rs_cc, csr_cc);

    const int gb_c = CDIV(N_C, 64);             // 938
    const int gb_v = CDIV(N_V, 64);             // 4
    const int ccb = CDIV(N_C, 16);              // 3750 cc blocks
    const int SM_BIG = 32768;

    // ---- layer 0 q~/k/v from x_cell ----
    gemm_qkv<<<gb_c, 256, SM_BIG, stream>>>(
        x_cell, 128, N_C,
        WT16, BQT, bk, BVT, BVT + CH, XQ, KV8);
    attn_uni<<<N_V + ccb, 256, 0, stream>>>(
        XQ, KV8, x_vcell, WQT + (size_t)CH * CH, BQT + CH,
        rs_cc, csr_cc, rs_cv, csr_cv, AGGV, N_C, ccb,
        nullptr, nullptr, nullptr, nullptr, nullptr, nullptr, nullptr, nullptr, nullptr);

    for (int li = 0; li < NL; li++) {
        const float* xc_src = (li == 0) ? x_cell : XC;   // xold for gemm128(li)
        const float* xv_src = (li == 0) ? x_vcell : XV;
        int b0 = (li * 2) * CH, b1 = (li * 2 + 1) * CH;
        size_t w1 = (size_t)(li * 2 + 1) * CH * CH;
        const _Float16* WT_a = WT16 + (size_t)(li * 5 + 4) * CH * CH;
        int do_qkv = (li + 1 < NL) ? 1 : 0;
        const _Float16* WT5n = WT16 + (size_t)((li + 1) % NL * 5) * CH * CH;
        int nb0 = ((li + 1) % NL * 2) * CH, nb1 = ((li + 1) % NL * 2 + 1) * CH;

        // fused: gemm128(li) c-side + v-side; then qkv(li+1) from block-local XC
        gemm_fused<<<gb_c + gb_v, 256, SM_BIG, stream>>>(
            gb_c, do_qkv,
            XQ, WT_a, ba + b0, XC, N_C,
            skip + li * 2, xc_src,
            Wk_o + li * CH, bk_o + li, KO,
            Wv_o + li * CH, bv_o + li, VO,
            WT5n, BQT + nb0, bk + nb0, BVT + nb0, BVT + nb1, XQ, KV8,
            AGGV, 128, Wa + w1, ba + b1, XV, N_V,
            skip + li * 2 + 1, xv_src,
            Wq_o + li * CH, bq_o + li, QO);

        if (do_qkv) {
            // attention for layer li+1, plus out-conv(li) tail -> OUTS[li]
            size_t w1n = (size_t)((li + 1) * 2 + 1) * CH * CH;
            attn_uni<<<N_V + ccb + N_V, 256, 0, stream>>>(
                XQ, KV8, XV, WQT + w1n, BQT + (li + 1) * 2 * CH + CH,
                rs_cc, csr_cc, rs_cv, csr_cv, AGGV, N_C, ccb,
                QO, KO, VO,
                arel_o + li, prel_o + li, mrel_o + li,
                Wa_o + li, ba_o + li, OUTS + li * N_V);
        }
    }

    // last layer's out-conv attention, then final head
    attn_out<<<N_V, 256, 0, stream>>>(QO, KO, VO, rs_cv, csr_cv,
                                      arel_o + (NL - 1), prel_o + (NL - 1), mrel_o + (NL - 1),
                                      Wa_o + (NL - 1), ba_o + (NL - 1), OUTS + (NL - 1) * N_V);
    final_head<<<1, 64, 0, stream>>>(OUTS, fc_W, fc_b, mlp_W1, mlp_b1, mlp_W2, mlp_b2,
                                     (float*)d_out);
}

// Round 12
// 487.415 us; speedup vs baseline: 1.2533x; 1.0048x over previous
//
#include <hip/hip_runtime.h>
#include <hip/hip_fp16.h>
#include <math.h>
#include <stdint.h>

#define N_C 60000
#define N_V 256
#define CH 128
#define NH 4
#define HD 32
#define NL 3
#define NE1 600000
#define NE2 240000

#define CDIV(a,b) (((a)+(b)-1)/(b))
#define EPB 1024   // elems per block in counting-sort kernels

// Node KV record (512 B, stride <<9), fp8-e4m3 storage (math stays f32):
//   bytes [0,256)   : cc view, 16 chunks of 16B: chunk j = { k[8j..8j+8) , v_cc[8j..8j+8) }
//   bytes [256,512) : cv view, chunk j = { k[8j..8j+8) , v_cv[8j..8j+8) }
// gemm weights in MFMA FRAGMENT ORDER (cvt_w16). LDS layout (GEMM kernels):
//   [Af 64x136 fp16 = 17408 B | W 32768 B]  -- DISJOINT regions, so:
//   * A and first W stage under one barrier;
//   * epilogue writes next-phase A (fp16) into Af: each wave touches only its
//     own 16 rows -> intra-wave DS ordering, NO barrier for the re-read;
//   * W staging uses short-lived tmp regs (R10's phase-long prefetch spilled).

typedef _Float16 f16x8 __attribute__((ext_vector_type(8)));
typedef _Float16 f16x4 __attribute__((ext_vector_type(4)));
typedef float f32x4 __attribute__((ext_vector_type(4)));
typedef float f32x2 __attribute__((ext_vector_type(2)));

__device__ __forceinline__ float gelu_tanh(float x) {
    float x3 = x * x * x;
    float t = tanhf(0.7978845608028654f * (x + 0.044715f * x3));
    return 0.5f * x * (1.0f + t);
}

__device__ __forceinline__ void fp8x8_to_f32(uint2 w, float* f) {
    f32x2 a = __builtin_amdgcn_cvt_pk_f32_fp8(w.x, false);
    f32x2 b = __builtin_amdgcn_cvt_pk_f32_fp8(w.x, true);
    f32x2 c = __builtin_amdgcn_cvt_pk_f32_fp8(w.y, false);
    f32x2 d = __builtin_amdgcn_cvt_pk_f32_fp8(w.y, true);
    f[0] = a.x; f[1] = a.y; f[2] = b.x; f[3] = b.y;
    f[4] = c.x; f[5] = c.y; f[6] = d.x; f[7] = d.y;
}

__device__ __forceinline__ float dot8f(const float* q, const float* k) {
    float d = q[0] * k[0];
    d = fmaf(q[1], k[1], d);
    d = fmaf(q[2], k[2], d);
    d = fmaf(q[3], k[3], d);
    d = fmaf(q[4], k[4], d);
    d = fmaf(q[5], k[5], d);
    d = fmaf(q[6], k[6], d);
    d = fmaf(q[7], k[7], d);
    return d;
}

// ---------------- weight composition (Q-side + V-side in one launch) -----------
__global__ __launch_bounds__(256) void compose_both(
    const float* __restrict__ Wq, const float* __restrict__ bq,
    const float* __restrict__ arel, const float* __restrict__ prel,
    float* __restrict__ WQT, float* __restrict__ BQT,
    const float* __restrict__ Wv, const float* __restrict__ bv,
    const float* __restrict__ mrel,
    float* __restrict__ WVT, float* __restrict__ BVT)
{
    const int total = NL * 2 * (CH + 1) * CH;
    int gid = blockIdx.x * blockDim.x + threadIdx.x;
    bool qside = gid < total;
    int g2 = qside ? gid : gid - total;
    if (g2 >= total) return;
    int li2 = g2 / ((CH + 1) * CH);
    int rem = g2 % ((CH + 1) * CH);
    int c   = rem / CH;          // 0..CH ; CH => bias row
    int col = rem % CH;
    int h = col >> 5, low = col & 31;
    const float* rel = qside ? arel : mrel;
    const float* rp;
    int step;
    if (qside) { rp = rel + (li2 * NH + h) * (HD * HD) + low * HD; step = 1; }
    else       { rp = rel + (li2 * NH + h) * (HD * HD) + low;      step = HD; }
    float scale = qside ? prel[li2 * NH + h] * 0.17677669529663687f : 1.f;
    int wsel = qside ? li2 : (li2 & ~1);   // v-side always uses Wv[li][0]
    const float* W    = qside ? Wq : Wv;
    const float* bvec = qside ? bq : bv;
    const float* src = (c < CH) ? (W + ((size_t)wsel * CH + c) * CH + h * HD)
                                : (bvec + wsel * CH + h * HD);
    float acc = 0.f;
    #pragma unroll
    for (int e = 0; e < HD; e++) acc = fmaf(src[e], rp[e * step], acc);
    acc *= scale;
    float* WT = qside ? WQT : WVT;
    float* BT = qside ? BQT : BVT;
    if (c < CH) WT[((size_t)li2 * CH + c) * CH + col] = acc;
    else        BT[li2 * CH + col] = acc;
}

// ---------------- weight fp16 fragment-order emit (one thread per element) -----
// w: 0=WQT(c) 1=Wk(c) 2=WVT_cc 3=WVT_cv 4=Wa(c)
__global__ __launch_bounds__(256) void cvt_w16(
    const float* __restrict__ WQT, const float* __restrict__ Wk,
    const float* __restrict__ WVT, const float* __restrict__ Wa,
    _Float16* __restrict__ WT16)
{
    int gid = blockIdx.x * 256 + threadIdx.x;
    const int PER = CH * CH;
    if (gid >= NL * 5 * PER) return;
    int b = gid / PER, o = gid % PER;
    int li = b / 5, w = b % 5;
    const float* src;
    if      (w == 0) src = WQT + (size_t)(li * 2) * PER;
    else if (w == 1) src = Wk  + (size_t)(li * 2) * PER;
    else if (w == 2) src = WVT + (size_t)(li * 2) * PER;
    else if (w == 3) src = WVT + (size_t)(li * 2 + 1) * PER;
    else             src = Wa  + (size_t)(li * 2) * PER;
    int i = o & 7, lane = (o >> 3) & 63, f = (o >> 9) & 7, kk = o >> 12;
    int mr = lane & 15, g = lane >> 4;
    int k = kk * 32 + g * 8 + i;
    int c = (w < 4) ? (mr * 8 + f) : (f * 16 + mr);
    WT16[gid] = (_Float16)src[k * CH + c];
}

// ================= CSR build (merged cc+cv launches) ==========================
__global__ __launch_bounds__(256) void bucket_hist2(
    const int* __restrict__ dcc, const int* __restrict__ dcv, int nb_cc,
    int* __restrict__ hcc, int* __restrict__ hcv)
{
    __shared__ int h[256];
    bool cv = (int)blockIdx.x >= nb_cc;
    const int* dst = cv ? dcv : dcc;
    int E = cv ? NE2 : NE1;
    int shift = cv ? 0 : 8;
    int* bh = cv ? hcv : hcc;
    int b = cv ? blockIdx.x - nb_cc : blockIdx.x;
    int t = threadIdx.x;
    h[t] = 0;
    __syncthreads();
    int i0 = b * EPB, i1 = min(i0 + EPB, E);
    for (int i = i0 + t; i < i1; i += 256)
        atomicAdd(&h[(dst[i] >> shift) & 255], 1);
    __syncthreads();
    if (h[t] > 0) atomicAdd(&bh[t], h[t]);
}

__global__ __launch_bounds__(256) void scan256x2(
    const int* __restrict__ hcc, int* __restrict__ base_cc, int* __restrict__ cur_cc,
    const int* __restrict__ hcv, int* __restrict__ base_cv, int* __restrict__ cur_cv)
{
    __shared__ int p[256];
    bool cv = blockIdx.x > 0;
    const int* h  = cv ? hcv : hcc;
    int* base     = cv ? base_cv : base_cc;
    int* cur      = cv ? cur_cv : cur_cc;
    int t = threadIdx.x;
    int v = h[t];
    p[t] = v;
    __syncthreads();
    for (int off = 1; off < 256; off <<= 1) {
        int u = (t >= off) ? p[t - off] : 0;
        __syncthreads();
        p[t] += u;
        __syncthreads();
    }
    base[t] = p[t] - v;
    cur[t]  = p[t] - v;
    if (t == 255) base[256] = p[255];
}

__global__ __launch_bounds__(256) void partition2(
    const int* __restrict__ scc, const int* __restrict__ dcc,
    const int* __restrict__ scv, const int* __restrict__ dcv, int nb_cc,
    int* __restrict__ cur_cc, int* __restrict__ cur_cv,
    int2* __restrict__ tmp_pair, int* __restrict__ out_src)
{
    __shared__ int cnt[256], base[256], cnt2[256];
    bool cv = (int)blockIdx.x >= nb_cc;
    const int* src = cv ? scv : scc;
    const int* dst = cv ? dcv : dcc;
    int E = cv ? NE2 : NE1;
    int shift = cv ? 0 : 8;
    int* cur = cv ? cur_cv : cur_cc;
    int b = cv ? blockIdx.x - nb_cc : blockIdx.x;
    int t = threadIdx.x;
    cnt[t] = 0; cnt2[t] = 0;
    __syncthreads();
    int i0 = b * EPB, i1 = min(i0 + EPB, E);
    for (int i = i0 + t; i < i1; i += 256)
        atomicAdd(&cnt[(dst[i] >> shift) & 255], 1);
    __syncthreads();
    if (cnt[t] > 0) base[t] = atomicAdd(&cur[t], cnt[t]);
    __syncthreads();
    for (int i = i0 + t; i < i1; i += 256) {
        int d = dst[i];
        int dig = (d >> shift) & 255;
        int r = atomicAdd(&cnt2[dig], 1);
        int pos = base[dig] + r;
        if (cv) out_src[pos] = src[i];
        else    tmp_pair[pos] = make_int2(src[i], d);
    }
}

__global__ __launch_bounds__(256) void bucket_finalize(
    const int2* __restrict__ tmp, const int* __restrict__ bbase, int n, int NE,
    int* __restrict__ rs, int* __restrict__ csr)
{
    __shared__ int cnt[256], pre[256], cnt2[256];
    int b = blockIdx.x, t = threadIdx.x;
    int s0 = bbase[b], s1 = bbase[b + 1];
    cnt[t] = 0; cnt2[t] = 0;
    __syncthreads();
    for (int i = s0 + t; i < s1; i += 256)
        atomicAdd(&cnt[tmp[i].y & 255], 1);
    __syncthreads();
    int v = cnt[t];
    pre[t] = v;
    __syncthreads();
    for (int off = 1; off < 256; off <<= 1) {
        int u = (t >= off) ? pre[t - off] : 0;
        __syncthreads();
        pre[t] += u;
        __syncthreads();
    }
    pre[t] -= v;   // exclusive
    __syncthreads();
    int dstid = b * 256 + t;
    if (dstid < n) rs[dstid] = s0 + pre[t];
    if (b == 0 && t == 0) rs[n] = NE;
    for (int i = s0 + t; i < s1; i += 256) {
        int2 e = tmp[i];
        int low = e.y & 255;
        int r = atomicAdd(&cnt2[low], 1);
        csr[s0 + pre[low] + r] = e.x;
    }
}

#define LDS_AF_BYTES 17408
#define SM_GEMM (LDS_AF_BYTES + 32768)   // 50176 B

// ---------------- layer-0 MFMA q~/k/v_cc/v_cv GEMM -----------------------------
__global__ __launch_bounds__(256) void gemm_qkv(
    const float* __restrict__ A, int lda, int M,
    const _Float16* __restrict__ WT4,   // 4 matrices, fragment order
    const float* __restrict__ b0, const float* __restrict__ b1,
    const float* __restrict__ b2, const float* __restrict__ b3,
    float* __restrict__ out, unsigned char* __restrict__ kv8)
{
    extern __shared__ char dynsm[];   // [Af | W]
    int tid = threadIdx.x;
    _Float16 (*Af)[136] = (_Float16(*)[136])dynsm;
    _Float16* Bl = (_Float16*)(dynsm + LDS_AF_BYTES);
    uint4* Blv = (uint4*)(dynsm + LDS_AF_BYTES);

    int row0 = blockIdx.x * 64;
    // stage A tile fp32 -> fp16 AND W0, one barrier
    #pragma unroll
    for (int i = 0; i < 8; i++) {
        int slot = tid + i * 256;            // 2048 float4 slots
        int r = slot >> 5, q = slot & 31;
        int rr = row0 + r;
        float4 v = make_float4(0.f, 0.f, 0.f, 0.f);
        if (rr < M) v = *(const float4*)(A + (size_t)rr * lda + q * 4);
        f16x4 h = { (_Float16)v.x, (_Float16)v.y, (_Float16)v.z, (_Float16)v.w };
        *(f16x4*)&Af[r][q * 4] = h;
    }
    {
        const uint4* WTv = (const uint4*)WT4;
        uint4 tmp[8];
        #pragma unroll
        for (int i = 0; i < 8; i++) tmp[i] = WTv[tid + i * 256];
        #pragma unroll
        for (int i = 0; i < 8; i++) Blv[tid + i * 256] = tmp[i];
    }
    __syncthreads();

    int lane = tid & 63, w = tid >> 6;
    int mr = lane & 15, g = lane >> 4;
    f16x8 afr[4];
    #pragma unroll
    for (int kk = 0; kk < 4; kk++)
        afr[kk] = *(const f16x8*)&Af[w * 16 + mr][kk * 32 + g * 8];

    const float* bs[4] = {b0, b1, b2, b3};
    uint2 kp[4];   // packed fp8 k piece per row (carried jw=1 -> jw=2,3)
    for (int jw = 0; jw < 4; jw++) {
        if (jw > 0) {
            const uint4* WTv = (const uint4*)(WT4 + (size_t)jw * CH * CH);
            uint4 tmp[8];
            #pragma unroll
            for (int i = 0; i < 8; i++) tmp[i] = WTv[tid + i * 256];
            #pragma unroll
            for (int i = 0; i < 8; i++) Blv[tid + i * 256] = tmp[i];
            __syncthreads();
        }

        f32x4 acc[8] = {};
        #pragma unroll
        for (int kk = 0; kk < 4; kk++) {
            f16x8 bf[8];
            #pragma unroll
            for (int f = 0; f < 8; f++)
                bf[f] = *(const f16x8*)(Bl + (size_t)((kk * 8 + f) * 64 + lane) * 8);
            #pragma unroll
            for (int f = 0; f < 8; f++)
                acc[f] = __builtin_amdgcn_mfma_f32_16x16x32_f16(afr[kk], bf[f], acc[f], 0, 0, 0);
        }
        const float* bb = bs[jw];
        float4 blo = *(const float4*)&bb[mr * 8];
        float4 bhi = *(const float4*)&bb[mr * 8 + 4];
        float bias[8] = {blo.x, blo.y, blo.z, blo.w, bhi.x, bhi.y, bhi.z, bhi.w};
        if (jw == 0) {
            #pragma unroll
            for (int r = 0; r < 4; r++) {
                int row = row0 + w * 16 + g * 4 + r;
                if (row < M) {
                    float4 o0 = make_float4(acc[0][r] + bias[0], acc[1][r] + bias[1],
                                            acc[2][r] + bias[2], acc[3][r] + bias[3]);
                    float4 o1 = make_float4(acc[4][r] + bias[4], acc[5][r] + bias[5],
                                            acc[6][r] + bias[6], acc[7][r] + bias[7]);
                    float* op = out + (size_t)row * 128 + mr * 8;
                    *(float4*)op = o0;
                    *(float4*)(op + 4) = o1;
                }
            }
        } else {
            #pragma unroll
            for (int r = 0; r < 4; r++) {
                float v0 = acc[0][r] + bias[0], v1 = acc[1][r] + bias[1];
                float v2 = acc[2][r] + bias[2], v3 = acc[3][r] + bias[3];
                float v4 = acc[4][r] + bias[4], v5 = acc[5][r] + bias[5];
                float v6 = acc[6][r] + bias[6], v7 = acc[7][r] + bias[7];
                unsigned int lo = (unsigned)__builtin_amdgcn_cvt_pk_fp8_f32(v0, v1, 0, false);
                lo = (unsigned)__builtin_amdgcn_cvt_pk_fp8_f32(v2, v3, (int)lo, true);
                unsigned int hi = (unsigned)__builtin_amdgcn_cvt_pk_fp8_f32(v4, v5, 0, false);
                hi = (unsigned)__builtin_amdgcn_cvt_pk_fp8_f32(v6, v7, (int)hi, true);
                if (jw == 1) {
                    kp[r] = make_uint2(lo, hi);
                } else {
                    int row = row0 + w * 16 + g * 4 + r;
                    if (row < M) {
                        unsigned char* base = kv8 + ((size_t)row << 9) + mr * 16
                                            + ((jw == 3) ? 256 : 0);
                        *(uint4*)base = make_uint4(kp[r].x, kp[r].y, lo, hi);
                    }
                }
            }
        }
        if (jw < 3) __syncthreads();   // guard W overwrite next iter
    }
}

// ---------------- FUSED: gemm128(li) c-side + gemm_qkv(li+1); v-side tail ------
__global__ __launch_bounds__(256) void gemm_fused(
    int nblk1, int do_qkv,
    // c-side gemm128 (layer li)
    const float* __restrict__ A1, const _Float16* __restrict__ Wa_h,
    const float* __restrict__ bias1, float* __restrict__ xc_out, int M,
    const float* __restrict__ gate1, const float* __restrict__ xold1,
    const float* __restrict__ wk1, const float* __restrict__ bk1, float* __restrict__ ko1,
    const float* __restrict__ wv1, const float* __restrict__ bv1, float* __restrict__ vo1,
    // qkv of layer li+1 (ignored when do_qkv == 0)
    const _Float16* __restrict__ WT4,
    const float* __restrict__ qb0, const float* __restrict__ qb1,
    const float* __restrict__ qb2, const float* __restrict__ qb3,
    float* __restrict__ xq_out, unsigned char* __restrict__ kv8,
    // v-side gemm128 (layer li)
    const float* __restrict__ A2, int lda2, const float* __restrict__ W2,
    const float* __restrict__ bias2, float* __restrict__ out2, int M2,
    const float* __restrict__ gate2, const float* __restrict__ xold2,
    const float* __restrict__ wk2, const float* __restrict__ bk2, float* __restrict__ ko2)
{
    extern __shared__ char dynsm[];
    int tid = threadIdx.x;

    if ((int)blockIdx.x >= nblk1) {
        // ======================= v-side: fp32 vector =======================
        float (*As)[36]  = (float(*)[36])dynsm;                 // 9216 B
        float (*Bs)[128] = (float(*)[128])(dynsm + 64 * 36 * 4); // 16384 B
        int row0 = (blockIdx.x - nblk1) * 64;
        int tx = tid & 15;
        int ty = tid >> 4;
        float acc[4][8] = {};
        for (int k0 = 0; k0 < 128; k0 += 32) {
            __syncthreads();
            #pragma unroll
            for (int i = 0; i < 2; i++) {
                int slot = tid + i * 256;            // [0,512) float4 slots
                int r = slot >> 3, kq = slot & 7;
                int rr = row0 + r;
                float4 v = make_float4(0.f, 0.f, 0.f, 0.f);
                if (rr < M2) v = *(const float4*)(A2 + (size_t)rr * lda2 + k0 + kq * 4);
                *(float4*)&As[r][kq * 4] = v;
            }
            #pragma unroll
            for (int i = 0; i < 4; i++) {
                int slot = tid + i * 256;            // [0,1024)
                int kr = slot >> 5, cq = slot & 31;
                *(float4*)&Bs[kr][cq * 4] = *(const float4*)(W2 + (size_t)(k0 + kr) * 128 + cq * 4);
            }
            __syncthreads();
            #pragma unroll
            for (int k4 = 0; k4 < 32; k4 += 4) {
                float4 av[4];
                #pragma unroll
                for (int i = 0; i < 4; i++)
                    av[i] = *(const float4*)&As[ty * 4 + i][k4];
                #pragma unroll
                for (int kk = 0; kk < 4; kk++) {
                    float4 bl = *(const float4*)&Bs[k4 + kk][tx * 4];
                    float4 bh = *(const float4*)&Bs[k4 + kk][64 + tx * 4];
                    float bb[8] = {bl.x, bl.y, bl.z, bl.w, bh.x, bh.y, bh.z, bh.w};
                    #pragma unroll
                    for (int i = 0; i < 4; i++) {
                        float a = ((const float*)&av[i])[kk];
                        #pragma unroll
                        for (int j = 0; j < 8; j++)
                            acc[i][j] = fmaf(a, bb[j], acc[i][j]);
                    }
                }
            }
        }
        float gt = 1.f / (1.f + expf(-gate2[0]));
        float og = 1.f - gt;
        float wkr[8];
        #pragma unroll
        for (int j = 0; j < 4; j++) {
            wkr[j]     = wk2[tx * 4 + j];
            wkr[4 + j] = wk2[64 + tx * 4 + j];
        }
        #pragma unroll
        for (int i = 0; i < 4; i++) {
            int r = row0 + ty * 4 + i;
            if (r >= M2) continue;   // uniform across each 16-lane group
            float vals[8];
            #pragma unroll
            for (int j = 0; j < 4; j++) {
                float v0 = acc[i][j]     + bias2[tx * 4 + j];
                float v1 = acc[i][4 + j] + bias2[64 + tx * 4 + j];
                v0 = gt * v0 + og * xold2[(size_t)r * 128 + tx * 4 + j];
                v1 = gt * v1 + og * xold2[(size_t)r * 128 + 64 + tx * 4 + j];
                vals[j] = v0;
                vals[4 + j] = v1;
            }
            float* op = out2 + (size_t)r * 128;
            *(float4*)(op + tx * 4)      = make_float4(vals[0], vals[1], vals[2], vals[3]);
            *(float4*)(op + 64 + tx * 4) = make_float4(vals[4], vals[5], vals[6], vals[7]);
            float pk = 0.f;
            #pragma unroll
            for (int j = 0; j < 8; j++) pk = fmaf(vals[j], wkr[j], pk);
            #pragma unroll
            for (int off = 1; off < 16; off <<= 1)
                pk += __shfl_xor(pk, off, 64);
            if (tx == 0) ko2[r] = pk + bk2[0];
        }
        return;
    }

    // ======================= c-side: gemm128 MFMA then qkv =======================
    _Float16 (*Af)[136] = (_Float16(*)[136])dynsm;
    _Float16* Bl = (_Float16*)(dynsm + LDS_AF_BYTES);
    uint4* Blv = (uint4*)(dynsm + LDS_AF_BYTES);
    int row0 = blockIdx.x * 64;
    // stage A and Wa together, one barrier
    #pragma unroll
    for (int i = 0; i < 8; i++) {
        int slot = tid + i * 256;
        int r = slot >> 5, q = slot & 31;
        int rr = row0 + r;
        float4 v = make_float4(0.f, 0.f, 0.f, 0.f);
        if (rr < M) v = *(const float4*)(A1 + (size_t)rr * 128 + q * 4);
        f16x4 h = { (_Float16)v.x, (_Float16)v.y, (_Float16)v.z, (_Float16)v.w };
        *(f16x4*)&Af[r][q * 4] = h;
    }
    {
        const uint4* WTv = (const uint4*)Wa_h;
        uint4 tmp[8];
        #pragma unroll
        for (int i = 0; i < 8; i++) tmp[i] = WTv[tid + i * 256];
        #pragma unroll
        for (int i = 0; i < 8; i++) Blv[tid + i * 256] = tmp[i];
    }
    __syncthreads();

    int lane = tid & 63, w = tid >> 6;
    int mr = lane & 15, g = lane >> 4;
    f16x8 afr[4];
    #pragma unroll
    for (int kk = 0; kk < 4; kk++)
        afr[kk] = *(const f16x8*)&Af[w * 16 + mr][kk * 32 + g * 8];

    f32x4 acc[8] = {};
    #pragma unroll
    for (int kk = 0; kk < 4; kk++) {
        f16x8 bf[8];
        #pragma unroll
        for (int f = 0; f < 8; f++)
            bf[f] = *(const f16x8*)(Bl + (size_t)((kk * 8 + f) * 64 + lane) * 8);
        #pragma unroll
        for (int f = 0; f < 8; f++)
            acc[f] = __builtin_amdgcn_mfma_f32_16x16x32_f16(afr[kk], bf[f], acc[f], 0, 0, 0);
    }

    // epilogue: gate+skip, XC write, out-conv k/v projections, and write the
    // gated value fp16 into Af (own-wave rows -> intra-wave ordered reuse).
    float gt = 1.f / (1.f + expf(-gate1[0]));
    float og = 1.f - gt;
    float pk[4] = {}, pv[4] = {};
    #pragma unroll
    for (int f = 0; f < 8; f++) {
        int col = f * 16 + mr;
        float bias = bias1[col];
        float wkc = wk1[col];
        float wvc = wv1[col];
        #pragma unroll
        for (int r = 0; r < 4; r++) {
            int row = row0 + w * 16 + g * 4 + r;
            float v = 0.f;
            if (row < M) {
                v = acc[f][r] + bias;
                v = gt * v + og * xold1[(size_t)row * 128 + col];
                xc_out[(size_t)row * 128 + col] = v;
                pk[r] = fmaf(v, wkc, pk[r]);
                pv[r] = fmaf(v, wvc, pv[r]);
            }
            Af[w * 16 + g * 4 + r][col] = (_Float16)v;
        }
    }
    #pragma unroll
    for (int r = 0; r < 4; r++) {
        #pragma unroll
        for (int off = 1; off < 16; off <<= 1) {
            pk[r] += __shfl_xor(pk[r], off, 64);
            pv[r] += __shfl_xor(pv[r], off, 64);
        }
    }
    if (mr == 0) {
        #pragma unroll
        for (int r = 0; r < 4; r++) {
            int row = row0 + w * 16 + g * 4 + r;
            if (row < M) {
                ko1[row] = pk[r] + bk1[0];
                vo1[row] = pv[r] + bv1[0];
            }
        }
    }

    if (!do_qkv) return;

    // -------- phase 2: next-layer q~/k/v_cc/v_cv from the in-LDS XC tile --------
    f16x8 afr2[4];
    #pragma unroll
    for (int kk = 0; kk < 4; kk++)
        afr2[kk] = *(const f16x8*)&Af[w * 16 + mr][kk * 32 + g * 8];
    __syncthreads();   // all waves done reading W(a) region before overwrite

    const float* bs[4] = {qb0, qb1, qb2, qb3};
    uint2 kp[4];
    for (int jw = 0; jw < 4; jw++) {
        {
            const uint4* WTv = (const uint4*)(WT4 + (size_t)jw * CH * CH);
            uint4 tmp[8];
            #pragma unroll
            for (int i = 0; i < 8; i++) tmp[i] = WTv[tid + i * 256];
            #pragma unroll
            for (int i = 0; i < 8; i++) Blv[tid + i * 256] = tmp[i];
        }
        __syncthreads();

        f32x4 acc2[8] = {};
        #pragma unroll
        for (int kk = 0; kk < 4; kk++) {
            f16x8 bf[8];
            #pragma unroll
            for (int f = 0; f < 8; f++)
                bf[f] = *(const f16x8*)(Bl + (size_t)((kk * 8 + f) * 64 + lane) * 8);
            #pragma unroll
            for (int f = 0; f < 8; f++)
                acc2[f] = __builtin_amdgcn_mfma_f32_16x16x32_f16(afr2[kk], bf[f], acc2[f], 0, 0, 0);
        }
        const float* bb = bs[jw];
        float4 blo = *(const float4*)&bb[mr * 8];
        float4 bhi = *(const float4*)&bb[mr * 8 + 4];
        float bias[8] = {blo.x, blo.y, blo.z, blo.w, bhi.x, bhi.y, bhi.z, bhi.w};
        if (jw == 0) {
            #pragma unroll
            for (int r = 0; r < 4; r++) {
                int row = row0 + w * 16 + g * 4 + r;
                if (row < M) {
                    float4 o0 = make_float4(acc2[0][r] + bias[0], acc2[1][r] + bias[1],
                                            acc2[2][r] + bias[2], acc2[3][r] + bias[3]);
                    float4 o1 = make_float4(acc2[4][r] + bias[4], acc2[5][r] + bias[5],
                                            acc2[6][r] + bias[6], acc2[7][r] + bias[7]);
                    float* op = xq_out + (size_t)row * 128 + mr * 8;
                    *(float4*)op = o0;
                    *(float4*)(op + 4) = o1;
                }
            }
        } else {
            #pragma unroll
            for (int r = 0; r < 4; r++) {
                float v0 = acc2[0][r] + bias[0], v1 = acc2[1][r] + bias[1];
                float v2 = acc2[2][r] + bias[2], v3 = acc2[3][r] + bias[3];
                float v4 = acc2[4][r] + bias[4], v5 = acc2[5][r] + bias[5];
                float v6 = acc2[6][r] + bias[6], v7 = acc2[7][r] + bias[7];
                unsigned int lo = (unsigned)__builtin_amdgcn_cvt_pk_fp8_f32(v0, v1, 0, false);
                lo = (unsigned)__builtin_amdgcn_cvt_pk_fp8_f32(v2, v3, (int)lo, true);
                unsigned int hi = (unsigned)__builtin_amdgcn_cvt_pk_fp8_f32(v4, v5, 0, false);
                hi = (unsigned)__builtin_amdgcn_cvt_pk_fp8_f32(v6, v7, (int)hi, true);
                if (jw == 1) {
                    kp[r] = make_uint2(lo, hi);
                } else {
                    int row = row0 + w * 16 + g * 4 + r;
                    if (row < M) {
                        unsigned char* base = kv8 + ((size_t)row << 9) + mr * 16
                                            + ((jw == 3) ? 256 : 0);
                        *(uint4*)base = make_uint4(kp[r].x, kp[r].y, lo, hi);
                    }
                }
            }
        }
        if (jw < 3) __syncthreads();
    }
}

// ---------------- cv gather: 4 groups on one node, 64-edge chunks --------------
__device__ __forceinline__ void gather_cv(
    const unsigned char* __restrict__ kv8, const int* __restrict__ csr,
    int e0, int e1, int g, int j, const float* q8,
    float& s_io, float acc[8])
{
    int lane = threadIdx.x & 63;
    float s = s_io;
    for (int cs = e0; cs < e1; cs += 64) {
        int n = e1 - cs; if (n > 64) n = 64;
        int nm1 = n - 1;
        int idx0 = 0;
        if (lane < n) idx0 = csr[cs + lane];
        int R = (n + 7) >> 3;
        uint4 a0, a1, b0, b1;

#define LD2(E0_, E1_, B0_, B1_) { \
            int i0_ = __shfl(idx0, min((E0_), nm1), 64); \
            int i1_ = __shfl(idx0, min((E1_), nm1), 64); \
            B0_ = *(const uint4*)(kv8 + ((size_t)i0_ << 9) + 256 + (j << 4)); \
            B1_ = *(const uint4*)(kv8 + ((size_t)i1_ << 9) + 256 + (j << 4)); }

#define CMP2(E0_, E1_, B0_, B1_) { \
            float k0f[8], k1f[8], v0f[8], v1f[8]; \
            fp8x8_to_f32(make_uint2(B0_.x, B0_.y), k0f); \
            fp8x8_to_f32(make_uint2(B1_.x, B1_.y), k1f); \
            float d0_ = dot8f(q8, k0f); \
            float d1_ = dot8f(q8, k1f); \
            d0_ += __shfl_xor(d0_, 1, 64); d1_ += __shfl_xor(d1_, 1, 64); \
            d0_ += __shfl_xor(d0_, 2, 64); d1_ += __shfl_xor(d1_, 2, 64); \
            float w0_ = ((E0_) < n) ? __expf(d0_) : 0.f; \
            float w1_ = ((E1_) < n) ? __expf(d1_) : 0.f; \
            s += w0_ + w1_; \
            fp8x8_to_f32(make_uint2(B0_.z, B0_.w), v0f); \
            fp8x8_to_f32(make_uint2(B1_.z, B1_.w), v1f); \
            acc[0] = fmaf(w0_, v0f[0], acc[0]); acc[0] = fmaf(w1_, v1f[0], acc[0]); \
            acc[1] = fmaf(w0_, v0f[1], acc[1]); acc[1] = fmaf(w1_, v1f[1], acc[1]); \
            acc[2] = fmaf(w0_, v0f[2], acc[2]); acc[2] = fmaf(w1_, v1f[2], acc[2]); \
            acc[3] = fmaf(w0_, v0f[3], acc[3]); acc[3] = fmaf(w1_, v1f[3], acc[3]); \
            acc[4] = fmaf(w0_, v0f[4], acc[4]); acc[4] = fmaf(w1_, v1f[4], acc[4]); \
            acc[5] = fmaf(w0_, v0f[5], acc[5]); acc[5] = fmaf(w1_, v1f[5], acc[5]); \
            acc[6] = fmaf(w0_, v0f[6], acc[6]); acc[6] = fmaf(w1_, v1f[6], acc[6]); \
            acc[7] = fmaf(w0_, v0f[7], acc[7]); acc[7] = fmaf(w1_, v1f[7], acc[7]); }

        LD2(g, g + 4, a0, a1);
        if (R > 1) LD2(g + 8, g + 12, b0, b1);
        for (int r = 0; r < R; r += 2) {
            int er = g + 8 * r;
            CMP2(er, er + 4, a0, a1);
            if (r + 2 < R) LD2(g + 8 * (r + 2), g + 8 * (r + 2) + 4, a0, a1);
            if (r + 1 < R) {
                int eo = g + 8 * (r + 1);
                CMP2(eo, eo + 4, b0, b1);
                if (r + 3 < R) LD2(g + 8 * (r + 3), g + 8 * (r + 3) + 4, b0, b1);
            }
        }
#undef LD2
#undef CMP2
    }
    s_io = s;
}

// ---------------- unified attention: cv | cc | prev-layer out-conv tail --------
__global__ __launch_bounds__(256) void attn_uni(
    float* __restrict__ xq, const unsigned char* __restrict__ kv8,
    const float* __restrict__ xv, const float* __restrict__ wqt,
    const float* __restrict__ bqt,
    const int* __restrict__ rs_cc, const int* __restrict__ csr_cc,
    const int* __restrict__ rs_cv, const int* __restrict__ csr_cv,
    float* __restrict__ aggv, int n_c, int ccb,
    // out-conv tail (prev layer); only when grid extends past N_V+ccb
    const float* __restrict__ qo, const float* __restrict__ ko,
    const float* __restrict__ vo,
    const float* __restrict__ arel_o, const float* __restrict__ prel_o,
    const float* __restrict__ mrel_o, const float* __restrict__ Wa_o,
    const float* __restrict__ ba_o, float* __restrict__ outl)
{
    __shared__ float smem[656];
    int lane = threadIdx.x & 63, wid = threadIdx.x >> 6;
    int g = lane >> 4, j = lane & 15;

    if (blockIdx.x < N_V) {
        // ---------------- cv node (4 waves, 4 groups each) ----------------
        int node = blockIdx.x;
        float* qrow = smem;          // [128]
        float* sm_s = smem + 128;    // [4][4]
        float* sm_a = smem + 144;    // [4][128]
        if (wid < 2) {
            int col = wid * 64 + lane;
            float a = bqt[col];
            const float* xr = xv + (size_t)node * 128;
            for (int k = 0; k < 128; k++)
                a = fmaf(xr[k], wqt[(size_t)k * 128 + col], a);
            qrow[col] = a;
        }
        __syncthreads();
        float q8[8];
        *(float4*)&q8[0] = *(const float4*)&qrow[8 * j];
        *(float4*)&q8[4] = *(const float4*)&qrow[8 * j + 4];
        int rs = rs_cv[node], re = rs_cv[node + 1];
        int cnt = re - rs;
        int per = (cnt + 3) >> 2;
        int e0 = rs + wid * per, e1 = min(e0 + per, re);
        float s = 0.f;
        float acc[8] = {};
        gather_cv(kv8, csr_cv, e0, e1, g, j, q8, s, acc);
        #pragma unroll
        for (int i = 0; i < 8; i++) {
            acc[i] += __shfl_xor(acc[i], 16, 64);
            acc[i] += __shfl_xor(acc[i], 32, 64);
        }
        s += __shfl_xor(s, 16, 64);
        s += __shfl_xor(s, 32, 64);
        if (g == 0) {
            *(float4*)&sm_a[wid * 128 + 8 * j]     = make_float4(acc[0], acc[1], acc[2], acc[3]);
            *(float4*)&sm_a[wid * 128 + 8 * j + 4] = make_float4(acc[4], acc[5], acc[6], acc[7]);
            if ((j & 3) == 0) sm_s[wid * 4 + (j >> 2)] = s;
        }
        __syncthreads();
        if (threadIdx.x < 64) {
            int lp = 2 * lane;
            int h = lp >> 5;
            float S = 0.f, AX = 0.f, AY = 0.f;
            #pragma unroll
            for (int i = 0; i < 4; i++) {
                S  += sm_s[i * 4 + h];
                float2 a2 = *(const float2*)&sm_a[i * 128 + lp];
                AX += a2.x;
                AY += a2.y;
            }
            float inv = (S > 0.f) ? 1.f / S : 0.f;
            aggv[(size_t)node * 128 + lp]     = gelu_tanh(AX * inv);
            aggv[(size_t)node * 128 + lp + 1] = gelu_tanh(AY * inv);
        }
    } else if ((int)blockIdx.x < N_V + ccb) {
        // ---------------- cc: one node per 16-lane group ----------------
        int node = (blockIdx.x - N_V) * 16 + wid * 4 + g;
        bool valid = (node < n_c);
        int rs = valid ? rs_cc[node] : 0;
        int re = valid ? rs_cc[node + 1] : 0;
        float q8[8];
        if (valid) {
            const float* qp = xq + (size_t)node * 128 + 8 * j;
            *(float4*)&q8[0] = *(const float4*)qp;
            *(float4*)&q8[4] = *(const float4*)(qp + 4);
        } else {
            #pragma unroll
            for (int i = 0; i < 8; i++) q8[i] = 0.f;
        }
        float s = 0.f;
        float acc[8] = {};
        int base = lane & 48;

        for (int cs = rs; cs < re; cs += 16) {
            int cnt = min(16, re - cs);
            int cm1 = cnt - 1;
            int idx = csr_cc[cs + min(j, cm1)];
            uint4 B0, B1, B2, B3;

#define LDE(E_, B_) { int i_ = __shfl(idx, base + min((E_), cm1), 64); \
            B_ = *(const uint4*)(kv8 + ((size_t)i_ << 9) + (j << 4)); }
#define CMPE(E_, B_) { float kf[8], vf[8]; \
            fp8x8_to_f32(make_uint2(B_.x, B_.y), kf); \
            float d_ = dot8f(q8, kf); \
            d_ += __shfl_xor(d_, 1, 64); d_ += __shfl_xor(d_, 2, 64); \
            float w_ = ((E_) < cnt) ? __expf(d_) : 0.f; \
            s += w_; \
            fp8x8_to_f32(make_uint2(B_.z, B_.w), vf); \
            acc[0] = fmaf(w_, vf[0], acc[0]); \
            acc[1] = fmaf(w_, vf[1], acc[1]); \
            acc[2] = fmaf(w_, vf[2], acc[2]); \
            acc[3] = fmaf(w_, vf[3], acc[3]); \
            acc[4] = fmaf(w_, vf[4], acc[4]); \
            acc[5] = fmaf(w_, vf[5], acc[5]); \
            acc[6] = fmaf(w_, vf[6], acc[6]); \
            acc[7] = fmaf(w_, vf[7], acc[7]); }

            LDE(0, B0) LDE(1, B1) LDE(2, B2) LDE(3, B3)
            CMPE(0, B0) CMPE(1, B1)
            if (cnt > 4) { LDE(4, B0) LDE(5, B1) }
            CMPE(2, B2) CMPE(3, B3)
            if (cnt > 6) { LDE(6, B2) LDE(7, B3) }
            if (cnt > 4) {
                CMPE(4, B0) CMPE(5, B1)
                if (cnt > 8) { LDE(8, B0) LDE(9, B1) }
                CMPE(6, B2) CMPE(7, B3)
                if (cnt > 10) { LDE(10, B2) LDE(11, B3) }
                if (cnt > 8) {
                    CMPE(8, B0) CMPE(9, B1)
                    if (cnt > 12) { LDE(12, B0) LDE(13, B1) }
                    CMPE(10, B2) CMPE(11, B3)
                    if (cnt > 14) { LDE(14, B2) LDE(15, B3) }
                    if (cnt > 12) {
                        CMPE(12, B0) CMPE(13, B1) CMPE(14, B2) CMPE(15, B3)
                    }
                }
            }
#undef LDE
#undef CMPE
        }
        if (valid) {
            float inv = (s > 0.f) ? 1.f / s : 0.f;
            float4 o0 = make_float4(gelu_tanh(acc[0] * inv), gelu_tanh(acc[1] * inv),
                                    gelu_tanh(acc[2] * inv), gelu_tanh(acc[3] * inv));
            float4 o1 = make_float4(gelu_tanh(acc[4] * inv), gelu_tanh(acc[5] * inv),
                                    gelu_tanh(acc[6] * inv), gelu_tanh(acc[7] * inv));
            float* op = xq + (size_t)node * 128 + 8 * j;
            *(float4*)op = o0;
            *(float4*)(op + 4) = o1;
        }
    } else {
        // ---------------- prev-layer out-conv scalar attention ----------------
        int node = blockIdx.x - N_V - ccb;
        float* sms = smem;       // [4]
        float* sma = smem + 4;   // [4]
        float qs = qo[node] * arel_o[0] * prel_o[0];
        int rs = rs_cv[node], re = rs_cv[node + 1];
        float s = 0.f, a = 0.f;
        for (int e = rs + (int)threadIdx.x; e < re; e += 256) {
            int si = csr_cv[e];
            float w = __expf(qs * ko[si]);
            s += w;
            a = fmaf(w, vo[si], a);
        }
        #pragma unroll
        for (int off = 32; off >= 1; off >>= 1) {
            s += __shfl_xor(s, off, 64);
            a += __shfl_xor(a, off, 64);
        }
        if (lane == 0) { sms[wid] = s; sma[wid] = a; }
        __syncthreads();
        if (threadIdx.x == 0) {
            float S = sms[0] + sms[1] + sms[2] + sms[3];
            float A = sma[0] + sma[1] + sma[2] + sma[3];
            float agg = (S > 0.f) ? A / S : 0.f;
            agg *= mrel_o[0];
            outl[node] = gelu_tanh(agg) * Wa_o[0] + ba_o[0];
        }
    }
}

// ---------------- out-conv scalar attention (standalone, last layer) -----------
__global__ __launch_bounds__(256) void attn_out(
    const float* __restrict__ qo, const float* __restrict__ ko, const float* __restrict__ vo,
    const int* __restrict__ rowstart, const int* __restrict__ csr,
    const float* __restrict__ arel_o, const float* __restrict__ prel_o,
    const float* __restrict__ mrel_o, const float* __restrict__ Wa_o,
    const float* __restrict__ ba_o, float* __restrict__ outl)
{
    int node = blockIdx.x;
    float qs = qo[node] * arel_o[0] * prel_o[0];
    int rs = rowstart[node], re = rowstart[node + 1];
    float s = 0.f, a = 0.f;
    for (int e = rs + (int)threadIdx.x; e < re; e += 256) {
        int si = csr[e];
        float w = __expf(qs * ko[si]);
        s += w;
        a = fmaf(w, vo[si], a);
    }
    #pragma unroll
    for (int off = 32; off >= 1; off >>= 1) {
        s += __shfl_xor(s, off, 64);
        a += __shfl_xor(a, off, 64);
    }
    __shared__ float sms[4], sma[4];
    int lane = threadIdx.x & 63, wid = threadIdx.x >> 6;
    if (lane == 0) { sms[wid] = s; sma[wid] = a; }
    __syncthreads();
    if (threadIdx.x == 0) {
        float S = sms[0] + sms[1] + sms[2] + sms[3];
        float A = sma[0] + sma[1] + sma[2] + sma[3];
        float agg = (S > 0.f) ? A / S : 0.f;
        agg *= mrel_o[0];
        outl[node] = gelu_tanh(agg) * Wa_o[0] + ba_o[0];
    }
}

// ---------------- final head: JK-max -> node_fc -> MLP ------------------------
__global__ void final_head(const float* __restrict__ outs,
    const float* __restrict__ fc_W, const float* __restrict__ fc_b,
    const float* __restrict__ W1, const float* __restrict__ b1,
    const float* __restrict__ W2, const float* __restrict__ b2,
    float* __restrict__ out)
{
    int b = threadIdx.x;
    if (b >= 64) return;
    float h = fc_b[0];
    #pragma unroll
    for (int v = 0; v < 4; v++) {
        int n = b * 4 + v;
        float jk = fmaxf(fmaxf(outs[0 * N_V + n], outs[1 * N_V + n]), outs[2 * N_V + n]);
        h = fmaf(jk, fc_W[v], h);
    }
    h = gelu_tanh(h);
    float h0 = gelu_tanh(h * W1[0] + b1[0]);
    float h1 = gelu_tanh(h * W1[1] + b1[1]);
    out[b] = h0 * W2[0] + h1 * W2[1] + b2[0];
}

// ---------------- orchestration ----------------------------------------------
extern "C" void kernel_launch(void* const* d_in, const int* in_sizes, int n_in,
                              void* d_out, int out_size, void* d_ws, size_t ws_size,
                              hipStream_t stream) {
    (void)in_sizes; (void)n_in; (void)out_size; (void)ws_size;
    const float* x_cell  = (const float*)d_in[0];
    const float* x_vcell = (const float*)d_in[1];
    const float* Wk   = (const float*)d_in[2];
    const float* bk   = (const float*)d_in[3];
    const float* Wq   = (const float*)d_in[4];
    const float* bq   = (const float*)d_in[5];
    const float* Wv   = (const float*)d_in[6];
    const float* bv   = (const float*)d_in[7];
    const float* Wa   = (const float*)d_in[8];
    const float* ba   = (const float*)d_in[9];
    const float* skip = (const float*)d_in[10];
    const float* arel = (const float*)d_in[11];
    const float* mrel = (const float*)d_in[12];
    const float* prel = (const float*)d_in[13];
    const float* Wk_o = (const float*)d_in[14];
    const float* bk_o = (const float*)d_in[15];
    const float* Wq_o = (const float*)d_in[16];
    const float* bq_o = (const float*)d_in[17];
    const float* Wv_o = (const float*)d_in[18];
    const float* bv_o = (const float*)d_in[19];
    const float* Wa_o = (const float*)d_in[20];
    const float* ba_o = (const float*)d_in[21];
    const float* arel_o = (const float*)d_in[22];
    const float* mrel_o = (const float*)d_in[23];
    const float* prel_o = (const float*)d_in[24];
    const float* fc_W  = (const float*)d_in[25];
    const float* fc_b  = (const float*)d_in[26];
    const float* mlp_W1 = (const float*)d_in[27];
    const float* mlp_b1 = (const float*)d_in[28];
    const float* mlp_W2 = (const float*)d_in[29];
    const float* mlp_b2 = (const float*)d_in[30];
    const int* src_cc = (const int*)d_in[31];
    const int* dst_cc = (const int*)d_in[32];
    const int* src_cv = (const int*)d_in[33];
    const int* dst_cv = (const int*)d_in[34];

    // workspace carve-up (256B aligned)
    char* p = (char*)d_ws;
    auto alloc = [&](size_t bytes) -> char* {
        uintptr_t q = ((uintptr_t)p + 255) & ~(uintptr_t)255;
        p = (char*)(q + bytes);
        return (char*)q;
    };
    float* WQT  = (float*)alloc(sizeof(float) * NL * 2 * CH * CH);
    float* BQT  = (float*)alloc(sizeof(float) * NL * 2 * CH);
    float* WVT  = (float*)alloc(sizeof(float) * NL * 2 * CH * CH);
    float* BVT  = (float*)alloc(sizeof(float) * NL * 2 * CH);
    _Float16* WT16 = (_Float16*)alloc(sizeof(_Float16) * NL * 5 * CH * CH);
    float* XC   = (float*)alloc(sizeof(float) * (size_t)N_C * CH);
    float* XV   = (float*)alloc(sizeof(float) * (size_t)N_V * CH);
    float* XQ   = (float*)alloc(sizeof(float) * (size_t)N_C * CH);  // q~ / agg
    unsigned char* KV8 = (unsigned char*)alloc((size_t)N_C * 512);  // k|v_cc , k|v_cv fp8
    float* AGGV = (float*)alloc(sizeof(float) * (size_t)N_V * CH);
    float* KO   = (float*)alloc(sizeof(float) * N_C);
    float* VO   = (float*)alloc(sizeof(float) * N_C);
    float* QO   = (float*)alloc(sizeof(float) * N_V);
    float* OUTS = (float*)alloc(sizeof(float) * NL * N_V);
    // CSR-build scratch (hist region zeroed in one memset)
    int* bhist    = (int*)alloc(sizeof(int) * 512);
    int* bhist_cc = bhist;
    int* bhist_cv = bhist + 256;
    int* bbase_cc = (int*)alloc(sizeof(int) * 257);
    int* cur_cc   = (int*)alloc(sizeof(int) * 256);
    int* cur_cv   = (int*)alloc(sizeof(int) * 256);
    int* rs_cc    = (int*)alloc(sizeof(int) * (N_C + 1));
    int* rs_cv    = (int*)alloc(sizeof(int) * (N_V + 1));
    int* csr_cc   = (int*)alloc(sizeof(int) * NE1);
    int* csr_cv   = (int*)alloc(sizeof(int) * NE2);
    int2* tmp_cc  = (int2*)alloc(sizeof(int2) * NE1);

    // ---- setup: composed weights + fp16 fragment weights + CSR ----
    const int tot_c = NL * 2 * (CH + 1) * CH;
    compose_both<<<CDIV(2 * tot_c, 256), 256, 0, stream>>>(
        Wq, bq, arel, prel, WQT, BQT, Wv, bv, mrel, WVT, BVT);
    cvt_w16<<<CDIV(NL * 5 * CH * CH, 256), 256, 0, stream>>>(WQT, Wk, WVT, Wa, WT16);
    hipMemsetAsync(bhist, 0, sizeof(int) * 512, stream);
    const int nb_cc = CDIV(NE1, EPB), nb_cv = CDIV(NE2, EPB);
    bucket_hist2<<<nb_cc + nb_cv, 256, 0, stream>>>(dst_cc, dst_cv, nb_cc,
                                                    bhist_cc, bhist_cv);
    scan256x2<<<2, 256, 0, stream>>>(bhist_cc, bbase_cc, cur_cc,
                                     bhist_cv, rs_cv, cur_cv);  // rs_cv IS cv row starts
    partition2<<<nb_cc + nb_cv, 256, 0, stream>>>(src_cc, dst_cc, src_cv, dst_cv, nb_cc,
                                                  cur_cc, cur_cv, tmp_cc, csr_cv);
    bucket_finalize<<<CDIV(N_C, 256), 256, 0, stream>>>(tmp_cc, bbase_cc, N_C, NE1,
                                                        rs_cc, csr_cc);

    const int gb_c = CDIV(N_C, 64);             // 938
    const int gb_v = CDIV(N_V, 64);             // 4
    const int ccb = CDIV(N_C, 16);              // 3750 cc blocks

    // ---- layer 0 q~/k/v from x_cell ----
    gemm_qkv<<<gb_c, 256, SM_GEMM, stream>>>(
        x_cell, 128, N_C,
        WT16, BQT, bk, BVT, BVT + CH, XQ, KV8);
    attn_uni<<<N_V + ccb, 256, 0, stream>>>(
        XQ, KV8, x_vcell, WQT + (size_t)CH * CH, BQT + CH,
        rs_cc, csr_cc, rs_cv, csr_cv, AGGV, N_C, ccb,
        nullptr, nullptr, nullptr, nullptr, nullptr, nullptr, nullptr, nullptr, nullptr);

    for (int li = 0; li < NL; li++) {
        const float* xc_src = (li == 0) ? x_cell : XC;   // xold for gemm128(li)
        const float* xv_src = (li == 0) ? x_vcell : XV;
        int b0 = (li * 2) * CH, b1 = (li * 2 + 1) * CH;
        size_t w1 = (size_t)(li * 2 + 1) * CH * CH;
        const _Float16* WT_a = WT16 + (size_t)(li * 5 + 4) * CH * CH;
        int do_qkv = (li + 1 < NL) ? 1 : 0;
        const _Float16* WT5n = WT16 + (size_t)((li + 1) % NL * 5) * CH * CH;
        int nb0 = ((li + 1) % NL * 2) * CH, nb1 = ((li + 1) % NL * 2 + 1) * CH;

        // fused: gemm128(li) c-side + v-side; then qkv(li+1) from in-LDS XC tile
        gemm_fused<<<gb_c + gb_v, 256, SM_GEMM, stream>>>(
            gb_c, do_qkv,
            XQ, WT_a, ba + b0, XC, N_C,
            skip + li * 2, xc_src,
            Wk_o + li * CH, bk_o + li, KO,
            Wv_o + li * CH, bv_o + li, VO,
            WT5n, BQT + nb0, bk + nb0, BVT + nb0, BVT + nb1, XQ, KV8,
            AGGV, 128, Wa + w1, ba + b1, XV, N_V,
            skip + li * 2 + 1, xv_src,
            Wq_o + li * CH, bq_o + li, QO);

        if (do_qkv) {
            // attention for layer li+1, plus out-conv(li) tail -> OUTS[li]
            size_t w1n = (size_t)((li + 1) * 2 + 1) * CH * CH;
            attn_uni<<<N_V + ccb + N_V, 256, 0, stream>>>(
                XQ, KV8, XV, WQT + w1n, BQT + (li + 1) * 2 * CH + CH,
                rs_cc, csr_cc, rs_cv, csr_cv, AGGV, N_C, ccb,
                QO, KO, VO,
                arel_o + li, prel_o + li, mrel_o + li,
                Wa_o + li, ba_o + li, OUTS + li * N_V);
        }
    }

    // last layer's out-conv attention, then final head
    attn_out<<<N_V, 256, 0, stream>>>(QO, KO, VO, rs_cv, csr_cv,
                                      arel_o + (NL - 1), prel_o + (NL - 1), mrel_o + (NL - 1),
                                      Wa_o + (NL - 1), ba_o + (NL - 1), OUTS + (NL - 1) * N_V);
    final_head<<<1, 64, 0, stream>>>(OUTS, fc_W, fc_b, mlp_W1, mlp_b1, mlp_W2, mlp_b2,
                                     (float*)d_out);
}

// Round 13
// 458.327 us; speedup vs baseline: 1.3328x; 1.0635x over previous
//
#include <hip/hip_runtime.h>
#include <hip/hip_fp16.h>
#include <math.h>
#include <stdint.h>

#define N_C 60000
#define N_V 256
#define CH 128
#define NH 4
#define HD 32
#define NL 3
#define NE1 600000
#define NE2 240000

#define CDIV(a,b) (((a)+(b)-1)/(b))
#define EPB 1024   // elems per block in counting-sort kernels

// Node KV record (512 B, stride <<9), fp8-e4m3 storage (math stays f32):
//   bytes [0,256)   : cc view, 16 chunks of 16B: chunk j = { k[8j..8j+8) , v_cc[8j..8j+8) }
//   bytes [256,512) : cv view, chunk j = { k[8j..8j+8) , v_cv[8j..8j+8) }
// ALL gemm weights in MFMA FRAGMENT ORDER with col map c = mr*8+f (incl. Wa):
// lane mr owns logical cols [8mr,8mr+8) -> every epilogue access (xold read,
// XC write, Af write, bias/wk/wv) is a contiguous vector op. LDS layout:
//   [Af 64x136 fp16 = 17408 B | W 32768 B] disjoint; W staging = short-lived
//   tmp regs (R10's phase-long prefetch spilled to scratch — don't).

typedef _Float16 f16x8 __attribute__((ext_vector_type(8)));
typedef _Float16 f16x4 __attribute__((ext_vector_type(4)));
typedef float f32x4 __attribute__((ext_vector_type(4)));
typedef float f32x2 __attribute__((ext_vector_type(2)));

__device__ __forceinline__ float gelu_tanh(float x) {
    float x3 = x * x * x;
    float t = tanhf(0.7978845608028654f * (x + 0.044715f * x3));
    return 0.5f * x * (1.0f + t);
}

__device__ __forceinline__ void fp8x8_to_f32(uint2 w, float* f) {
    f32x2 a = __builtin_amdgcn_cvt_pk_f32_fp8(w.x, false);
    f32x2 b = __builtin_amdgcn_cvt_pk_f32_fp8(w.x, true);
    f32x2 c = __builtin_amdgcn_cvt_pk_f32_fp8(w.y, false);
    f32x2 d = __builtin_amdgcn_cvt_pk_f32_fp8(w.y, true);
    f[0] = a.x; f[1] = a.y; f[2] = b.x; f[3] = b.y;
    f[4] = c.x; f[5] = c.y; f[6] = d.x; f[7] = d.y;
}

__device__ __forceinline__ float dot8f(const float* q, const float* k) {
    float d = q[0] * k[0];
    d = fmaf(q[1], k[1], d);
    d = fmaf(q[2], k[2], d);
    d = fmaf(q[3], k[3], d);
    d = fmaf(q[4], k[4], d);
    d = fmaf(q[5], k[5], d);
    d = fmaf(q[6], k[6], d);
    d = fmaf(q[7], k[7], d);
    return d;
}

// ---------------- weight composition (Q-side + V-side in one launch) -----------
__global__ __launch_bounds__(256) void compose_both(
    const float* __restrict__ Wq, const float* __restrict__ bq,
    const float* __restrict__ arel, const float* __restrict__ prel,
    float* __restrict__ WQT, float* __restrict__ BQT,
    const float* __restrict__ Wv, const float* __restrict__ bv,
    const float* __restrict__ mrel,
    float* __restrict__ WVT, float* __restrict__ BVT)
{
    const int total = NL * 2 * (CH + 1) * CH;
    int gid = blockIdx.x * blockDim.x + threadIdx.x;
    bool qside = gid < total;
    int g2 = qside ? gid : gid - total;
    if (g2 >= total) return;
    int li2 = g2 / ((CH + 1) * CH);
    int rem = g2 % ((CH + 1) * CH);
    int c   = rem / CH;          // 0..CH ; CH => bias row
    int col = rem % CH;
    int h = col >> 5, low = col & 31;
    const float* rel = qside ? arel : mrel;
    const float* rp;
    int step;
    if (qside) { rp = rel + (li2 * NH + h) * (HD * HD) + low * HD; step = 1; }
    else       { rp = rel + (li2 * NH + h) * (HD * HD) + low;      step = HD; }
    float scale = qside ? prel[li2 * NH + h] * 0.17677669529663687f : 1.f;
    int wsel = qside ? li2 : (li2 & ~1);   // v-side always uses Wv[li][0]
    const float* W    = qside ? Wq : Wv;
    const float* bvec = qside ? bq : bv;
    const float* src = (c < CH) ? (W + ((size_t)wsel * CH + c) * CH + h * HD)
                                : (bvec + wsel * CH + h * HD);
    float acc = 0.f;
    #pragma unroll
    for (int e = 0; e < HD; e++) acc = fmaf(src[e], rp[e * step], acc);
    acc *= scale;
    float* WT = qside ? WQT : WVT;
    float* BT = qside ? BQT : BVT;
    if (c < CH) WT[((size_t)li2 * CH + c) * CH + col] = acc;
    else        BT[li2 * CH + col] = acc;
}

// ---------------- weight fp16 fragment-order emit (one thread per element) -----
// w: 0=WQT(c) 1=Wk(c) 2=WVT_cc 3=WVT_cv 4=Wa(c); ALL use col map c = mr*8+f
__global__ __launch_bounds__(256) void cvt_w16(
    const float* __restrict__ WQT, const float* __restrict__ Wk,
    const float* __restrict__ WVT, const float* __restrict__ Wa,
    _Float16* __restrict__ WT16)
{
    int gid = blockIdx.x * 256 + threadIdx.x;
    const int PER = CH * CH;
    if (gid >= NL * 5 * PER) return;
    int b = gid / PER, o = gid % PER;
    int li = b / 5, w = b % 5;
    const float* src;
    if      (w == 0) src = WQT + (size_t)(li * 2) * PER;
    else if (w == 1) src = Wk  + (size_t)(li * 2) * PER;
    else if (w == 2) src = WVT + (size_t)(li * 2) * PER;
    else if (w == 3) src = WVT + (size_t)(li * 2 + 1) * PER;
    else             src = Wa  + (size_t)(li * 2) * PER;
    int i = o & 7, lane = (o >> 3) & 63, f = (o >> 9) & 7, kk = o >> 12;
    int mr = lane & 15, g = lane >> 4;
    int k = kk * 32 + g * 8 + i;
    int c = mr * 8 + f;
    WT16[gid] = (_Float16)src[k * CH + c];
}

// ================= CSR build (merged cc+cv launches) ==========================
__global__ __launch_bounds__(256) void bucket_hist2(
    const int* __restrict__ dcc, const int* __restrict__ dcv, int nb_cc,
    int* __restrict__ hcc, int* __restrict__ hcv)
{
    __shared__ int h[256];
    bool cv = (int)blockIdx.x >= nb_cc;
    const int* dst = cv ? dcv : dcc;
    int E = cv ? NE2 : NE1;
    int shift = cv ? 0 : 8;
    int* bh = cv ? hcv : hcc;
    int b = cv ? blockIdx.x - nb_cc : blockIdx.x;
    int t = threadIdx.x;
    h[t] = 0;
    __syncthreads();
    int i0 = b * EPB, i1 = min(i0 + EPB, E);
    for (int i = i0 + t; i < i1; i += 256)
        atomicAdd(&h[(dst[i] >> shift) & 255], 1);
    __syncthreads();
    if (h[t] > 0) atomicAdd(&bh[t], h[t]);
}

__global__ __launch_bounds__(256) void scan256x2(
    const int* __restrict__ hcc, int* __restrict__ base_cc, int* __restrict__ cur_cc,
    const int* __restrict__ hcv, int* __restrict__ base_cv, int* __restrict__ cur_cv)
{
    __shared__ int p[256];
    bool cv = blockIdx.x > 0;
    const int* h  = cv ? hcv : hcc;
    int* base     = cv ? base_cv : base_cc;
    int* cur      = cv ? cur_cv : cur_cc;
    int t = threadIdx.x;
    int v = h[t];
    p[t] = v;
    __syncthreads();
    for (int off = 1; off < 256; off <<= 1) {
        int u = (t >= off) ? p[t - off] : 0;
        __syncthreads();
        p[t] += u;
        __syncthreads();
    }
    base[t] = p[t] - v;
    cur[t]  = p[t] - v;
    if (t == 255) base[256] = p[255];
}

__global__ __launch_bounds__(256) void partition2(
    const int* __restrict__ scc, const int* __restrict__ dcc,
    const int* __restrict__ scv, const int* __restrict__ dcv, int nb_cc,
    int* __restrict__ cur_cc, int* __restrict__ cur_cv,
    int2* __restrict__ tmp_pair, int* __restrict__ out_src)
{
    __shared__ int cnt[256], base[256], cnt2[256];
    bool cv = (int)blockIdx.x >= nb_cc;
    const int* src = cv ? scv : scc;
    const int* dst = cv ? dcv : dcc;
    int E = cv ? NE2 : NE1;
    int shift = cv ? 0 : 8;
    int* cur = cv ? cur_cv : cur_cc;
    int b = cv ? blockIdx.x - nb_cc : blockIdx.x;
    int t = threadIdx.x;
    cnt[t] = 0; cnt2[t] = 0;
    __syncthreads();
    int i0 = b * EPB, i1 = min(i0 + EPB, E);
    for (int i = i0 + t; i < i1; i += 256)
        atomicAdd(&cnt[(dst[i] >> shift) & 255], 1);
    __syncthreads();
    if (cnt[t] > 0) base[t] = atomicAdd(&cur[t], cnt[t]);
    __syncthreads();
    for (int i = i0 + t; i < i1; i += 256) {
        int d = dst[i];
        int dig = (d >> shift) & 255;
        int r = atomicAdd(&cnt2[dig], 1);
        int pos = base[dig] + r;
        if (cv) out_src[pos] = src[i];
        else    tmp_pair[pos] = make_int2(src[i], d);
    }
}

__global__ __launch_bounds__(256) void bucket_finalize(
    const int2* __restrict__ tmp, const int* __restrict__ bbase, int n, int NE,
    int* __restrict__ rs, int* __restrict__ csr)
{
    __shared__ int cnt[256], pre[256], cnt2[256];
    int b = blockIdx.x, t = threadIdx.x;
    int s0 = bbase[b], s1 = bbase[b + 1];
    cnt[t] = 0; cnt2[t] = 0;
    __syncthreads();
    for (int i = s0 + t; i < s1; i += 256)
        atomicAdd(&cnt[tmp[i].y & 255], 1);
    __syncthreads();
    int v = cnt[t];
    pre[t] = v;
    __syncthreads();
    for (int off = 1; off < 256; off <<= 1) {
        int u = (t >= off) ? pre[t - off] : 0;
        __syncthreads();
        pre[t] += u;
        __syncthreads();
    }
    pre[t] -= v;   // exclusive
    __syncthreads();
    int dstid = b * 256 + t;
    if (dstid < n) rs[dstid] = s0 + pre[t];
    if (b == 0 && t == 0) rs[n] = NE;
    for (int i = s0 + t; i < s1; i += 256) {
        int2 e = tmp[i];
        int low = e.y & 255;
        int r = atomicAdd(&cnt2[low], 1);
        csr[s0 + pre[low] + r] = e.x;
    }
}

#define LDS_AF_BYTES 17408
#define SM_GEMM (LDS_AF_BYTES + 32768)   // 50176 B

// ---------------- layer-0 MFMA q~/k/v_cc/v_cv GEMM -----------------------------
__global__ __launch_bounds__(256) void gemm_qkv(
    const float* __restrict__ A, int lda, int M,
    const _Float16* __restrict__ WT4,   // 4 matrices, fragment order
    const float* __restrict__ b0, const float* __restrict__ b1,
    const float* __restrict__ b2, const float* __restrict__ b3,
    float* __restrict__ out, unsigned char* __restrict__ kv8)
{
    extern __shared__ char dynsm[];   // [Af | W]
    int tid = threadIdx.x;
    _Float16 (*Af)[136] = (_Float16(*)[136])dynsm;
    _Float16* Bl = (_Float16*)(dynsm + LDS_AF_BYTES);
    uint4* Blv = (uint4*)(dynsm + LDS_AF_BYTES);

    int row0 = blockIdx.x * 64;
    // stage A tile fp32 -> fp16 AND W0, one barrier
    #pragma unroll
    for (int i = 0; i < 8; i++) {
        int slot = tid + i * 256;            // 2048 float4 slots
        int r = slot >> 5, q = slot & 31;
        int rr = row0 + r;
        float4 v = make_float4(0.f, 0.f, 0.f, 0.f);
        if (rr < M) v = *(const float4*)(A + (size_t)rr * lda + q * 4);
        f16x4 h = { (_Float16)v.x, (_Float16)v.y, (_Float16)v.z, (_Float16)v.w };
        *(f16x4*)&Af[r][q * 4] = h;
    }
    {
        const uint4* WTv = (const uint4*)WT4;
        uint4 tmp[8];
        #pragma unroll
        for (int i = 0; i < 8; i++) tmp[i] = WTv[tid + i * 256];
        #pragma unroll
        for (int i = 0; i < 8; i++) Blv[tid + i * 256] = tmp[i];
    }
    __syncthreads();

    int lane = tid & 63, w = tid >> 6;
    int mr = lane & 15, g = lane >> 4;
    f16x8 afr[4];
    #pragma unroll
    for (int kk = 0; kk < 4; kk++)
        afr[kk] = *(const f16x8*)&Af[w * 16 + mr][kk * 32 + g * 8];

    const float* bs[4] = {b0, b1, b2, b3};
    uint2 kp[4];   // packed fp8 k piece per row (carried jw=1 -> jw=2,3)
    for (int jw = 0; jw < 4; jw++) {
        if (jw > 0) {
            const uint4* WTv = (const uint4*)(WT4 + (size_t)jw * CH * CH);
            uint4 tmp[8];
            #pragma unroll
            for (int i = 0; i < 8; i++) tmp[i] = WTv[tid + i * 256];
            #pragma unroll
            for (int i = 0; i < 8; i++) Blv[tid + i * 256] = tmp[i];
            __syncthreads();
        }

        f32x4 acc[8] = {};
        #pragma unroll
        for (int kk = 0; kk < 4; kk++) {
            f16x8 bf[8];
            #pragma unroll
            for (int f = 0; f < 8; f++)
                bf[f] = *(const f16x8*)(Bl + (size_t)((kk * 8 + f) * 64 + lane) * 8);
            #pragma unroll
            for (int f = 0; f < 8; f++)
                acc[f] = __builtin_amdgcn_mfma_f32_16x16x32_f16(afr[kk], bf[f], acc[f], 0, 0, 0);
        }
        const float* bb = bs[jw];
        float4 blo = *(const float4*)&bb[mr * 8];
        float4 bhi = *(const float4*)&bb[mr * 8 + 4];
        float bias[8] = {blo.x, blo.y, blo.z, blo.w, bhi.x, bhi.y, bhi.z, bhi.w};
        if (jw == 0) {
            #pragma unroll
            for (int r = 0; r < 4; r++) {
                int row = row0 + w * 16 + g * 4 + r;
                if (row < M) {
                    float4 o0 = make_float4(acc[0][r] + bias[0], acc[1][r] + bias[1],
                                            acc[2][r] + bias[2], acc[3][r] + bias[3]);
                    float4 o1 = make_float4(acc[4][r] + bias[4], acc[5][r] + bias[5],
                                            acc[6][r] + bias[6], acc[7][r] + bias[7]);
                    float* op = out + (size_t)row * 128 + mr * 8;
                    *(float4*)op = o0;
                    *(float4*)(op + 4) = o1;
                }
            }
        } else {
            #pragma unroll
            for (int r = 0; r < 4; r++) {
                float v0 = acc[0][r] + bias[0], v1 = acc[1][r] + bias[1];
                float v2 = acc[2][r] + bias[2], v3 = acc[3][r] + bias[3];
                float v4 = acc[4][r] + bias[4], v5 = acc[5][r] + bias[5];
                float v6 = acc[6][r] + bias[6], v7 = acc[7][r] + bias[7];
                unsigned int lo = (unsigned)__builtin_amdgcn_cvt_pk_fp8_f32(v0, v1, 0, false);
                lo = (unsigned)__builtin_amdgcn_cvt_pk_fp8_f32(v2, v3, (int)lo, true);
                unsigned int hi = (unsigned)__builtin_amdgcn_cvt_pk_fp8_f32(v4, v5, 0, false);
                hi = (unsigned)__builtin_amdgcn_cvt_pk_fp8_f32(v6, v7, (int)hi, true);
                if (jw == 1) {
                    kp[r] = make_uint2(lo, hi);
                } else {
                    int row = row0 + w * 16 + g * 4 + r;
                    if (row < M) {
                        unsigned char* base = kv8 + ((size_t)row << 9) + mr * 16
                                            + ((jw == 3) ? 256 : 0);
                        *(uint4*)base = make_uint4(kp[r].x, kp[r].y, lo, hi);
                    }
                }
            }
        }
        if (jw < 3) __syncthreads();   // guard W overwrite next iter
    }
}

// ---------------- FUSED: gemm128(li) c-side + gemm_qkv(li+1); v-side tail ------
__global__ __launch_bounds__(256) void gemm_fused(
    int nblk1, int do_qkv,
    // c-side gemm128 (layer li)
    const float* __restrict__ A1, const _Float16* __restrict__ Wa_h,
    const float* __restrict__ bias1, float* __restrict__ xc_out, int M,
    const float* __restrict__ gate1, const float* __restrict__ xold1,
    const float* __restrict__ wk1, const float* __restrict__ bk1, float* __restrict__ ko1,
    const float* __restrict__ wv1, const float* __restrict__ bv1, float* __restrict__ vo1,
    // qkv of layer li+1 (ignored when do_qkv == 0)
    const _Float16* __restrict__ WT4,
    const float* __restrict__ qb0, const float* __restrict__ qb1,
    const float* __restrict__ qb2, const float* __restrict__ qb3,
    float* __restrict__ xq_out, unsigned char* __restrict__ kv8,
    // v-side gemm128 (layer li)
    const float* __restrict__ A2, int lda2, const float* __restrict__ W2,
    const float* __restrict__ bias2, float* __restrict__ out2, int M2,
    const float* __restrict__ gate2, const float* __restrict__ xold2,
    const float* __restrict__ wk2, const float* __restrict__ bk2, float* __restrict__ ko2)
{
    extern __shared__ char dynsm[];
    int tid = threadIdx.x;

    if ((int)blockIdx.x >= nblk1) {
        // ======================= v-side: fp32 vector =======================
        float (*As)[36]  = (float(*)[36])dynsm;                 // 9216 B
        float (*Bs)[128] = (float(*)[128])(dynsm + 64 * 36 * 4); // 16384 B
        int row0 = (blockIdx.x - nblk1) * 64;
        int tx = tid & 15;
        int ty = tid >> 4;
        float acc[4][8] = {};
        for (int k0 = 0; k0 < 128; k0 += 32) {
            __syncthreads();
            #pragma unroll
            for (int i = 0; i < 2; i++) {
                int slot = tid + i * 256;            // [0,512) float4 slots
                int r = slot >> 3, kq = slot & 7;
                int rr = row0 + r;
                float4 v = make_float4(0.f, 0.f, 0.f, 0.f);
                if (rr < M2) v = *(const float4*)(A2 + (size_t)rr * lda2 + k0 + kq * 4);
                *(float4*)&As[r][kq * 4] = v;
            }
            #pragma unroll
            for (int i = 0; i < 4; i++) {
                int slot = tid + i * 256;            // [0,1024)
                int kr = slot >> 5, cq = slot & 31;
                *(float4*)&Bs[kr][cq * 4] = *(const float4*)(W2 + (size_t)(k0 + kr) * 128 + cq * 4);
            }
            __syncthreads();
            #pragma unroll
            for (int k4 = 0; k4 < 32; k4 += 4) {
                float4 av[4];
                #pragma unroll
                for (int i = 0; i < 4; i++)
                    av[i] = *(const float4*)&As[ty * 4 + i][k4];
                #pragma unroll
                for (int kk = 0; kk < 4; kk++) {
                    float4 bl = *(const float4*)&Bs[k4 + kk][tx * 4];
                    float4 bh = *(const float4*)&Bs[k4 + kk][64 + tx * 4];
                    float bb[8] = {bl.x, bl.y, bl.z, bl.w, bh.x, bh.y, bh.z, bh.w};
                    #pragma unroll
                    for (int i = 0; i < 4; i++) {
                        float a = ((const float*)&av[i])[kk];
                        #pragma unroll
                        for (int j = 0; j < 8; j++)
                            acc[i][j] = fmaf(a, bb[j], acc[i][j]);
                    }
                }
            }
        }
        float gt = 1.f / (1.f + expf(-gate2[0]));
        float og = 1.f - gt;
        float wkr[8];
        #pragma unroll
        for (int j = 0; j < 4; j++) {
            wkr[j]     = wk2[tx * 4 + j];
            wkr[4 + j] = wk2[64 + tx * 4 + j];
        }
        #pragma unroll
        for (int i = 0; i < 4; i++) {
            int r = row0 + ty * 4 + i;
            if (r >= M2) continue;   // uniform across each 16-lane group
            float vals[8];
            #pragma unroll
            for (int j = 0; j < 4; j++) {
                float v0 = acc[i][j]     + bias2[tx * 4 + j];
                float v1 = acc[i][4 + j] + bias2[64 + tx * 4 + j];
                v0 = gt * v0 + og * xold2[(size_t)r * 128 + tx * 4 + j];
                v1 = gt * v1 + og * xold2[(size_t)r * 128 + 64 + tx * 4 + j];
                vals[j] = v0;
                vals[4 + j] = v1;
            }
            float* op = out2 + (size_t)r * 128;
            *(float4*)(op + tx * 4)      = make_float4(vals[0], vals[1], vals[2], vals[3]);
            *(float4*)(op + 64 + tx * 4) = make_float4(vals[4], vals[5], vals[6], vals[7]);
            float pk = 0.f;
            #pragma unroll
            for (int j = 0; j < 8; j++) pk = fmaf(vals[j], wkr[j], pk);
            #pragma unroll
            for (int off = 1; off < 16; off <<= 1)
                pk += __shfl_xor(pk, off, 64);
            if (tx == 0) ko2[r] = pk + bk2[0];
        }
        return;
    }

    // ======================= c-side: gemm128 MFMA then qkv =======================
    _Float16 (*Af)[136] = (_Float16(*)[136])dynsm;
    _Float16* Bl = (_Float16*)(dynsm + LDS_AF_BYTES);
    uint4* Blv = (uint4*)(dynsm + LDS_AF_BYTES);
    int row0 = blockIdx.x * 64;
    // stage A and Wa together, one barrier
    #pragma unroll
    for (int i = 0; i < 8; i++) {
        int slot = tid + i * 256;
        int r = slot >> 5, q = slot & 31;
        int rr = row0 + r;
        float4 v = make_float4(0.f, 0.f, 0.f, 0.f);
        if (rr < M) v = *(const float4*)(A1 + (size_t)rr * 128 + q * 4);
        f16x4 h = { (_Float16)v.x, (_Float16)v.y, (_Float16)v.z, (_Float16)v.w };
        *(f16x4*)&Af[r][q * 4] = h;
    }
    {
        const uint4* WTv = (const uint4*)Wa_h;
        uint4 tmp[8];
        #pragma unroll
        for (int i = 0; i < 8; i++) tmp[i] = WTv[tid + i * 256];
        #pragma unroll
        for (int i = 0; i < 8; i++) Blv[tid + i * 256] = tmp[i];
    }
    __syncthreads();

    int lane = tid & 63, w = tid >> 6;
    int mr = lane & 15, g = lane >> 4;
    f16x8 afr[4];
    #pragma unroll
    for (int kk = 0; kk < 4; kk++)
        afr[kk] = *(const f16x8*)&Af[w * 16 + mr][kk * 32 + g * 8];

    f32x4 acc[8] = {};
    #pragma unroll
    for (int kk = 0; kk < 4; kk++) {
        f16x8 bf[8];
        #pragma unroll
        for (int f = 0; f < 8; f++)
            bf[f] = *(const f16x8*)(Bl + (size_t)((kk * 8 + f) * 64 + lane) * 8);
        #pragma unroll
        for (int f = 0; f < 8; f++)
            acc[f] = __builtin_amdgcn_mfma_f32_16x16x32_f16(afr[kk], bf[f], acc[f], 0, 0, 0);
    }

    // epilogue (lane mr owns logical cols [8mr,8mr+8)): vectorized gate+skip,
    // XC write, out-conv projections, fp16 Af write (own rows, no barrier).
    float gt = 1.f / (1.f + expf(-gate1[0]));
    float og = 1.f - gt;
    float4 b_lo = *(const float4*)&bias1[mr * 8];
    float4 b_hi = *(const float4*)&bias1[mr * 8 + 4];
    float bias[8] = {b_lo.x, b_lo.y, b_lo.z, b_lo.w, b_hi.x, b_hi.y, b_hi.z, b_hi.w};
    float4 wk_lo = *(const float4*)&wk1[mr * 8];
    float4 wk_hi = *(const float4*)&wk1[mr * 8 + 4];
    float wkr[8] = {wk_lo.x, wk_lo.y, wk_lo.z, wk_lo.w, wk_hi.x, wk_hi.y, wk_hi.z, wk_hi.w};
    float4 wv_lo = *(const float4*)&wv1[mr * 8];
    float4 wv_hi = *(const float4*)&wv1[mr * 8 + 4];
    float wvr[8] = {wv_lo.x, wv_lo.y, wv_lo.z, wv_lo.w, wv_hi.x, wv_hi.y, wv_hi.z, wv_hi.w};
    float pk[4] = {}, pv[4] = {};
    #pragma unroll
    for (int r = 0; r < 4; r++) {
        int row = row0 + w * 16 + g * 4 + r;
        float v[8];
        if (row < M) {
            const float* xo = xold1 + (size_t)row * 128 + mr * 8;
            float4 x0 = *(const float4*)xo;
            float4 x1 = *(const float4*)(xo + 4);
            float xo8[8] = {x0.x, x0.y, x0.z, x0.w, x1.x, x1.y, x1.z, x1.w};
            #pragma unroll
            for (int f = 0; f < 8; f++) {
                v[f] = gt * (acc[f][r] + bias[f]) + og * xo8[f];
                pk[r] = fmaf(v[f], wkr[f], pk[r]);
                pv[r] = fmaf(v[f], wvr[f], pv[r]);
            }
            float* op = xc_out + (size_t)row * 128 + mr * 8;
            *(float4*)op       = make_float4(v[0], v[1], v[2], v[3]);
            *(float4*)(op + 4) = make_float4(v[4], v[5], v[6], v[7]);
        } else {
            #pragma unroll
            for (int f = 0; f < 8; f++) v[f] = 0.f;
        }
        f16x8 hv = { (_Float16)v[0], (_Float16)v[1], (_Float16)v[2], (_Float16)v[3],
                     (_Float16)v[4], (_Float16)v[5], (_Float16)v[6], (_Float16)v[7] };
        *(f16x8*)&Af[w * 16 + g * 4 + r][mr * 8] = hv;
    }
    #pragma unroll
    for (int r = 0; r < 4; r++) {
        #pragma unroll
        for (int off = 1; off < 16; off <<= 1) {
            pk[r] += __shfl_xor(pk[r], off, 64);
            pv[r] += __shfl_xor(pv[r], off, 64);
        }
    }
    if (mr == 0) {
        #pragma unroll
        for (int r = 0; r < 4; r++) {
            int row = row0 + w * 16 + g * 4 + r;
            if (row < M) {
                ko1[row] = pk[r] + bk1[0];
                vo1[row] = pv[r] + bv1[0];
            }
        }
    }

    if (!do_qkv) return;

    // -------- phase 2: next-layer q~/k/v_cc/v_cv from the in-LDS XC tile --------
    f16x8 afr2[4];
    #pragma unroll
    for (int kk = 0; kk < 4; kk++)
        afr2[kk] = *(const f16x8*)&Af[w * 16 + mr][kk * 32 + g * 8];
    __syncthreads();   // all waves done reading W(a) region before overwrite

    const float* bs[4] = {qb0, qb1, qb2, qb3};
    uint2 kp[4];
    for (int jw = 0; jw < 4; jw++) {
        {
            const uint4* WTv = (const uint4*)(WT4 + (size_t)jw * CH * CH);
            uint4 tmp[8];
            #pragma unroll
            for (int i = 0; i < 8; i++) tmp[i] = WTv[tid + i * 256];
            #pragma unroll
            for (int i = 0; i < 8; i++) Blv[tid + i * 256] = tmp[i];
        }
        __syncthreads();

        f32x4 acc2[8] = {};
        #pragma unroll
        for (int kk = 0; kk < 4; kk++) {
            f16x8 bf[8];
            #pragma unroll
            for (int f = 0; f < 8; f++)
                bf[f] = *(const f16x8*)(Bl + (size_t)((kk * 8 + f) * 64 + lane) * 8);
            #pragma unroll
            for (int f = 0; f < 8; f++)
                acc2[f] = __builtin_amdgcn_mfma_f32_16x16x32_f16(afr2[kk], bf[f], acc2[f], 0, 0, 0);
        }
        const float* bb = bs[jw];
        float4 blo = *(const float4*)&bb[mr * 8];
        float4 bhi = *(const float4*)&bb[mr * 8 + 4];
        float bias2v[8] = {blo.x, blo.y, blo.z, blo.w, bhi.x, bhi.y, bhi.z, bhi.w};
        if (jw == 0) {
            #pragma unroll
            for (int r = 0; r < 4; r++) {
                int row = row0 + w * 16 + g * 4 + r;
                if (row < M) {
                    float4 o0 = make_float4(acc2[0][r] + bias2v[0], acc2[1][r] + bias2v[1],
                                            acc2[2][r] + bias2v[2], acc2[3][r] + bias2v[3]);
                    float4 o1 = make_float4(acc2[4][r] + bias2v[4], acc2[5][r] + bias2v[5],
                                            acc2[6][r] + bias2v[6], acc2[7][r] + bias2v[7]);
                    float* op = xq_out + (size_t)row * 128 + mr * 8;
                    *(float4*)op = o0;
                    *(float4*)(op + 4) = o1;
                }
            }
        } else {
            #pragma unroll
            for (int r = 0; r < 4; r++) {
                float v0 = acc2[0][r] + bias2v[0], v1 = acc2[1][r] + bias2v[1];
                float v2 = acc2[2][r] + bias2v[2], v3 = acc2[3][r] + bias2v[3];
                float v4 = acc2[4][r] + bias2v[4], v5 = acc2[5][r] + bias2v[5];
                float v6 = acc2[6][r] + bias2v[6], v7 = acc2[7][r] + bias2v[7];
                unsigned int lo = (unsigned)__builtin_amdgcn_cvt_pk_fp8_f32(v0, v1, 0, false);
                lo = (unsigned)__builtin_amdgcn_cvt_pk_fp8_f32(v2, v3, (int)lo, true);
                unsigned int hi = (unsigned)__builtin_amdgcn_cvt_pk_fp8_f32(v4, v5, 0, false);
                hi = (unsigned)__builtin_amdgcn_cvt_pk_fp8_f32(v6, v7, (int)hi, true);
                if (jw == 1) {
                    kp[r] = make_uint2(lo, hi);
                } else {
                    int row = row0 + w * 16 + g * 4 + r;
                    if (row < M) {
                        unsigned char* base = kv8 + ((size_t)row << 9) + mr * 16
                                            + ((jw == 3) ? 256 : 0);
                        *(uint4*)base = make_uint4(kp[r].x, kp[r].y, lo, hi);
                    }
                }
            }
        }
        if (jw < 3) __syncthreads();
    }
}

// ---------------- cv gather: 4 groups on one node, 64-edge chunks --------------
__device__ __forceinline__ void gather_cv(
    const unsigned char* __restrict__ kv8, const int* __restrict__ csr,
    int e0, int e1, int g, int j, const float* q8,
    float& s_io, float acc[8])
{
    int lane = threadIdx.x & 63;
    float s = s_io;
    for (int cs = e0; cs < e1; cs += 64) {
        int n = e1 - cs; if (n > 64) n = 64;
        int nm1 = n - 1;
        int idx0 = 0;
        if (lane < n) idx0 = csr[cs + lane];
        int R = (n + 7) >> 3;
        uint4 a0, a1, b0, b1;

#define LD2(E0_, E1_, B0_, B1_) { \
            int i0_ = __shfl(idx0, min((E0_), nm1), 64); \
            int i1_ = __shfl(idx0, min((E1_), nm1), 64); \
            B0_ = *(const uint4*)(kv8 + ((size_t)i0_ << 9) + 256 + (j << 4)); \
            B1_ = *(const uint4*)(kv8 + ((size_t)i1_ << 9) + 256 + (j << 4)); }

#define CMP2(E0_, E1_, B0_, B1_) { \
            float k0f[8], k1f[8], v0f[8], v1f[8]; \
            fp8x8_to_f32(make_uint2(B0_.x, B0_.y), k0f); \
            fp8x8_to_f32(make_uint2(B1_.x, B1_.y), k1f); \
            float d0_ = dot8f(q8, k0f); \
            float d1_ = dot8f(q8, k1f); \
            d0_ += __shfl_xor(d0_, 1, 64); d1_ += __shfl_xor(d1_, 1, 64); \
            d0_ += __shfl_xor(d0_, 2, 64); d1_ += __shfl_xor(d1_, 2, 64); \
            float w0_ = ((E0_) < n) ? __expf(d0_) : 0.f; \
            float w1_ = ((E1_) < n) ? __expf(d1_) : 0.f; \
            s += w0_ + w1_; \
            fp8x8_to_f32(make_uint2(B0_.z, B0_.w), v0f); \
            fp8x8_to_f32(make_uint2(B1_.z, B1_.w), v1f); \
            acc[0] = fmaf(w0_, v0f[0], acc[0]); acc[0] = fmaf(w1_, v1f[0], acc[0]); \
            acc[1] = fmaf(w0_, v0f[1], acc[1]); acc[1] = fmaf(w1_, v1f[1], acc[1]); \
            acc[2] = fmaf(w0_, v0f[2], acc[2]); acc[2] = fmaf(w1_, v1f[2], acc[2]); \
            acc[3] = fmaf(w0_, v0f[3], acc[3]); acc[3] = fmaf(w1_, v1f[3], acc[3]); \
            acc[4] = fmaf(w0_, v0f[4], acc[4]); acc[4] = fmaf(w1_, v1f[4], acc[4]); \
            acc[5] = fmaf(w0_, v0f[5], acc[5]); acc[5] = fmaf(w1_, v1f[5], acc[5]); \
            acc[6] = fmaf(w0_, v0f[6], acc[6]); acc[6] = fmaf(w1_, v1f[6], acc[6]); \
            acc[7] = fmaf(w0_, v0f[7], acc[7]); acc[7] = fmaf(w1_, v1f[7], acc[7]); }

        LD2(g, g + 4, a0, a1);
        if (R > 1) LD2(g + 8, g + 12, b0, b1);
        for (int r = 0; r < R; r += 2) {
            int er = g + 8 * r;
            CMP2(er, er + 4, a0, a1);
            if (r + 2 < R) LD2(g + 8 * (r + 2), g + 8 * (r + 2) + 4, a0, a1);
            if (r + 1 < R) {
                int eo = g + 8 * (r + 1);
                CMP2(eo, eo + 4, b0, b1);
                if (r + 3 < R) LD2(g + 8 * (r + 3), g + 8 * (r + 3) + 4, b0, b1);
            }
        }
#undef LD2
#undef CMP2
    }
    s_io = s;
}

// ---------------- unified attention: cv | cc | prev-layer out-conv tail --------
__global__ __launch_bounds__(256) void attn_uni(
    float* __restrict__ xq, const unsigned char* __restrict__ kv8,
    const float* __restrict__ xv, const float* __restrict__ wqt,
    const float* __restrict__ bqt,
    const int* __restrict__ rs_cc, const int* __restrict__ csr_cc,
    const int* __restrict__ rs_cv, const int* __restrict__ csr_cv,
    float* __restrict__ aggv, int n_c, int ccb,
    // out-conv tail (prev layer); only when grid extends past N_V+ccb
    const float* __restrict__ qo, const float* __restrict__ ko,
    const float* __restrict__ vo,
    const float* __restrict__ arel_o, const float* __restrict__ prel_o,
    const float* __restrict__ mrel_o, const float* __restrict__ Wa_o,
    const float* __restrict__ ba_o, float* __restrict__ outl)
{
    __shared__ float smem[656];
    int lane = threadIdx.x & 63, wid = threadIdx.x >> 6;
    int g = lane >> 4, j = lane & 15;

    if (blockIdx.x < N_V) {
        // ---------------- cv node (4 waves, 4 groups each) ----------------
        int node = blockIdx.x;
        float* qrow = smem;          // [128]
        float* sm_s = smem + 128;    // [4][4]
        float* sm_a = smem + 144;    // [4][128]
        if (wid < 2) {
            int col = wid * 64 + lane;
            float a = bqt[col];
            const float* xr = xv + (size_t)node * 128;
            for (int k = 0; k < 128; k++)
                a = fmaf(xr[k], wqt[(size_t)k * 128 + col], a);
            qrow[col] = a;
        }
        __syncthreads();
        float q8[8];
        *(float4*)&q8[0] = *(const float4*)&qrow[8 * j];
        *(float4*)&q8[4] = *(const float4*)&qrow[8 * j + 4];
        int rs = rs_cv[node], re = rs_cv[node + 1];
        int cnt = re - rs;
        int per = (cnt + 3) >> 2;
        int e0 = rs + wid * per, e1 = min(e0 + per, re);
        float s = 0.f;
        float acc[8] = {};
        gather_cv(kv8, csr_cv, e0, e1, g, j, q8, s, acc);
        #pragma unroll
        for (int i = 0; i < 8; i++) {
            acc[i] += __shfl_xor(acc[i], 16, 64);
            acc[i] += __shfl_xor(acc[i], 32, 64);
        }
        s += __shfl_xor(s, 16, 64);
        s += __shfl_xor(s, 32, 64);
        if (g == 0) {
            *(float4*)&sm_a[wid * 128 + 8 * j]     = make_float4(acc[0], acc[1], acc[2], acc[3]);
            *(float4*)&sm_a[wid * 128 + 8 * j + 4] = make_float4(acc[4], acc[5], acc[6], acc[7]);
            if ((j & 3) == 0) sm_s[wid * 4 + (j >> 2)] = s;
        }
        __syncthreads();
        if (threadIdx.x < 64) {
            int lp = 2 * lane;
            int h = lp >> 5;
            float S = 0.f, AX = 0.f, AY = 0.f;
            #pragma unroll
            for (int i = 0; i < 4; i++) {
                S  += sm_s[i * 4 + h];
                float2 a2 = *(const float2*)&sm_a[i * 128 + lp];
                AX += a2.x;
                AY += a2.y;
            }
            float inv = (S > 0.f) ? 1.f / S : 0.f;
            aggv[(size_t)node * 128 + lp]     = gelu_tanh(AX * inv);
            aggv[(size_t)node * 128 + lp + 1] = gelu_tanh(AY * inv);
        }
    } else if ((int)blockIdx.x < N_V + ccb) {
        // ---------------- cc: one node per 16-lane group ----------------
        int node = (blockIdx.x - N_V) * 16 + wid * 4 + g;
        bool valid = (node < n_c);
        int rs = valid ? rs_cc[node] : 0;
        int re = valid ? rs_cc[node + 1] : 0;
        float q8[8];
        if (valid) {
            const float* qp = xq + (size_t)node * 128 + 8 * j;
            *(float4*)&q8[0] = *(const float4*)qp;
            *(float4*)&q8[4] = *(const float4*)(qp + 4);
        } else {
            #pragma unroll
            for (int i = 0; i < 8; i++) q8[i] = 0.f;
        }
        float s = 0.f;
        float acc[8] = {};
        int base = lane & 48;

        for (int cs = rs; cs < re; cs += 16) {
            int cnt = min(16, re - cs);
            int cm1 = cnt - 1;
            int idx = csr_cc[cs + min(j, cm1)];
            uint4 B0, B1, B2, B3;

#define LDE(E_, B_) { int i_ = __shfl(idx, base + min((E_), cm1), 64); \
            B_ = *(const uint4*)(kv8 + ((size_t)i_ << 9) + (j << 4)); }
#define CMPE(E_, B_) { float kf[8], vf[8]; \
            fp8x8_to_f32(make_uint2(B_.x, B_.y), kf); \
            float d_ = dot8f(q8, kf); \
            d_ += __shfl_xor(d_, 1, 64); d_ += __shfl_xor(d_, 2, 64); \
            float w_ = ((E_) < cnt) ? __expf(d_) : 0.f; \
            s += w_; \
            fp8x8_to_f32(make_uint2(B_.z, B_.w), vf); \
            acc[0] = fmaf(w_, vf[0], acc[0]); \
            acc[1] = fmaf(w_, vf[1], acc[1]); \
            acc[2] = fmaf(w_, vf[2], acc[2]); \
            acc[3] = fmaf(w_, vf[3], acc[3]); \
            acc[4] = fmaf(w_, vf[4], acc[4]); \
            acc[5] = fmaf(w_, vf[5], acc[5]); \
            acc[6] = fmaf(w_, vf[6], acc[6]); \
            acc[7] = fmaf(w_, vf[7], acc[7]); }

            LDE(0, B0) LDE(1, B1) LDE(2, B2) LDE(3, B3)
            CMPE(0, B0) CMPE(1, B1)
            if (cnt > 4) { LDE(4, B0) LDE(5, B1) }
            CMPE(2, B2) CMPE(3, B3)
            if (cnt > 6) { LDE(6, B2) LDE(7, B3) }
            if (cnt > 4) {
                CMPE(4, B0) CMPE(5, B1)
                if (cnt > 8) { LDE(8, B0) LDE(9, B1) }
                CMPE(6, B2) CMPE(7, B3)
                if (cnt > 10) { LDE(10, B2) LDE(11, B3) }
                if (cnt > 8) {
                    CMPE(8, B0) CMPE(9, B1)
                    if (cnt > 12) { LDE(12, B0) LDE(13, B1) }
                    CMPE(10, B2) CMPE(11, B3)
                    if (cnt > 14) { LDE(14, B2) LDE(15, B3) }
                    if (cnt > 12) {
                        CMPE(12, B0) CMPE(13, B1) CMPE(14, B2) CMPE(15, B3)
                    }
                }
            }
#undef LDE
#undef CMPE
        }
        if (valid) {
            float inv = (s > 0.f) ? 1.f / s : 0.f;
            float4 o0 = make_float4(gelu_tanh(acc[0] * inv), gelu_tanh(acc[1] * inv),
                                    gelu_tanh(acc[2] * inv), gelu_tanh(acc[3] * inv));
            float4 o1 = make_float4(gelu_tanh(acc[4] * inv), gelu_tanh(acc[5] * inv),
                                    gelu_tanh(acc[6] * inv), gelu_tanh(acc[7] * inv));
            float* op = xq + (size_t)node * 128 + 8 * j;
            *(float4*)op = o0;
            *(float4*)(op + 4) = o1;
        }
    } else {
        // ---------------- prev-layer out-conv scalar attention ----------------
        int node = blockIdx.x - N_V - ccb;
        float* sms = smem;       // [4]
        float* sma = smem + 4;   // [4]
        float qs = qo[node] * arel_o[0] * prel_o[0];
        int rs = rs_cv[node], re = rs_cv[node + 1];
        float s = 0.f, a = 0.f;
        for (int e = rs + (int)threadIdx.x; e < re; e += 256) {
            int si = csr_cv[e];
            float w = __expf(qs * ko[si]);
            s += w;
            a = fmaf(w, vo[si], a);
        }
        #pragma unroll
        for (int off = 32; off >= 1; off >>= 1) {
            s += __shfl_xor(s, off, 64);
            a += __shfl_xor(a, off, 64);
        }
        if (lane == 0) { sms[wid] = s; sma[wid] = a; }
        __syncthreads();
        if (threadIdx.x == 0) {
            float S = sms[0] + sms[1] + sms[2] + sms[3];
            float A = sma[0] + sma[1] + sma[2] + sma[3];
            float agg = (S > 0.f) ? A / S : 0.f;
            agg *= mrel_o[0];
            outl[node] = gelu_tanh(agg) * Wa_o[0] + ba_o[0];
        }
    }
}

// ---------------- out-conv scalar attention (standalone, last layer) -----------
__global__ __launch_bounds__(256) void attn_out(
    const float* __restrict__ qo, const float* __restrict__ ko, const float* __restrict__ vo,
    const int* __restrict__ rowstart, const int* __restrict__ csr,
    const float* __restrict__ arel_o, const float* __restrict__ prel_o,
    const float* __restrict__ mrel_o, const float* __restrict__ Wa_o,
    const float* __restrict__ ba_o, float* __restrict__ outl)
{
    int node = blockIdx.x;
    float qs = qo[node] * arel_o[0] * prel_o[0];
    int rs = rowstart[node], re = rowstart[node + 1];
    float s = 0.f, a = 0.f;
    for (int e = rs + (int)threadIdx.x; e < re; e += 256) {
        int si = csr[e];
        float w = __expf(qs * ko[si]);
        s += w;
        a = fmaf(w, vo[si], a);
    }
    #pragma unroll
    for (int off = 32; off >= 1; off >>= 1) {
        s += __shfl_xor(s, off, 64);
        a += __shfl_xor(a, off, 64);
    }
    __shared__ float sms[4], sma[4];
    int lane = threadIdx.x & 63, wid = threadIdx.x >> 6;
    if (lane == 0) { sms[wid] = s; sma[wid] = a; }
    __syncthreads();
    if (threadIdx.x == 0) {
        float S = sms[0] + sms[1] + sms[2] + sms[3];
        float A = sma[0] + sma[1] + sma[2] + sma[3];
        float agg = (S > 0.f) ? A / S : 0.f;
        agg *= mrel_o[0];
        outl[node] = gelu_tanh(agg) * Wa_o[0] + ba_o[0];
    }
}

// ---------------- final head: JK-max -> node_fc -> MLP ------------------------
__global__ void final_head(const float* __restrict__ outs,
    const float* __restrict__ fc_W, const float* __restrict__ fc_b,
    const float* __restrict__ W1, const float* __restrict__ b1,
    const float* __restrict__ W2, const float* __restrict__ b2,
    float* __restrict__ out)
{
    int b = threadIdx.x;
    if (b >= 64) return;
    float h = fc_b[0];
    #pragma unroll
    for (int v = 0; v < 4; v++) {
        int n = b * 4 + v;
        float jk = fmaxf(fmaxf(outs[0 * N_V + n], outs[1 * N_V + n]), outs[2 * N_V + n]);
        h = fmaf(jk, fc_W[v], h);
    }
    h = gelu_tanh(h);
    float h0 = gelu_tanh(h * W1[0] + b1[0]);
    float h1 = gelu_tanh(h * W1[1] + b1[1]);
    out[b] = h0 * W2[0] + h1 * W2[1] + b2[0];
}

// ---------------- orchestration ----------------------------------------------
extern "C" void kernel_launch(void* const* d_in, const int* in_sizes, int n_in,
                              void* d_out, int out_size, void* d_ws, size_t ws_size,
                              hipStream_t stream) {
    (void)in_sizes; (void)n_in; (void)out_size; (void)ws_size;
    const float* x_cell  = (const float*)d_in[0];
    const float* x_vcell = (const float*)d_in[1];
    const float* Wk   = (const float*)d_in[2];
    const float* bk   = (const float*)d_in[3];
    const float* Wq   = (const float*)d_in[4];
    const float* bq   = (const float*)d_in[5];
    const float* Wv   = (const float*)d_in[6];
    const float* bv   = (const float*)d_in[7];
    const float* Wa   = (const float*)d_in[8];
    const float* ba   = (const float*)d_in[9];
    const float* skip = (const float*)d_in[10];
    const float* arel = (const float*)d_in[11];
    const float* mrel = (const float*)d_in[12];
    const float* prel = (const float*)d_in[13];
    const float* Wk_o = (const float*)d_in[14];
    const float* bk_o = (const float*)d_in[15];
    const float* Wq_o = (const float*)d_in[16];
    const float* bq_o = (const float*)d_in[17];
    const float* Wv_o = (const float*)d_in[18];
    const float* bv_o = (const float*)d_in[19];
    const float* Wa_o = (const float*)d_in[20];
    const float* ba_o = (const float*)d_in[21];
    const float* arel_o = (const float*)d_in[22];
    const float* mrel_o = (const float*)d_in[23];
    const float* prel_o = (const float*)d_in[24];
    const float* fc_W  = (const float*)d_in[25];
    const float* fc_b  = (const float*)d_in[26];
    const float* mlp_W1 = (const float*)d_in[27];
    const float* mlp_b1 = (const float*)d_in[28];
    const float* mlp_W2 = (const float*)d_in[29];
    const float* mlp_b2 = (const float*)d_in[30];
    const int* src_cc = (const int*)d_in[31];
    const int* dst_cc = (const int*)d_in[32];
    const int* src_cv = (const int*)d_in[33];
    const int* dst_cv = (const int*)d_in[34];

    // workspace carve-up (256B aligned)
    char* p = (char*)d_ws;
    auto alloc = [&](size_t bytes) -> char* {
        uintptr_t q = ((uintptr_t)p + 255) & ~(uintptr_t)255;
        p = (char*)(q + bytes);
        return (char*)q;
    };
    float* WQT  = (float*)alloc(sizeof(float) * NL * 2 * CH * CH);
    float* BQT  = (float*)alloc(sizeof(float) * NL * 2 * CH);
    float* WVT  = (float*)alloc(sizeof(float) * NL * 2 * CH * CH);
    float* BVT  = (float*)alloc(sizeof(float) * NL * 2 * CH);
    _Float16* WT16 = (_Float16*)alloc(sizeof(_Float16) * NL * 5 * CH * CH);
    float* XC   = (float*)alloc(sizeof(float) * (size_t)N_C * CH);
    float* XV   = (float*)alloc(sizeof(float) * (size_t)N_V * CH);
    float* XQ   = (float*)alloc(sizeof(float) * (size_t)N_C * CH);  // q~ / agg
    unsigned char* KV8 = (unsigned char*)alloc((size_t)N_C * 512);  // k|v_cc , k|v_cv fp8
    float* AGGV = (float*)alloc(sizeof(float) * (size_t)N_V * CH);
    float* KO   = (float*)alloc(sizeof(float) * N_C);
    float* VO   = (float*)alloc(sizeof(float) * N_C);
    float* QO   = (float*)alloc(sizeof(float) * N_V);
    float* OUTS = (float*)alloc(sizeof(float) * NL * N_V);
    // CSR-build scratch (hist region zeroed in one memset)
    int* bhist    = (int*)alloc(sizeof(int) * 512);
    int* bhist_cc = bhist;
    int* bhist_cv = bhist + 256;
    int* bbase_cc = (int*)alloc(sizeof(int) * 257);
    int* cur_cc   = (int*)alloc(sizeof(int) * 256);
    int* cur_cv   = (int*)alloc(sizeof(int) * 256);
    int* rs_cc    = (int*)alloc(sizeof(int) * (N_C + 1));
    int* rs_cv    = (int*)alloc(sizeof(int) * (N_V + 1));
    int* csr_cc   = (int*)alloc(sizeof(int) * NE1);
    int* csr_cv   = (int*)alloc(sizeof(int) * NE2);
    int2* tmp_cc  = (int2*)alloc(sizeof(int2) * NE1);

    // ---- setup: composed weights + fp16 fragment weights + CSR ----
    const int tot_c = NL * 2 * (CH + 1) * CH;
    compose_both<<<CDIV(2 * tot_c, 256), 256, 0, stream>>>(
        Wq, bq, arel, prel, WQT, BQT, Wv, bv, mrel, WVT, BVT);
    cvt_w16<<<CDIV(NL * 5 * CH * CH, 256), 256, 0, stream>>>(WQT, Wk, WVT, Wa, WT16);
    hipMemsetAsync(bhist, 0, sizeof(int) * 512, stream);
    const int nb_cc = CDIV(NE1, EPB), nb_cv = CDIV(NE2, EPB);
    bucket_hist2<<<nb_cc + nb_cv, 256, 0, stream>>>(dst_cc, dst_cv, nb_cc,
                                                    bhist_cc, bhist_cv);
    scan256x2<<<2, 256, 0, stream>>>(bhist_cc, bbase_cc, cur_cc,
                                     bhist_cv, rs_cv, cur_cv);  // rs_cv IS cv row starts
    partition2<<<nb_cc + nb_cv, 256, 0, stream>>>(src_cc, dst_cc, src_cv, dst_cv, nb_cc,
                                                  cur_cc, cur_cv, tmp_cc, csr_cv);
    bucket_finalize<<<CDIV(N_C, 256), 256, 0, stream>>>(tmp_cc, bbase_cc, N_C, NE1,
                                                        rs_cc, csr_cc);

    const int gb_c = CDIV(N_C, 64);             // 938
    const int gb_v = CDIV(N_V, 64);             // 4
    const int ccb = CDIV(N_C, 16);              // 3750 cc blocks

    // ---- layer 0 q~/k/v from x_cell ----
    gemm_qkv<<<gb_c, 256, SM_GEMM, stream>>>(
        x_cell, 128, N_C,
        WT16, BQT, bk, BVT, BVT + CH, XQ, KV8);
    attn_uni<<<N_V + ccb, 256, 0, stream>>>(
        XQ, KV8, x_vcell, WQT + (size_t)CH * CH, BQT + CH,
        rs_cc, csr_cc, rs_cv, csr_cv, AGGV, N_C, ccb,
        nullptr, nullptr, nullptr, nullptr, nullptr, nullptr, nullptr, nullptr, nullptr);

    for (int li = 0; li < NL; li++) {
        const float* xc_src = (li == 0) ? x_cell : XC;   // xold for gemm128(li)
        const float* xv_src = (li == 0) ? x_vcell : XV;
        int b0 = (li * 2) * CH, b1 = (li * 2 + 1) * CH;
        size_t w1 = (size_t)(li * 2 + 1) * CH * CH;
        const _Float16* WT_a = WT16 + (size_t)(li * 5 + 4) * CH * CH;
        int do_qkv = (li + 1 < NL) ? 1 : 0;
        const _Float16* WT5n = WT16 + (size_t)((li + 1) % NL * 5) * CH * CH;
        int nb0 = ((li + 1) % NL * 2) * CH, nb1 = ((li + 1) % NL * 2 + 1) * CH;

        // fused: gemm128(li) c-side + v-side; then qkv(li+1) from in-LDS XC tile
        gemm_fused<<<gb_c + gb_v, 256, SM_GEMM, stream>>>(
            gb_c, do_qkv,
            XQ, WT_a, ba + b0, XC, N_C,
            skip + li * 2, xc_src,
            Wk_o + li * CH, bk_o + li, KO,
            Wv_o + li * CH, bv_o + li, VO,
            WT5n, BQT + nb0, bk + nb0, BVT + nb0, BVT + nb1, XQ, KV8,
            AGGV, 128, Wa + w1, ba + b1, XV, N_V,
            skip + li * 2 + 1, xv_src,
            Wq_o + li * CH, bq_o + li, QO);

        if (do_qkv) {
            // attention for layer li+1, plus out-conv(li) tail -> OUTS[li]
            size_t w1n = (size_t)((li + 1) * 2 + 1) * CH * CH;
            attn_uni<<<N_V + ccb + N_V, 256, 0, stream>>>(
                XQ, KV8, XV, WQT + w1n, BQT + (li + 1) * 2 * CH + CH,
                rs_cc, csr_cc, rs_cv, csr_cv, AGGV, N_C, ccb,
                QO, KO, VO,
                arel_o + li, prel_o + li, mrel_o + li,
                Wa_o + li, ba_o + li, OUTS + li * N_V);
        }
    }

    // last layer's out-conv attention, then final head
    attn_out<<<N_V, 256, 0, stream>>>(QO, KO, VO, rs_cv, csr_cv,
                                      arel_o + (NL - 1), prel_o + (NL - 1), mrel_o + (NL - 1),
                                      Wa_o + (NL - 1), ba_o + (NL - 1), OUTS + (NL - 1) * N_V);
    final_head<<<1, 64, 0, stream>>>(OUTS, fc_W, fc_b, mlp_W1, mlp_b1, mlp_W2, mlp_b2,
                                     (float*)d_out);
}